// Round 3
// baseline (5933.172 us; speedup 1.0000x reference)
//
#include <hip/hip_runtime.h>
#include <stdint.h>

typedef __attribute__((ext_vector_type(4))) float f32x4;
typedef __attribute__((ext_vector_type(8))) short s16x8;
typedef unsigned short u16;

constexpr int    Tn  = 8;
constexpr int    Nn  = 512;
constexpr int    Cn  = 768;
constexpr int    Dn  = 64;
constexpr int    BHn = 96;
constexpr int    BNn = 4096;
constexpr int    C3n = 2304;
constexpr size_t BHND = 3145728;     // B*H*N*D
constexpr size_t BHNN = 25165824;    // B*H*N*N
constexpr size_t BNC  = 3145728;     // B*N*C

// ---- all state lives in device globals (zero-init -> NOBITS, no .so bloat) ----
__device__ float  g_qkvt[(size_t)BNn * C3n];
__device__ float  g_qq[BHND];
__device__ float  g_kq[BHND];
__device__ float  g_vq[BHND];
__device__ int8_t g_qa[BHND];
__device__ int8_t g_ka[BHND];
__device__ int8_t g_va[BHND];
__device__ u16    g_A1[BHND * 2];                  // [bh][n][128]
__device__ u16    g_B1[BHND * 2];
__device__ short  g_S16[BHNN];
__device__ short  g_aifq[BHNN];                    // q*8, exact int
__device__ int8_t g_aifa[BHNN];
__device__ int8_t g_smX[BHNN];
__device__ float  g_smY[BHNN];
__device__ float  g_sifq[BHNN];
__device__ int8_t g_sifa[BHNN];
__device__ u16    g_A2[BHNN * 2];                  // [bh*n][1024]
__device__ u16    g_vT[(size_t)BHn * Dn * 1024];   // [bh][d][1024]
__device__ float  g_pv[BHND];
__device__ float  g_oq[BHND];
__device__ int8_t g_oa[BHND];
__device__ float  g_osp[BNC];
__device__ float  g_proj[BNC];
__device__ float  g_pq[BNC];
__device__ int8_t g_pa[BNC];

static __device__ __forceinline__ u16 f2bf(float f) {
    union { float f; unsigned int u; } v; v.f = f;
    return (u16)(v.u >> 16);   // exact for small-integer-valued floats
}

// symmetric IF neuron step (pos_max=7, neg_min=-8)
static __device__ __forceinline__ float if_sym(float x, float& q, int8_t& a8) {
    float q2 = q + x;
    int a = a8;
    bool pos = ((q2 - 1.0f) >= 0.0f) && (a < 7);
    bool neg = (q2 < 0.0f) && (a > -8);
    float out = pos ? 1.0f : (neg ? -1.0f : 0.0f);
    q = q2 - out;
    a8 = (int8_t)(a + (int)out);
    return out;
}

// ---------------- init all persistent states ----------------
__global__ __launch_bounds__(256) void init_states() {
    size_t i0 = (size_t)blockIdx.x * blockDim.x + threadIdx.x;
    size_t stride = (size_t)gridDim.x * blockDim.x;
    for (size_t i = i0; i < BHNN; i += stride) {
        if (i < BHND) {
            g_qq[i] = 0.5f; g_kq[i] = 0.5f; g_vq[i] = 0.5f;
            g_qa[i] = 0; g_ka[i] = 0; g_va[i] = 0;
            g_oq[i] = 0.5f; g_oa[i] = 0;
            g_pq[i] = 0.5f; g_pa[i] = 0;       // BNC == BHND
        }
        g_aifq[i] = 4;       // q=0.5 stored as q*8
        g_aifa[i] = 0;
        g_smX[i]  = 0;
        g_smY[i]  = 0.0f;
        g_sifq[i] = 0.5f;
        g_sifa[i] = 0;
    }
}

// ---------------- fp32 NT GEMM body: C[m][j] = sum_k A[m][k]*B[j][k] --------
// k accumulated strictly ascending with fused fmaf per output (Eigen gebp order).
static __device__ __forceinline__ void gemm_f32_nt_body(
    const float* __restrict__ A, int lda,
    const float* __restrict__ B, int ldb,
    float* __restrict__ C, int ldc, int K)
{
    __shared__ __align__(16) float As[16][128];
    __shared__ __align__(16) float Bs[16][128];
    const int tid = threadIdx.x;
    const int m0 = blockIdx.y * 128;
    const int j0 = blockIdx.x * 128;
    const int ty = tid >> 4, tx = tid & 15;
    float acc[8][8];
#pragma unroll
    for (int i = 0; i < 8; ++i)
#pragma unroll
        for (int j = 0; j < 8; ++j) acc[i][j] = 0.0f;

    for (int k0 = 0; k0 < K; k0 += 16) {
#pragma unroll
        for (int u = 0; u < 2; ++u) {
            int f4 = tid + u * 256;
            int row = f4 >> 2;
            int c4 = (f4 & 3) << 2;
            float4 av = *(const float4*)(A + (size_t)(m0 + row) * lda + k0 + c4);
            As[c4 + 0][row] = av.x; As[c4 + 1][row] = av.y;
            As[c4 + 2][row] = av.z; As[c4 + 3][row] = av.w;
            float4 bv = *(const float4*)(B + (size_t)(j0 + row) * ldb + k0 + c4);
            Bs[c4 + 0][row] = bv.x; Bs[c4 + 1][row] = bv.y;
            Bs[c4 + 2][row] = bv.z; Bs[c4 + 3][row] = bv.w;
        }
        __syncthreads();
#pragma unroll
        for (int k = 0; k < 16; ++k) {
            float a[8], b[8];
            *(float4*)(a)     = *(const float4*)&As[k][ty * 8];
            *(float4*)(a + 4) = *(const float4*)&As[k][ty * 8 + 4];
            *(float4*)(b)     = *(const float4*)&Bs[k][tx * 8];
            *(float4*)(b + 4) = *(const float4*)&Bs[k][tx * 8 + 4];
#pragma unroll
            for (int i = 0; i < 8; ++i)
#pragma unroll
                for (int j = 0; j < 8; ++j)
                    acc[i][j] = fmaf(a[i], b[j], acc[i][j]);
        }
        __syncthreads();
    }
#pragma unroll
    for (int i = 0; i < 8; ++i) {
        float* cp = C + (size_t)(m0 + ty * 8 + i) * ldc + j0 + tx * 8;
#pragma unroll
        for (int j = 0; j < 8; ++j) cp[j] = acc[i][j];
    }
}

__global__ __launch_bounds__(256) void gemm_qkv_kernel(
    const float* __restrict__ xt, const float* __restrict__ w_qkv)
{
    gemm_f32_nt_body(xt, Cn, w_qkv, Cn, g_qkvt, C3n, Cn);
}

__global__ __launch_bounds__(256) void gemm_proj_kernel(const float* __restrict__ w_proj)
{
    gemm_f32_nt_body(g_osp, Cn, w_proj, Cn, g_proj, Cn, Cn);
}

// ---------------- q/k/v IF step + build bf16 operands ----------------------
__global__ __launch_bounds__(256) void if_qkv() {
    int idx = blockIdx.x * 256 + threadIdx.x;   // [0, BHND)
    int d = idx & 63;
    int n = (idx >> 6) & 511;
    int bh = idx >> 15;
    int b = bh / 12, h = bh - b * 12;
    size_t qrow = ((size_t)(b * Nn + n)) * C3n + h * 64 + d;

    float xq = g_qkvt[qrow];
    float xk = g_qkvt[qrow + 768];
    float xv = g_qkvt[qrow + 1536];

    float fq = g_qq[idx]; int8_t aq = g_qa[idx];
    float so_q = if_sym(xq, fq, aq);
    g_qq[idx] = fq; g_qa[idx] = aq;

    float fk = g_kq[idx]; int8_t ak = g_ka[idx];
    float so_k = if_sym(xk, fk, ak);
    g_kq[idx] = fk; g_ka[idx] = ak;

    float fv = g_vq[idx]; int8_t av = g_va[idx];
    float so_v = if_sym(xv, fv, av);
    g_vq[idx] = fv; g_va[idx] = av;

    // attn operands (K=128): A1 = [acc_q | q_spike], B1 = [k_spike | k_acc-k]
    size_t a1b = ((size_t)bh * Nn + n) * 128 + d;
    g_A1[a1b]      = f2bf((float)aq);
    g_A1[a1b + 64] = f2bf(so_q);
    g_B1[a1b]      = f2bf(so_k);
    g_B1[a1b + 64] = f2bf((float)ak - so_k);

    // PV B operand transposed: vT[bh][d][k]: k<512 v spike, k>=512 v_acc-v
    size_t vtb = ((size_t)bh * Dn + d) * 1024 + n;
    g_vT[vtb]       = f2bf(so_v);
    g_vT[vtb + 512] = f2bf((float)av - so_v);
}

// ---------------- attn logits: S = accq@k^T + q@(kacc-k)^T (exact ints) -----
__global__ __launch_bounds__(256) void gemm_attn() {
    int bh = blockIdx.y;
    int tm = blockIdx.x >> 3, tn = blockIdx.x & 7;
    int wave = threadIdx.x >> 6, lane = threadIdx.x & 63;
    int wr = wave >> 1, wc = wave & 1;
    int row0 = tm * 64 + wr * 32, col0 = tn * 64 + wc * 32;
    const u16* Ab = g_A1 + (size_t)bh * Nn * 128;
    const u16* Bb = g_B1 + (size_t)bh * Nn * 128;
    int lr = lane & 15, kg = (lane >> 4) * 8;
    f32x4 acc[2][2] = {};
#pragma unroll
    for (int kk = 0; kk < 128; kk += 32) {
        s16x8 a0 = *(const s16x8*)&Ab[(row0 + lr) * 128 + kk + kg];
        s16x8 a1 = *(const s16x8*)&Ab[(row0 + 16 + lr) * 128 + kk + kg];
        s16x8 b0 = *(const s16x8*)&Bb[(col0 + lr) * 128 + kk + kg];
        s16x8 b1 = *(const s16x8*)&Bb[(col0 + 16 + lr) * 128 + kk + kg];
        acc[0][0] = __builtin_amdgcn_mfma_f32_16x16x32_bf16(a0, b0, acc[0][0], 0, 0, 0);
        acc[0][1] = __builtin_amdgcn_mfma_f32_16x16x32_bf16(a0, b1, acc[0][1], 0, 0, 0);
        acc[1][0] = __builtin_amdgcn_mfma_f32_16x16x32_bf16(a1, b0, acc[1][0], 0, 0, 0);
        acc[1][1] = __builtin_amdgcn_mfma_f32_16x16x32_bf16(a1, b1, acc[1][1], 0, 0, 0);
    }
    short* Sb = g_S16 + (size_t)bh * Nn * Nn;
#pragma unroll
    for (int i = 0; i < 2; ++i)
#pragma unroll
        for (int j = 0; j < 2; ++j)
#pragma unroll
            for (int q = 0; q < 4; ++q) {
                int row = row0 + i * 16 + (lane >> 4) * 4 + q;
                int col = col0 + j * 16 + lr;
                Sb[row * Nn + col] = (short)(int)acc[i][j][q];
            }
}

// ---------------- aif IF (int) + spiking softmax + sif IF -------------------
__global__ __launch_bounds__(256) void attn_pipeline(float scale_t) {
    size_t base = (size_t)blockIdx.x * Nn;   // row = bh*512 + n
    int tid = threadIdx.x;
    __shared__ int   redI[4];
    __shared__ float redF[4];

    int X[2];
    int myMax = -128;
#pragma unroll
    for (int u = 0; u < 2; ++u) {
        int c = tid + u * 256;
        int s  = g_S16[base + c];
        int q8 = g_aifq[base + c] + s;      // q*8 integer arithmetic, exact
        int a  = g_aifa[base + c];
        bool pos = (q8 >= 8) && (a < 7);
        bool neg = (q8 < 0) && (a > -8);
        int o = pos ? 1 : (neg ? -1 : 0);
        g_aifq[base + c] = (short)(q8 - (o << 3));
        g_aifa[base + c] = (int8_t)(a + o);
        int x = g_smX[base + c] + o;
        g_smX[base + c] = (int8_t)x;
        X[u] = x;
        myMax = max(myMax, x);
    }
    for (int off = 32; off; off >>= 1) myMax = max(myMax, __shfl_xor(myMax, off));
    if ((tid & 63) == 0) redI[tid >> 6] = myMax;
    __syncthreads();
    int M = max(max(redI[0], redI[1]), max(redI[2], redI[3]));

    float e[2];
    float mySum = 0.0f;
#pragma unroll
    for (int u = 0; u < 2; ++u) { e[u] = expf((float)(X[u] - M)); mySum += e[u]; }
    for (int off = 32; off; off >>= 1) mySum += __shfl_xor(mySum, off);
    if ((tid & 63) == 0) redF[tid >> 6] = mySum;
    __syncthreads();
    float Ssum = (redF[0] + redF[1]) + (redF[2] + redF[3]);

#pragma unroll
    for (int u = 0; u < 2; ++u) {
        int c = tid + u * 256;
        float y = (e[u] / Ssum) * scale_t;
        float dlt = y - g_smY[base + c];
        g_smY[base + c] = y;
        float q = g_sifq[base + c] + dlt;
        int a = g_sifa[base + c];
        bool pos = ((q - 1.0f) >= 0.0f) && (a < 7);
        bool neg = (q < 0.0f) && (a > 0);   // neg_min = 0 (unsym)
        float o = pos ? 1.0f : (neg ? -1.0f : 0.0f);
        g_sifq[base + c] = q - o;
        int an = a + (int)o;
        g_sifa[base + c] = (int8_t)an;
        // PV A-operand: [sif_acc | spike], K=1024
        g_A2[base * 2 + c]       = f2bf((float)an);
        g_A2[base * 2 + 512 + c] = f2bf(o);
    }
}

// ---------------- PV: out[n][d] = sum_k A2[n][k]*vT[d][k] (exact ints) ------
__global__ __launch_bounds__(256) void gemm_pv() {
    int bh = blockIdx.y;
    int tm = blockIdx.x;
    int wave = threadIdx.x >> 6, lane = threadIdx.x & 63;
    int wr = wave >> 1, wc = wave & 1;
    int row0 = tm * 64 + wr * 32, col0 = wc * 32;
    const u16* Ab = g_A2 + (size_t)bh * Nn * 1024;
    const u16* Bb = g_vT + (size_t)bh * Dn * 1024;
    int lr = lane & 15, kg = (lane >> 4) * 8;
    f32x4 acc[2][2] = {};
    for (int kk = 0; kk < 1024; kk += 32) {
        s16x8 a0 = *(const s16x8*)&Ab[(row0 + lr) * 1024 + kk + kg];
        s16x8 a1 = *(const s16x8*)&Ab[(row0 + 16 + lr) * 1024 + kk + kg];
        s16x8 b0 = *(const s16x8*)&Bb[(col0 + lr) * 1024 + kk + kg];
        s16x8 b1 = *(const s16x8*)&Bb[(col0 + 16 + lr) * 1024 + kk + kg];
        acc[0][0] = __builtin_amdgcn_mfma_f32_16x16x32_bf16(a0, b0, acc[0][0], 0, 0, 0);
        acc[0][1] = __builtin_amdgcn_mfma_f32_16x16x32_bf16(a0, b1, acc[0][1], 0, 0, 0);
        acc[1][0] = __builtin_amdgcn_mfma_f32_16x16x32_bf16(a1, b0, acc[1][0], 0, 0, 0);
        acc[1][1] = __builtin_amdgcn_mfma_f32_16x16x32_bf16(a1, b1, acc[1][1], 0, 0, 0);
    }
    float* Pb = g_pv + (size_t)bh * Nn * Dn;
#pragma unroll
    for (int i = 0; i < 2; ++i)
#pragma unroll
        for (int j = 0; j < 2; ++j)
#pragma unroll
            for (int q = 0; q < 4; ++q) {
                int row = row0 + i * 16 + (lane >> 4) * 4 + q;
                int col = col0 + j * 16 + lr;
                Pb[row * Dn + col] = acc[i][j][q];
            }
}

// ---------------- oif IF + write proj-input spikes [B,N,C] ------------------
__global__ __launch_bounds__(256) void oif_kernel() {
    int idx = blockIdx.x * 256 + threadIdx.x;
    float x = g_pv[idx];
    float q = g_oq[idx]; int8_t a = g_oa[idx];
    float o = if_sym(x, q, a);
    g_oq[idx] = q; g_oa[idx] = a;
    int d = idx & 63;
    int n = (idx >> 6) & 511;
    int bh = idx >> 15;
    int b = bh / 12, h = bh - b * 12;
    g_osp[((size_t)(b * Nn + n)) * Cn + h * 64 + d] = o;
}

// ---------------- pif IF + write output spikes ------------------------------
__global__ __launch_bounds__(256) void pif_kernel(float* __restrict__ outp) {
    int idx = blockIdx.x * 256 + threadIdx.x;
    float x = g_proj[idx];
    float q = g_pq[idx]; int8_t a = g_pa[idx];
    float o = if_sym(x, q, a);
    g_pq[idx] = q; g_pa[idx] = a;
    outp[idx] = o;
}

extern "C" void kernel_launch(void* const* d_in, const int* in_sizes, int n_in,
                              void* d_out, int out_size, void* d_ws, size_t ws_size,
                              hipStream_t stream) {
    (void)in_sizes; (void)n_in; (void)out_size; (void)d_ws; (void)ws_size;
    const float* x      = (const float*)d_in[0];
    const float* w_qkv  = (const float*)d_in[1];
    const float* w_proj = (const float*)d_in[2];
    float* outp = (float*)d_out;

    init_states<<<2048, 256, 0, stream>>>();

    for (int t = 0; t < Tn; ++t) {
        const float* xt = x + (size_t)t * BNC;
        gemm_qkv_kernel<<<dim3(C3n / 128, BNn / 128), 256, 0, stream>>>(xt, w_qkv);
        if_qkv<<<(int)(BHND / 256), 256, 0, stream>>>();
        gemm_attn<<<dim3(64, BHn), 256, 0, stream>>>();
        float st = (t + 1) < 6 ? (float)(t + 1) / 6.0f : 1.0f;
        attn_pipeline<<<BHn * Nn, 256, 0, stream>>>(st);
        gemm_pv<<<dim3(8, BHn), 256, 0, stream>>>();
        oif_kernel<<<(int)(BHND / 256), 256, 0, stream>>>();
        gemm_proj_kernel<<<dim3(Cn / 128, BNn / 128), 256, 0, stream>>>(w_proj);
        pif_kernel<<<(int)(BNC / 256), 256, 0, stream>>>(outp + (size_t)t * BNC);
    }
}

// Round 5
// 5466.068 us; speedup vs baseline: 1.0855x; 1.0855x over previous
//
#include <hip/hip_runtime.h>
#include <stdint.h>

typedef __attribute__((ext_vector_type(4))) float f32x4;
typedef __attribute__((ext_vector_type(8))) short s16x8;
typedef unsigned short u16;

constexpr int    Tn  = 8;
constexpr int    Nn  = 512;
constexpr int    Cn  = 768;
constexpr int    Dn  = 64;
constexpr int    BHn = 96;
constexpr int    BNn = 4096;
constexpr int    C3n = 2304;
constexpr size_t BHND = 3145728;     // B*H*N*D
constexpr size_t BHNN = 25165824;    // B*H*N*N
constexpr size_t BNC  = 3145728;     // B*N*C

// ---- all state lives in device globals (zero-init -> NOBITS, no .so bloat) ----
__device__ float  g_qkvt[(size_t)BNn * C3n];
__device__ float  g_qq[BHND];
__device__ float  g_kq[BHND];
__device__ float  g_vq[BHND];
__device__ int8_t g_qa[BHND];
__device__ int8_t g_ka[BHND];
__device__ int8_t g_va[BHND];
__device__ u16    g_A1[BHND * 2];                  // [bh][n][128]
__device__ u16    g_B1[BHND * 2];
__device__ short  g_S16[BHNN];
__device__ short  g_aifq[BHNN];                    // q*8, exact int
__device__ int8_t g_aifa[BHNN];
__device__ int8_t g_smX[BHNN];
__device__ float  g_smY[BHNN];
__device__ float  g_sifq[BHNN];
__device__ int8_t g_sifa[BHNN];
__device__ u16    g_A2[BHNN * 2];                  // [bh*n][1024]
__device__ u16    g_vT[(size_t)BHn * Dn * 1024];   // [bh][d][1024]
__device__ float  g_pv[BHND];
__device__ float  g_oq[BHND];
__device__ int8_t g_oa[BHND];
__device__ float  g_osp[BNC];
__device__ float  g_proj[BNC];
__device__ float  g_pq[BNC];
__device__ int8_t g_pa[BNC];

static __device__ __forceinline__ u16 f2bf(float f) {
    union { float f; unsigned int u; } v; v.f = f;
    return (u16)(v.u >> 16);   // exact for small-integer-valued floats
}

// symmetric IF neuron step (pos_max=7, neg_min=-8)
static __device__ __forceinline__ float if_sym(float x, float& q, int8_t& a8) {
    float q2 = q + x;
    int a = a8;
    bool pos = ((q2 - 1.0f) >= 0.0f) && (a < 7);
    bool neg = (q2 < 0.0f) && (a > -8);
    float out = pos ? 1.0f : (neg ? -1.0f : 0.0f);
    q = q2 - out;
    a8 = (int8_t)(a + (int)out);
    return out;
}

// ---------------- init all persistent states ----------------
__global__ __launch_bounds__(256) void init_states() {
    size_t i0 = (size_t)blockIdx.x * blockDim.x + threadIdx.x;
    size_t stride = (size_t)gridDim.x * blockDim.x;
    for (size_t i = i0; i < BHNN; i += stride) {
        if (i < BHND) {
            g_qq[i] = 0.5f; g_kq[i] = 0.5f; g_vq[i] = 0.5f;
            g_qa[i] = 0; g_ka[i] = 0; g_va[i] = 0;
            g_oq[i] = 0.5f; g_oa[i] = 0;
            g_pq[i] = 0.5f; g_pa[i] = 0;       // BNC == BHND
        }
        g_aifq[i] = 4;       // q=0.5 stored as q*8
        g_aifa[i] = 0;
        g_smX[i]  = 0;
        g_smY[i]  = 0.0f;
        g_sifq[i] = 0.5f;
        g_sifa[i] = 0;
    }
}

// ---------------- fp32 NT GEMM v2: C[m][j] = sum_k A[m][k]*B[j][k] ----------
// Per-output accumulation is ONE fp32 fmaf chain, k strictly ascending ->
// bit-identical to the round-3 bit-exact version. LDS strides padded so every
// access is <=2-way (free). Two concrete kernels (no template, no GGL macro).

// qkv: [4096 x 2304], K=768. Tile 128x96, 8x6/thread, grid 24x32 = 768 blocks.
__global__ __launch_bounds__(256) void gemm_qkv_128x96(
    const float* __restrict__ A, const float* __restrict__ B)
{
    __shared__ __align__(16) float As[16][132];   // 128+4: stride%32 == 4
    __shared__ __align__(16) float Bs[16][100];   // 96+4 : stride%32 == 4
    const int tid = threadIdx.x;
    const int m0 = blockIdx.y * 128;
    const int j0 = blockIdx.x * 96;
    const int ty = tid >> 4, tx = tid & 15;

    float acc[8][6];
#pragma unroll
    for (int i = 0; i < 8; ++i)
#pragma unroll
        for (int j = 0; j < 6; ++j) acc[i][j] = 0.0f;

    for (int k0 = 0; k0 < Cn; k0 += 16) {
#pragma unroll
        for (int u = 0; u < 2; ++u) {
            int f = tid + u * 256;               // 0..511
            int row = f >> 2;                    // 0..127
            int c4 = (f & 3) * 4;                // 0,4,8,12
            float4 av = *(const float4*)(A + (size_t)(m0 + row) * Cn + k0 + c4);
            As[c4 + 0][row] = av.x; As[c4 + 1][row] = av.y;
            As[c4 + 2][row] = av.z; As[c4 + 3][row] = av.w;
        }
#pragma unroll
        for (int u = 0; u < 3; ++u) {
            int f = tid + u * 256;               // 0..767
            int row = f >> 3;                    // 0..95
            int c2 = (f & 7) * 2;                // 0..14
            float2 bv = *(const float2*)(B + (size_t)(j0 + row) * Cn + k0 + c2);
            Bs[c2][row] = bv.x; Bs[c2 + 1][row] = bv.y;
        }
        __syncthreads();
#pragma unroll
        for (int k = 0; k < 16; ++k) {
            alignas(16) float a[8];
            alignas(8)  float b[6];
            *(float4*)(a)     = *(const float4*)&As[k][ty * 8];
            *(float4*)(a + 4) = *(const float4*)&As[k][ty * 8 + 4];
#pragma unroll
            for (int u = 0; u < 3; ++u) {
                float2 t = *(const float2*)&Bs[k][tx * 2 + 32 * u];
                b[2 * u] = t.x; b[2 * u + 1] = t.y;
            }
#pragma unroll
            for (int i = 0; i < 8; ++i)
#pragma unroll
                for (int j = 0; j < 6; ++j)
                    acc[i][j] = fmaf(a[i], b[j], acc[i][j]);
        }
        __syncthreads();
    }
#pragma unroll
    for (int i = 0; i < 8; ++i) {
        float* cp = g_qkvt + (size_t)(m0 + ty * 8 + i) * C3n + j0 + tx * 2;
#pragma unroll
        for (int u = 0; u < 3; ++u) {
            float2 t; t.x = acc[i][2 * u]; t.y = acc[i][2 * u + 1];
            *(float2*)(cp + 32 * u) = t;
        }
    }
}

// proj: [4096 x 768], K=768. Tile 64x96, 4x6/thread, grid 8x64 = 512 blocks.
__global__ __launch_bounds__(256) void gemm_proj_64x96(const float* __restrict__ B)
{
    __shared__ __align__(16) float As[16][68];    // 64+4
    __shared__ __align__(16) float Bs[16][100];
    const int tid = threadIdx.x;
    const int m0 = blockIdx.y * 64;
    const int j0 = blockIdx.x * 96;
    const int ty = tid >> 4, tx = tid & 15;
    const float* A = g_osp;

    float acc[4][6];
#pragma unroll
    for (int i = 0; i < 4; ++i)
#pragma unroll
        for (int j = 0; j < 6; ++j) acc[i][j] = 0.0f;

    for (int k0 = 0; k0 < Cn; k0 += 16) {
        {
            int row = tid >> 2;                  // 0..63
            int c4 = (tid & 3) * 4;
            float4 av = *(const float4*)(A + (size_t)(m0 + row) * Cn + k0 + c4);
            As[c4 + 0][row] = av.x; As[c4 + 1][row] = av.y;
            As[c4 + 2][row] = av.z; As[c4 + 3][row] = av.w;
        }
#pragma unroll
        for (int u = 0; u < 3; ++u) {
            int f = tid + u * 256;
            int row = f >> 3;
            int c2 = (f & 7) * 2;
            float2 bv = *(const float2*)(B + (size_t)(j0 + row) * Cn + k0 + c2);
            Bs[c2][row] = bv.x; Bs[c2 + 1][row] = bv.y;
        }
        __syncthreads();
#pragma unroll
        for (int k = 0; k < 16; ++k) {
            alignas(16) float a[4];
            alignas(8)  float b[6];
            *(float4*)(a) = *(const float4*)&As[k][ty * 4];
#pragma unroll
            for (int u = 0; u < 3; ++u) {
                float2 t = *(const float2*)&Bs[k][tx * 2 + 32 * u];
                b[2 * u] = t.x; b[2 * u + 1] = t.y;
            }
#pragma unroll
            for (int i = 0; i < 4; ++i)
#pragma unroll
                for (int j = 0; j < 6; ++j)
                    acc[i][j] = fmaf(a[i], b[j], acc[i][j]);
        }
        __syncthreads();
    }
#pragma unroll
    for (int i = 0; i < 4; ++i) {
        float* cp = g_proj + (size_t)(m0 + ty * 4 + i) * Cn + j0 + tx * 2;
#pragma unroll
        for (int u = 0; u < 3; ++u) {
            float2 t; t.x = acc[i][2 * u]; t.y = acc[i][2 * u + 1];
            *(float2*)(cp + 32 * u) = t;
        }
    }
}

// ---------------- q/k/v IF step + build bf16 operands ----------------------
__global__ __launch_bounds__(256) void if_qkv() {
    int idx = blockIdx.x * 256 + threadIdx.x;   // [0, BHND)
    int d = idx & 63;
    int n = (idx >> 6) & 511;
    int bh = idx >> 15;
    int b = bh / 12, h = bh - b * 12;
    size_t qrow = ((size_t)(b * Nn + n)) * C3n + h * 64 + d;

    float xq = g_qkvt[qrow];
    float xk = g_qkvt[qrow + 768];
    float xv = g_qkvt[qrow + 1536];

    float fq = g_qq[idx]; int8_t aq = g_qa[idx];
    float so_q = if_sym(xq, fq, aq);
    g_qq[idx] = fq; g_qa[idx] = aq;

    float fk = g_kq[idx]; int8_t ak = g_ka[idx];
    float so_k = if_sym(xk, fk, ak);
    g_kq[idx] = fk; g_ka[idx] = ak;

    float fv = g_vq[idx]; int8_t av = g_va[idx];
    float so_v = if_sym(xv, fv, av);
    g_vq[idx] = fv; g_va[idx] = av;

    // attn operands (K=128): A1 = [acc_q | q_spike], B1 = [k_spike | k_acc-k]
    size_t a1b = ((size_t)bh * Nn + n) * 128 + d;
    g_A1[a1b]      = f2bf((float)aq);
    g_A1[a1b + 64] = f2bf(so_q);
    g_B1[a1b]      = f2bf(so_k);
    g_B1[a1b + 64] = f2bf((float)ak - so_k);

    // PV B operand transposed: vT[bh][d][k]: k<512 v spike, k>=512 v_acc-v
    size_t vtb = ((size_t)bh * Dn + d) * 1024 + n;
    g_vT[vtb]       = f2bf(so_v);
    g_vT[vtb + 512] = f2bf((float)av - so_v);
}

// ---------------- attn logits: S = accq@k^T + q@(kacc-k)^T (exact ints) -----
__global__ __launch_bounds__(256) void gemm_attn() {
    int bh = blockIdx.y;
    int tm = blockIdx.x >> 3, tn = blockIdx.x & 7;
    int wave = threadIdx.x >> 6, lane = threadIdx.x & 63;
    int wr = wave >> 1, wc = wave & 1;
    int row0 = tm * 64 + wr * 32, col0 = tn * 64 + wc * 32;
    const u16* Ab = g_A1 + (size_t)bh * Nn * 128;
    const u16* Bb = g_B1 + (size_t)bh * Nn * 128;
    int lr = lane & 15, kg = (lane >> 4) * 8;
    f32x4 acc[2][2] = {};
#pragma unroll
    for (int kk = 0; kk < 128; kk += 32) {
        s16x8 a0 = *(const s16x8*)&Ab[(row0 + lr) * 128 + kk + kg];
        s16x8 a1 = *(const s16x8*)&Ab[(row0 + 16 + lr) * 128 + kk + kg];
        s16x8 b0 = *(const s16x8*)&Bb[(col0 + lr) * 128 + kk + kg];
        s16x8 b1 = *(const s16x8*)&Bb[(col0 + 16 + lr) * 128 + kk + kg];
        acc[0][0] = __builtin_amdgcn_mfma_f32_16x16x32_bf16(a0, b0, acc[0][0], 0, 0, 0);
        acc[0][1] = __builtin_amdgcn_mfma_f32_16x16x32_bf16(a0, b1, acc[0][1], 0, 0, 0);
        acc[1][0] = __builtin_amdgcn_mfma_f32_16x16x32_bf16(a1, b0, acc[1][0], 0, 0, 0);
        acc[1][1] = __builtin_amdgcn_mfma_f32_16x16x32_bf16(a1, b1, acc[1][1], 0, 0, 0);
    }
    short* Sb = g_S16 + (size_t)bh * Nn * Nn;
#pragma unroll
    for (int i = 0; i < 2; ++i)
#pragma unroll
        for (int j = 0; j < 2; ++j)
#pragma unroll
            for (int q = 0; q < 4; ++q) {
                int row = row0 + i * 16 + (lane >> 4) * 4 + q;
                int col = col0 + j * 16 + lr;
                Sb[row * Nn + col] = (short)(int)acc[i][j][q];
            }
}

// ---------------- aif IF (int) + spiking softmax + sif IF -------------------
// UNTOUCHED from the bit-exact-passing version (reduction order frozen).
__global__ __launch_bounds__(256) void attn_pipeline(float scale_t) {
    size_t base = (size_t)blockIdx.x * Nn;   // row = bh*512 + n
    int tid = threadIdx.x;
    __shared__ int   redI[4];
    __shared__ float redF[4];

    int X[2];
    int myMax = -128;
#pragma unroll
    for (int u = 0; u < 2; ++u) {
        int c = tid + u * 256;
        int s  = g_S16[base + c];
        int q8 = g_aifq[base + c] + s;      // q*8 integer arithmetic, exact
        int a  = g_aifa[base + c];
        bool pos = (q8 >= 8) && (a < 7);
        bool neg = (q8 < 0) && (a > -8);
        int o = pos ? 1 : (neg ? -1 : 0);
        g_aifq[base + c] = (short)(q8 - (o << 3));
        g_aifa[base + c] = (int8_t)(a + o);
        int x = g_smX[base + c] + o;
        g_smX[base + c] = (int8_t)x;
        X[u] = x;
        myMax = max(myMax, x);
    }
    for (int off = 32; off; off >>= 1) myMax = max(myMax, __shfl_xor(myMax, off));
    if ((tid & 63) == 0) redI[tid >> 6] = myMax;
    __syncthreads();
    int M = max(max(redI[0], redI[1]), max(redI[2], redI[3]));

    float e[2];
    float mySum = 0.0f;
#pragma unroll
    for (int u = 0; u < 2; ++u) { e[u] = expf((float)(X[u] - M)); mySum += e[u]; }
    for (int off = 32; off; off >>= 1) mySum += __shfl_xor(mySum, off);
    if ((tid & 63) == 0) redF[tid >> 6] = mySum;
    __syncthreads();
    float Ssum = (redF[0] + redF[1]) + (redF[2] + redF[3]);

#pragma unroll
    for (int u = 0; u < 2; ++u) {
        int c = tid + u * 256;
        float y = (e[u] / Ssum) * scale_t;
        float dlt = y - g_smY[base + c];
        g_smY[base + c] = y;
        float q = g_sifq[base + c] + dlt;
        int a = g_sifa[base + c];
        bool pos = ((q - 1.0f) >= 0.0f) && (a < 7);
        bool neg = (q < 0.0f) && (a > 0);   // neg_min = 0 (unsym)
        float o = pos ? 1.0f : (neg ? -1.0f : 0.0f);
        g_sifq[base + c] = q - o;
        int an = a + (int)o;
        g_sifa[base + c] = (int8_t)an;
        // PV A-operand: [sif_acc | spike], K=1024
        g_A2[base * 2 + c]       = f2bf((float)an);
        g_A2[base * 2 + 512 + c] = f2bf(o);
    }
}

// ---------------- PV: out[n][d] = sum_k A2[n][k]*vT[d][k] (exact ints) ------
__global__ __launch_bounds__(256) void gemm_pv() {
    int bh = blockIdx.y;
    int tm = blockIdx.x;
    int wave = threadIdx.x >> 6, lane = threadIdx.x & 63;
    int wr = wave >> 1, wc = wave & 1;
    int row0 = tm * 64 + wr * 32, col0 = wc * 32;
    const u16* Ab = g_A2 + (size_t)bh * Nn * 1024;
    const u16* Bb = g_vT + (size_t)bh * Dn * 1024;
    int lr = lane & 15, kg = (lane >> 4) * 8;
    f32x4 acc[2][2] = {};
    for (int kk = 0; kk < 1024; kk += 32) {
        s16x8 a0 = *(const s16x8*)&Ab[(row0 + lr) * 1024 + kk + kg];
        s16x8 a1 = *(const s16x8*)&Ab[(row0 + 16 + lr) * 1024 + kk + kg];
        s16x8 b0 = *(const s16x8*)&Bb[(col0 + lr) * 1024 + kk + kg];
        s16x8 b1 = *(const s16x8*)&Bb[(col0 + 16 + lr) * 1024 + kk + kg];
        acc[0][0] = __builtin_amdgcn_mfma_f32_16x16x32_bf16(a0, b0, acc[0][0], 0, 0, 0);
        acc[0][1] = __builtin_amdgcn_mfma_f32_16x16x32_bf16(a0, b1, acc[0][1], 0, 0, 0);
        acc[1][0] = __builtin_amdgcn_mfma_f32_16x16x32_bf16(a1, b0, acc[1][0], 0, 0, 0);
        acc[1][1] = __builtin_amdgcn_mfma_f32_16x16x32_bf16(a1, b1, acc[1][1], 0, 0, 0);
    }
    float* Pb = g_pv + (size_t)bh * Nn * Dn;
#pragma unroll
    for (int i = 0; i < 2; ++i)
#pragma unroll
        for (int j = 0; j < 2; ++j)
#pragma unroll
            for (int q = 0; q < 4; ++q) {
                int row = row0 + i * 16 + (lane >> 4) * 4 + q;
                int col = col0 + j * 16 + lr;
                Pb[row * Dn + col] = acc[i][j][q];
            }
}

// ---------------- oif IF + write proj-input spikes [B,N,C] ------------------
__global__ __launch_bounds__(256) void oif_kernel() {
    int idx = blockIdx.x * 256 + threadIdx.x;
    float x = g_pv[idx];
    float q = g_oq[idx]; int8_t a = g_oa[idx];
    float o = if_sym(x, q, a);
    g_oq[idx] = q; g_oa[idx] = a;
    int d = idx & 63;
    int n = (idx >> 6) & 511;
    int bh = idx >> 15;
    int b = bh / 12, h = bh - b * 12;
    g_osp[((size_t)(b * Nn + n)) * Cn + h * 64 + d] = o;
}

// ---------------- pif IF + write output spikes ------------------------------
__global__ __launch_bounds__(256) void pif_kernel(float* __restrict__ outp) {
    int idx = blockIdx.x * 256 + threadIdx.x;
    float x = g_proj[idx];
    float q = g_pq[idx]; int8_t a = g_pa[idx];
    float o = if_sym(x, q, a);
    g_pq[idx] = q; g_pa[idx] = a;
    outp[idx] = o;
}

extern "C" void kernel_launch(void* const* d_in, const int* in_sizes, int n_in,
                              void* d_out, int out_size, void* d_ws, size_t ws_size,
                              hipStream_t stream) {
    (void)in_sizes; (void)n_in; (void)out_size; (void)d_ws; (void)ws_size;
    const float* x      = (const float*)d_in[0];
    const float* w_qkv  = (const float*)d_in[1];
    const float* w_proj = (const float*)d_in[2];
    float* outp = (float*)d_out;

    init_states<<<2048, 256, 0, stream>>>();

    for (int t = 0; t < Tn; ++t) {
        const float* xt = x + (size_t)t * BNC;
        // qkv = x_t @ w_qkv^T  [4096 x 2304], K=768: tile 128x96, 768 blocks
        gemm_qkv_128x96<<<dim3(C3n / 96, BNn / 128), 256, 0, stream>>>(xt, w_qkv);
        if_qkv<<<(int)(BHND / 256), 256, 0, stream>>>();
        gemm_attn<<<dim3(64, BHn), 256, 0, stream>>>();
        float st = (t + 1) < 6 ? (float)(t + 1) / 6.0f : 1.0f;
        attn_pipeline<<<BHn * Nn, 256, 0, stream>>>(st);
        gemm_pv<<<dim3(8, BHn), 256, 0, stream>>>();
        oif_kernel<<<(int)(BHND / 256), 256, 0, stream>>>();
        // proj = ospike @ w_proj^T  [4096 x 768], K=768: tile 64x96, 512 blocks
        gemm_proj_64x96<<<dim3(Cn / 96, BNn / 64), 256, 0, stream>>>(w_proj);
        pif_kernel<<<(int)(BNC / 256), 256, 0, stream>>>(outp + (size_t)t * BNC);
    }
}

// Round 6
// 5102.890 us; speedup vs baseline: 1.1627x; 1.0712x over previous
//
#include <hip/hip_runtime.h>
#include <stdint.h>

typedef __attribute__((ext_vector_type(4))) float f32x4;
typedef __attribute__((ext_vector_type(8))) short s16x8;
typedef __attribute__((ext_vector_type(8))) char  s8x8;
typedef unsigned short u16;

constexpr int    Tn  = 8;
constexpr int    Nn  = 512;
constexpr int    Cn  = 768;
constexpr int    Dn  = 64;
constexpr int    BHn = 96;
constexpr int    BNn = 4096;
constexpr int    C3n = 2304;
constexpr size_t BHND = 3145728;     // B*H*N*D
constexpr size_t BHNN = 25165824;    // B*H*N*N
constexpr size_t BNC  = 3145728;     // B*N*C

// ---- all state lives in device globals (zero-init -> NOBITS) ----
__device__ float  g_qkvt[(size_t)BNn * C3n];
__device__ float  g_qq[BHND];
__device__ float  g_kq[BHND];
__device__ float  g_vq[BHND];
__device__ int8_t g_qa[BHND];
__device__ int8_t g_ka[BHND];
__device__ int8_t g_va[BHND];
__device__ u16    g_A1[BHND * 2];                  // [bh][n][128]
__device__ u16    g_B1[BHND * 2];
__device__ short  g_S16[BHNN];
__device__ short  g_aifq[BHNN];                    // q*8, exact int (also == smX state via aifa)
__device__ int8_t g_aifa[BHNN];                    // == smX (proven identical)
__device__ float  g_smY[BHNN];
__device__ float  g_sifq[BHNN];
__device__ int8_t g_sifa[BHNN];
__device__ u16    g_spk[BHNN];                     // sif spike (bf16), PV A-operand upper half
__device__ u16    g_vT[(size_t)BHn * Dn * 1024];   // [bh][d][1024]
__device__ float  g_pv[BHND];
__device__ float  g_oq[BHND];
__device__ int8_t g_oa[BHND];
__device__ float  g_osp[BNC];
__device__ float  g_proj[BNC];
__device__ float  g_pq[BNC];
__device__ int8_t g_pa[BNC];

static __device__ __forceinline__ u16 f2bf(float f) {
    union { float f; unsigned int u; } v; v.f = f;
    return (u16)(v.u >> 16);   // exact for small-integer-valued floats
}

static __device__ __forceinline__ s16x8 cvt_i8_bf16x8(const int8_t* p) {
    s8x8 v = *(const s8x8*)p;
    s16x8 r;
#pragma unroll
    for (int j = 0; j < 8; ++j) r[j] = (short)f2bf((float)v[j]);
    return r;
}

// symmetric IF neuron step (pos_max=7, neg_min=-8)
static __device__ __forceinline__ float if_sym(float x, float& q, int8_t& a8) {
    float q2 = q + x;
    int a = a8;
    bool pos = ((q2 - 1.0f) >= 0.0f) && (a < 7);
    bool neg = (q2 < 0.0f) && (a > -8);
    float out = pos ? 1.0f : (neg ? -1.0f : 0.0f);
    q = q2 - out;
    a8 = (int8_t)(a + (int)out);
    return out;
}

// ---------------- init all persistent states ----------------
__global__ __launch_bounds__(256) void init_states() {
    size_t i0 = (size_t)blockIdx.x * blockDim.x + threadIdx.x;
    size_t stride = (size_t)gridDim.x * blockDim.x;
    for (size_t i = i0; i < BHNN; i += stride) {
        if (i < BHND) {
            g_qq[i] = 0.5f; g_kq[i] = 0.5f; g_vq[i] = 0.5f;
            g_qa[i] = 0; g_ka[i] = 0; g_va[i] = 0;
            g_oq[i] = 0.5f; g_oa[i] = 0;
            g_pq[i] = 0.5f; g_pa[i] = 0;       // BNC == BHND
        }
        g_aifq[i] = 4;       // q=0.5 stored as q*8
        g_aifa[i] = 0;
        g_smY[i]  = 0.0f;
        g_sifq[i] = 0.5f;
        g_sifa[i] = 0;
    }
}

// ---------------- fp32 NT GEMMs: C[m][j] = sum_k A[m][k]*B[j][k] ------------
// ONE fp32 fmaf chain per output, k strictly ascending -> bit-identical to the
// round-3/5 bit-exact versions. Register-staged prefetch: next chunk's global
// loads issued before the compute loop so HBM latency hides under the FMAs.

// qkv: [4096 x 2304], K=768. Tile 128x96, 8x6/thread, grid 24x32 = 768 blocks.
__global__ __launch_bounds__(256) void gemm_qkv_128x96(
    const float* __restrict__ A, const float* __restrict__ B)
{
    __shared__ __align__(16) float As[16][132];   // 128+4: stride%32 == 4
    __shared__ __align__(16) float Bs[16][100];   // 96+4 : stride%32 == 4
    const int tid = threadIdx.x;
    const int m0 = blockIdx.y * 128;
    const int j0 = blockIdx.x * 96;
    const int ty = tid >> 4, tx = tid & 15;

    const int arow0 = tid >> 2,        ac4 = (tid & 3) * 4;       // A slot 0
    const int arow1 = (tid + 256) >> 2, dummy = 0; (void)dummy;   // A slot 1
    float acc[8][6];
#pragma unroll
    for (int i = 0; i < 8; ++i)
#pragma unroll
        for (int j = 0; j < 6; ++j) acc[i][j] = 0.0f;

    float4 pa[2];
    float2 pb[3];

    auto load_chunk = [&](int k0) {
#pragma unroll
        for (int u = 0; u < 2; ++u) {
            int f = tid + u * 256;
            int row = f >> 2;
            int c4 = (f & 3) * 4;
            pa[u] = *(const float4*)(A + (size_t)(m0 + row) * Cn + k0 + c4);
        }
#pragma unroll
        for (int u = 0; u < 3; ++u) {
            int f = tid + u * 256;
            int row = f >> 3;
            int c2 = (f & 7) * 2;
            pb[u] = *(const float2*)(B + (size_t)(j0 + row) * Cn + k0 + c2);
        }
    };
    auto store_chunk = [&]() {
#pragma unroll
        for (int u = 0; u < 2; ++u) {
            int f = tid + u * 256;
            int row = f >> 2;
            int c4 = (f & 3) * 4;
            As[c4 + 0][row] = pa[u].x; As[c4 + 1][row] = pa[u].y;
            As[c4 + 2][row] = pa[u].z; As[c4 + 3][row] = pa[u].w;
        }
#pragma unroll
        for (int u = 0; u < 3; ++u) {
            int f = tid + u * 256;
            int row = f >> 3;
            int c2 = (f & 7) * 2;
            Bs[c2][row] = pb[u].x; Bs[c2 + 1][row] = pb[u].y;
        }
    };
    auto compute_chunk = [&]() {
#pragma unroll
        for (int k = 0; k < 16; ++k) {
            alignas(16) float a[8];
            alignas(8)  float b[6];
            *(float4*)(a)     = *(const float4*)&As[k][ty * 8];
            *(float4*)(a + 4) = *(const float4*)&As[k][ty * 8 + 4];
#pragma unroll
            for (int u = 0; u < 3; ++u) {
                float2 t = *(const float2*)&Bs[k][tx * 2 + 32 * u];
                b[2 * u] = t.x; b[2 * u + 1] = t.y;
            }
#pragma unroll
            for (int i = 0; i < 8; ++i)
#pragma unroll
                for (int j = 0; j < 6; ++j)
                    acc[i][j] = fmaf(a[i], b[j], acc[i][j]);
        }
    };

    load_chunk(0);
    store_chunk();
    for (int k0 = 16; k0 < Cn; k0 += 16) {
        __syncthreads();
        load_chunk(k0);          // in flight during compute
        compute_chunk();
        __syncthreads();
        store_chunk();
    }
    __syncthreads();
    compute_chunk();

#pragma unroll
    for (int i = 0; i < 8; ++i) {
        float* cp = g_qkvt + (size_t)(m0 + ty * 8 + i) * C3n + j0 + tx * 2;
#pragma unroll
        for (int u = 0; u < 3; ++u) {
            float2 t; t.x = acc[i][2 * u]; t.y = acc[i][2 * u + 1];
            *(float2*)(cp + 32 * u) = t;
        }
    }
}

// proj: [4096 x 768], K=768. Tile 64x96, 4x6/thread, grid 8x64 = 512 blocks.
__global__ __launch_bounds__(256) void gemm_proj_64x96(const float* __restrict__ B)
{
    __shared__ __align__(16) float As[16][68];    // 64+4
    __shared__ __align__(16) float Bs[16][100];
    const int tid = threadIdx.x;
    const int m0 = blockIdx.y * 64;
    const int j0 = blockIdx.x * 96;
    const int ty = tid >> 4, tx = tid & 15;
    const float* A = g_osp;

    float acc[4][6];
#pragma unroll
    for (int i = 0; i < 4; ++i)
#pragma unroll
        for (int j = 0; j < 6; ++j) acc[i][j] = 0.0f;

    float4 pa0;
    float2 pb[3];

    auto load_chunk = [&](int k0) {
        int row = tid >> 2;
        int c4 = (tid & 3) * 4;
        pa0 = *(const float4*)(A + (size_t)(m0 + row) * Cn + k0 + c4);
#pragma unroll
        for (int u = 0; u < 3; ++u) {
            int f = tid + u * 256;
            int r2 = f >> 3;
            int c2 = (f & 7) * 2;
            pb[u] = *(const float2*)(B + (size_t)(j0 + r2) * Cn + k0 + c2);
        }
    };
    auto store_chunk = [&]() {
        int row = tid >> 2;
        int c4 = (tid & 3) * 4;
        As[c4 + 0][row] = pa0.x; As[c4 + 1][row] = pa0.y;
        As[c4 + 2][row] = pa0.z; As[c4 + 3][row] = pa0.w;
#pragma unroll
        for (int u = 0; u < 3; ++u) {
            int f = tid + u * 256;
            int r2 = f >> 3;
            int c2 = (f & 7) * 2;
            Bs[c2][r2] = pb[u].x; Bs[c2 + 1][r2] = pb[u].y;
        }
    };
    auto compute_chunk = [&]() {
#pragma unroll
        for (int k = 0; k < 16; ++k) {
            alignas(16) float a[4];
            alignas(8)  float b[6];
            *(float4*)(a) = *(const float4*)&As[k][ty * 4];
#pragma unroll
            for (int u = 0; u < 3; ++u) {
                float2 t = *(const float2*)&Bs[k][tx * 2 + 32 * u];
                b[2 * u] = t.x; b[2 * u + 1] = t.y;
            }
#pragma unroll
            for (int i = 0; i < 4; ++i)
#pragma unroll
                for (int j = 0; j < 6; ++j)
                    acc[i][j] = fmaf(a[i], b[j], acc[i][j]);
        }
    };

    load_chunk(0);
    store_chunk();
    for (int k0 = 16; k0 < Cn; k0 += 16) {
        __syncthreads();
        load_chunk(k0);
        compute_chunk();
        __syncthreads();
        store_chunk();
    }
    __syncthreads();
    compute_chunk();

#pragma unroll
    for (int i = 0; i < 4; ++i) {
        float* cp = g_proj + (size_t)(m0 + ty * 4 + i) * Cn + j0 + tx * 2;
#pragma unroll
        for (int u = 0; u < 3; ++u) {
            float2 t; t.x = acc[i][2 * u]; t.y = acc[i][2 * u + 1];
            *(float2*)(cp + 32 * u) = t;
        }
    }
}

// ---------------- q/k/v IF step + build bf16 operands ----------------------
__global__ __launch_bounds__(256) void if_qkv() {
    int idx = blockIdx.x * 256 + threadIdx.x;   // [0, BHND)
    int d = idx & 63;
    int n = (idx >> 6) & 511;
    int bh = idx >> 15;
    int b = bh / 12, h = bh - b * 12;
    size_t qrow = ((size_t)(b * Nn + n)) * C3n + h * 64 + d;

    float xq = g_qkvt[qrow];
    float xk = g_qkvt[qrow + 768];
    float xv = g_qkvt[qrow + 1536];

    float fq = g_qq[idx]; int8_t aq = g_qa[idx];
    float so_q = if_sym(xq, fq, aq);
    g_qq[idx] = fq; g_qa[idx] = aq;

    float fk = g_kq[idx]; int8_t ak = g_ka[idx];
    float so_k = if_sym(xk, fk, ak);
    g_kq[idx] = fk; g_ka[idx] = ak;

    float fv = g_vq[idx]; int8_t av = g_va[idx];
    float so_v = if_sym(xv, fv, av);
    g_vq[idx] = fv; g_va[idx] = av;

    // attn operands (K=128): A1 = [acc_q | q_spike], B1 = [k_spike | k_acc-k]
    size_t a1b = ((size_t)bh * Nn + n) * 128 + d;
    g_A1[a1b]      = f2bf((float)aq);
    g_A1[a1b + 64] = f2bf(so_q);
    g_B1[a1b]      = f2bf(so_k);
    g_B1[a1b + 64] = f2bf((float)ak - so_k);

    // PV B operand transposed: vT[bh][d][k]: k<512 v spike, k>=512 v_acc-v
    size_t vtb = ((size_t)bh * Dn + d) * 1024 + n;
    g_vT[vtb]       = f2bf(so_v);
    g_vT[vtb + 512] = f2bf((float)av - so_v);
}

// ---------------- attn logits: S = accq@k^T + q@(kacc-k)^T (exact ints) -----
__global__ __launch_bounds__(256) void gemm_attn() {
    int bh = blockIdx.y;
    int tm = blockIdx.x >> 3, tn = blockIdx.x & 7;
    int wave = threadIdx.x >> 6, lane = threadIdx.x & 63;
    int wr = wave >> 1, wc = wave & 1;
    int row0 = tm * 64 + wr * 32, col0 = tn * 64 + wc * 32;
    const u16* Ab = g_A1 + (size_t)bh * Nn * 128;
    const u16* Bb = g_B1 + (size_t)bh * Nn * 128;
    int lr = lane & 15, kg = (lane >> 4) * 8;
    f32x4 acc[2][2] = {};
#pragma unroll
    for (int kk = 0; kk < 128; kk += 32) {
        s16x8 a0 = *(const s16x8*)&Ab[(row0 + lr) * 128 + kk + kg];
        s16x8 a1 = *(const s16x8*)&Ab[(row0 + 16 + lr) * 128 + kk + kg];
        s16x8 b0 = *(const s16x8*)&Bb[(col0 + lr) * 128 + kk + kg];
        s16x8 b1 = *(const s16x8*)&Bb[(col0 + 16 + lr) * 128 + kk + kg];
        acc[0][0] = __builtin_amdgcn_mfma_f32_16x16x32_bf16(a0, b0, acc[0][0], 0, 0, 0);
        acc[0][1] = __builtin_amdgcn_mfma_f32_16x16x32_bf16(a0, b1, acc[0][1], 0, 0, 0);
        acc[1][0] = __builtin_amdgcn_mfma_f32_16x16x32_bf16(a1, b0, acc[1][0], 0, 0, 0);
        acc[1][1] = __builtin_amdgcn_mfma_f32_16x16x32_bf16(a1, b1, acc[1][1], 0, 0, 0);
    }
    short* Sb = g_S16 + (size_t)bh * Nn * Nn;
#pragma unroll
    for (int i = 0; i < 2; ++i)
#pragma unroll
        for (int j = 0; j < 2; ++j)
#pragma unroll
            for (int q = 0; q < 4; ++q) {
                int row = row0 + i * 16 + (lane >> 4) * 4 + q;
                int col = col0 + j * 16 + lr;
                Sb[row * Nn + col] = (short)(int)acc[i][j][q];
            }
}

// ---------------- aif IF (int) + spiking softmax + sif IF -------------------
// smX removed: smX == aifa exactly (both accumulate the same integer spike o).
__global__ __launch_bounds__(256) void attn_pipeline(float scale_t) {
    size_t base = (size_t)blockIdx.x * Nn;   // row = bh*512 + n
    int tid = threadIdx.x;
    __shared__ int   redI[4];
    __shared__ float redF[4];

    int X[2];
    int myMax = -128;
#pragma unroll
    for (int u = 0; u < 2; ++u) {
        int c = tid + u * 256;
        int s  = g_S16[base + c];
        int q8 = g_aifq[base + c] + s;      // q*8 integer arithmetic, exact
        int a  = g_aifa[base + c];
        bool pos = (q8 >= 8) && (a < 7);
        bool neg = (q8 < 0) && (a > -8);
        int o = pos ? 1 : (neg ? -1 : 0);
        g_aifq[base + c] = (short)(q8 - (o << 3));
        a += o;
        g_aifa[base + c] = (int8_t)a;
        X[u] = a;                            // == smX_new (exact identity)
        myMax = max(myMax, a);
    }
    for (int off = 32; off; off >>= 1) myMax = max(myMax, __shfl_xor(myMax, off));
    if ((tid & 63) == 0) redI[tid >> 6] = myMax;
    __syncthreads();
    int M = max(max(redI[0], redI[1]), max(redI[2], redI[3]));

    float e[2];
    float mySum = 0.0f;
#pragma unroll
    for (int u = 0; u < 2; ++u) { e[u] = expf((float)(X[u] - M)); mySum += e[u]; }
    for (int off = 32; off; off >>= 1) mySum += __shfl_xor(mySum, off);
    if ((tid & 63) == 0) redF[tid >> 6] = mySum;
    __syncthreads();
    float Ssum = (redF[0] + redF[1]) + (redF[2] + redF[3]);

#pragma unroll
    for (int u = 0; u < 2; ++u) {
        int c = tid + u * 256;
        float y = (e[u] / Ssum) * scale_t;
        float dlt = y - g_smY[base + c];
        g_smY[base + c] = y;
        float q = g_sifq[base + c] + dlt;
        int a = g_sifa[base + c];
        bool pos = ((q - 1.0f) >= 0.0f) && (a < 7);
        bool neg = (q < 0.0f) && (a > 0);   // neg_min = 0 (unsym)
        float o = pos ? 1.0f : (neg ? -1.0f : 0.0f);
        g_sifq[base + c] = q - o;
        g_sifa[base + c] = (int8_t)(a + (int)o);
        g_spk[base + c]  = f2bf(o);          // PV spike operand (acc half == sifa)
    }
}

// ---------------- PV: out[n][d] = sifa@v + spk@(vacc-v) (exact ints) --------
__global__ __launch_bounds__(256) void gemm_pv() {
    int bh = blockIdx.y;
    int tm = blockIdx.x;
    int wave = threadIdx.x >> 6, lane = threadIdx.x & 63;
    int wr = wave >> 1, wc = wave & 1;
    int row0 = tm * 64 + wr * 32, col0 = wc * 32;
    const int8_t* Aa  = g_sifa + (size_t)bh * Nn * Nn;   // [n][512] int8
    const u16*    Asp = g_spk  + (size_t)bh * Nn * Nn;   // [n][512] bf16
    const u16*    Bb  = g_vT   + (size_t)bh * Dn * 1024; // [d][1024]
    int lr = lane & 15, kg = (lane >> 4) * 8;
    f32x4 acc[2][2] = {};
    for (int kk = 0; kk < 512; kk += 32) {
        s16x8 a0 = cvt_i8_bf16x8(Aa + (size_t)(row0 + lr) * 512 + kk + kg);
        s16x8 a1 = cvt_i8_bf16x8(Aa + (size_t)(row0 + 16 + lr) * 512 + kk + kg);
        s16x8 b0 = *(const s16x8*)&Bb[(col0 + lr) * 1024 + kk + kg];
        s16x8 b1 = *(const s16x8*)&Bb[(col0 + 16 + lr) * 1024 + kk + kg];
        acc[0][0] = __builtin_amdgcn_mfma_f32_16x16x32_bf16(a0, b0, acc[0][0], 0, 0, 0);
        acc[0][1] = __builtin_amdgcn_mfma_f32_16x16x32_bf16(a0, b1, acc[0][1], 0, 0, 0);
        acc[1][0] = __builtin_amdgcn_mfma_f32_16x16x32_bf16(a1, b0, acc[1][0], 0, 0, 0);
        acc[1][1] = __builtin_amdgcn_mfma_f32_16x16x32_bf16(a1, b1, acc[1][1], 0, 0, 0);
    }
    for (int kk = 0; kk < 512; kk += 32) {
        s16x8 a0 = *(const s16x8*)&Asp[(size_t)(row0 + lr) * 512 + kk + kg];
        s16x8 a1 = *(const s16x8*)&Asp[(size_t)(row0 + 16 + lr) * 512 + kk + kg];
        s16x8 b0 = *(const s16x8*)&Bb[(col0 + lr) * 1024 + 512 + kk + kg];
        s16x8 b1 = *(const s16x8*)&Bb[(col0 + 16 + lr) * 1024 + 512 + kk + kg];
        acc[0][0] = __builtin_amdgcn_mfma_f32_16x16x32_bf16(a0, b0, acc[0][0], 0, 0, 0);
        acc[0][1] = __builtin_amdgcn_mfma_f32_16x16x32_bf16(a0, b1, acc[0][1], 0, 0, 0);
        acc[1][0] = __builtin_amdgcn_mfma_f32_16x16x32_bf16(a1, b0, acc[1][0], 0, 0, 0);
        acc[1][1] = __builtin_amdgcn_mfma_f32_16x16x32_bf16(a1, b1, acc[1][1], 0, 0, 0);
    }
    float* Pb = g_pv + (size_t)bh * Nn * Dn;
#pragma unroll
    for (int i = 0; i < 2; ++i)
#pragma unroll
        for (int j = 0; j < 2; ++j)
#pragma unroll
            for (int q = 0; q < 4; ++q) {
                int row = row0 + i * 16 + (lane >> 4) * 4 + q;
                int col = col0 + j * 16 + lr;
                Pb[row * Dn + col] = acc[i][j][q];
            }
}

// ---------------- oif IF + write proj-input spikes [B,N,C] ------------------
__global__ __launch_bounds__(256) void oif_kernel() {
    int idx = blockIdx.x * 256 + threadIdx.x;
    float x = g_pv[idx];
    float q = g_oq[idx]; int8_t a = g_oa[idx];
    float o = if_sym(x, q, a);
    g_oq[idx] = q; g_oa[idx] = a;
    int d = idx & 63;
    int n = (idx >> 6) & 511;
    int bh = idx >> 15;
    int b = bh / 12, h = bh - b * 12;
    g_osp[((size_t)(b * Nn + n)) * Cn + h * 64 + d] = o;
}

// ---------------- pif IF + write output spikes ------------------------------
__global__ __launch_bounds__(256) void pif_kernel(float* __restrict__ outp) {
    int idx = blockIdx.x * 256 + threadIdx.x;
    float x = g_proj[idx];
    float q = g_pq[idx]; int8_t a = g_pa[idx];
    float o = if_sym(x, q, a);
    g_pq[idx] = q; g_pa[idx] = a;
    outp[idx] = o;
}

extern "C" void kernel_launch(void* const* d_in, const int* in_sizes, int n_in,
                              void* d_out, int out_size, void* d_ws, size_t ws_size,
                              hipStream_t stream) {
    (void)in_sizes; (void)n_in; (void)out_size; (void)d_ws; (void)ws_size;
    const float* x      = (const float*)d_in[0];
    const float* w_qkv  = (const float*)d_in[1];
    const float* w_proj = (const float*)d_in[2];
    float* outp = (float*)d_out;

    init_states<<<2048, 256, 0, stream>>>();

    for (int t = 0; t < Tn; ++t) {
        const float* xt = x + (size_t)t * BNC;
        // qkv = x_t @ w_qkv^T  [4096 x 2304], K=768: tile 128x96, 768 blocks
        gemm_qkv_128x96<<<dim3(C3n / 96, BNn / 128), 256, 0, stream>>>(xt, w_qkv);
        if_qkv<<<(int)(BHND / 256), 256, 0, stream>>>();
        gemm_attn<<<dim3(64, BHn), 256, 0, stream>>>();
        float st = (t + 1) < 6 ? (float)(t + 1) / 6.0f : 1.0f;
        attn_pipeline<<<BHn * Nn, 256, 0, stream>>>(st);
        gemm_pv<<<dim3(8, BHn), 256, 0, stream>>>();
        oif_kernel<<<(int)(BHND / 256), 256, 0, stream>>>();
        // proj = ospike @ w_proj^T  [4096 x 768], K=768: tile 64x96, 512 blocks
        gemm_proj_64x96<<<dim3(Cn / 96, BNn / 64), 256, 0, stream>>>(w_proj);
        pif_kernel<<<(int)(BNC / 256), 256, 0, stream>>>(outp + (size_t)t * BNC);
    }
}

// Round 7
// 5005.821 us; speedup vs baseline: 1.1853x; 1.0194x over previous
//
#include <hip/hip_runtime.h>
#include <stdint.h>

typedef __attribute__((ext_vector_type(4))) float f32x4;
typedef __attribute__((ext_vector_type(8))) short s16x8;
typedef __attribute__((ext_vector_type(8))) char  s8x8;
typedef unsigned short u16;

constexpr int    Tn  = 8;
constexpr int    Nn  = 512;
constexpr int    Cn  = 768;
constexpr int    Dn  = 64;
constexpr int    BHn = 96;
constexpr int    BNn = 4096;
constexpr int    C3n = 2304;
constexpr size_t BHND = 3145728;     // B*H*N*D
constexpr size_t BHNN = 25165824;    // B*H*N*N
constexpr size_t BNC  = 3145728;     // B*N*C

// ---- all state lives in device globals (zero-init -> NOBITS) ----
__device__ float  g_qkvt[(size_t)BNn * C3n];
__device__ float  g_qq[BHND];
__device__ float  g_kq[BHND];
__device__ float  g_vq[BHND];
__device__ int8_t g_qa[BHND];
__device__ int8_t g_ka[BHND];
__device__ int8_t g_va[BHND];
__device__ u16    g_A1[BHND * 2];                  // [bh][n][128]
__device__ u16    g_B1[BHND * 2];
__device__ short  g_S16[BHNN];
__device__ short  g_aifq[BHNN];                    // q*8, exact int
__device__ int8_t g_aifa[BHNN];                    // == smX (proven identical)
__device__ float  g_smY[BHNN];
__device__ float  g_sifq[BHNN];
__device__ int8_t g_sifa[BHNN];
__device__ u16    g_spk[BHNN];                     // sif spike (bf16), PV A upper half
__device__ u16    g_vT[(size_t)BHn * Dn * 1024];   // [bh][d][1024]
__device__ float  g_pv[BHND];
__device__ float  g_oq[BHND];
__device__ int8_t g_oa[BHND];
__device__ float  g_osp[BNC];
__device__ float  g_proj[BNC];
__device__ float  g_pq[BNC];
__device__ int8_t g_pa[BNC];

static __device__ __forceinline__ u16 f2bf(float f) {
    union { float f; unsigned int u; } v; v.f = f;
    return (u16)(v.u >> 16);   // exact for small-integer-valued floats
}

static __device__ __forceinline__ s16x8 cvt_i8_bf16x8(const int8_t* p) {
    s8x8 v = *(const s8x8*)p;
    s16x8 r;
#pragma unroll
    for (int j = 0; j < 8; ++j) r[j] = (short)f2bf((float)v[j]);
    return r;
}

// symmetric IF neuron step (pos_max=7, neg_min=-8)
static __device__ __forceinline__ float if_sym(float x, float& q, int8_t& a8) {
    float q2 = q + x;
    int a = a8;
    bool pos = ((q2 - 1.0f) >= 0.0f) && (a < 7);
    bool neg = (q2 < 0.0f) && (a > -8);
    float out = pos ? 1.0f : (neg ? -1.0f : 0.0f);
    q = q2 - out;
    a8 = (int8_t)(a + (int)out);
    return out;
}

// ---------------- init all persistent states ----------------
__global__ __launch_bounds__(256) void init_states() {
    size_t i0 = (size_t)blockIdx.x * blockDim.x + threadIdx.x;
    size_t stride = (size_t)gridDim.x * blockDim.x;
    for (size_t i = i0; i < BHNN; i += stride) {
        if (i < BHND) {
            g_qq[i] = 0.5f; g_kq[i] = 0.5f; g_vq[i] = 0.5f;
            g_qa[i] = 0; g_ka[i] = 0; g_va[i] = 0;
            g_oq[i] = 0.5f; g_oa[i] = 0;
            g_pq[i] = 0.5f; g_pa[i] = 0;       // BNC == BHND
        }
        g_aifq[i] = 4;       // q=0.5 stored as q*8
        g_aifa[i] = 0;
        g_smY[i]  = 0.0f;
        g_sifq[i] = 0.5f;
        g_sifa[i] = 0;
    }
}

// ---------------- fp32 NT GEMMs: C[m][j] = sum_k A[m][k]*B[j][k] ------------
// ONE fp32 fmaf chain per output, k strictly ascending -> bit-identical.
// Double-buffered LDS, ONE barrier per 16-k chunk: load(next)->regs,
// compute(cur), store regs->buf(cur^1), barrier.

// qkv: [4096 x 2304], K=768. Tile 128x96, 8x6/thread, grid 24x32 = 768 blocks.
__global__ __launch_bounds__(256) void gemm_qkv_128x96(
    const float* __restrict__ A, const float* __restrict__ B)
{
    __shared__ __align__(16) float As[2][16][132];   // 128+4: stride%32 == 4
    __shared__ __align__(16) float Bs[2][16][100];   // 96+4 : stride%32 == 4
    const int tid = threadIdx.x;
    const int m0 = blockIdx.y * 128;
    const int j0 = blockIdx.x * 96;
    const int ty = tid >> 4, tx = tid & 15;

    float acc[8][6];
#pragma unroll
    for (int i = 0; i < 8; ++i)
#pragma unroll
        for (int j = 0; j < 6; ++j) acc[i][j] = 0.0f;

    float4 pa[2];
    float2 pb[3];

    auto load_chunk = [&](int k0) {
#pragma unroll
        for (int u = 0; u < 2; ++u) {
            int f = tid + u * 256;
            int row = f >> 2;
            int c4 = (f & 3) * 4;
            pa[u] = *(const float4*)(A + (size_t)(m0 + row) * Cn + k0 + c4);
        }
#pragma unroll
        for (int u = 0; u < 3; ++u) {
            int f = tid + u * 256;
            int row = f >> 3;
            int c2 = (f & 7) * 2;
            pb[u] = *(const float2*)(B + (size_t)(j0 + row) * Cn + k0 + c2);
        }
    };
    auto store_chunk = [&](int buf) {
#pragma unroll
        for (int u = 0; u < 2; ++u) {
            int f = tid + u * 256;
            int row = f >> 2;
            int c4 = (f & 3) * 4;
            As[buf][c4 + 0][row] = pa[u].x; As[buf][c4 + 1][row] = pa[u].y;
            As[buf][c4 + 2][row] = pa[u].z; As[buf][c4 + 3][row] = pa[u].w;
        }
#pragma unroll
        for (int u = 0; u < 3; ++u) {
            int f = tid + u * 256;
            int row = f >> 3;
            int c2 = (f & 7) * 2;
            Bs[buf][c2][row] = pb[u].x; Bs[buf][c2 + 1][row] = pb[u].y;
        }
    };
    auto compute_chunk = [&](int buf) {
#pragma unroll
        for (int k = 0; k < 16; ++k) {
            alignas(16) float a[8];
            alignas(8)  float b[6];
            *(float4*)(a)     = *(const float4*)&As[buf][k][ty * 8];
            *(float4*)(a + 4) = *(const float4*)&As[buf][k][ty * 8 + 4];
#pragma unroll
            for (int u = 0; u < 3; ++u) {
                float2 t = *(const float2*)&Bs[buf][k][tx * 2 + 32 * u];
                b[2 * u] = t.x; b[2 * u + 1] = t.y;
            }
#pragma unroll
            for (int i = 0; i < 8; ++i)
#pragma unroll
                for (int j = 0; j < 6; ++j)
                    acc[i][j] = fmaf(a[i], b[j], acc[i][j]);
        }
    };

    load_chunk(0);
    store_chunk(0);
    __syncthreads();
    int cur = 0;
    for (int k0 = 16; k0 < Cn; k0 += 16) {
        load_chunk(k0);          // global loads in flight during compute
        compute_chunk(cur);
        store_chunk(cur ^ 1);    // other buffer: no pre-store barrier needed
        __syncthreads();
        cur ^= 1;
    }
    compute_chunk(cur);

#pragma unroll
    for (int i = 0; i < 8; ++i) {
        float* cp = g_qkvt + (size_t)(m0 + ty * 8 + i) * C3n + j0 + tx * 2;
#pragma unroll
        for (int u = 0; u < 3; ++u) {
            float2 t; t.x = acc[i][2 * u]; t.y = acc[i][2 * u + 1];
            *(float2*)(cp + 32 * u) = t;
        }
    }
}

// proj: [4096 x 768], K=768. Tile 64x96, 4x6/thread, grid 8x64 = 512 blocks.
__global__ __launch_bounds__(256) void gemm_proj_64x96(const float* __restrict__ B)
{
    __shared__ __align__(16) float As[2][16][68];    // 64+4
    __shared__ __align__(16) float Bs[2][16][100];
    const int tid = threadIdx.x;
    const int m0 = blockIdx.y * 64;
    const int j0 = blockIdx.x * 96;
    const int ty = tid >> 4, tx = tid & 15;
    const float* A = g_osp;

    float acc[4][6];
#pragma unroll
    for (int i = 0; i < 4; ++i)
#pragma unroll
        for (int j = 0; j < 6; ++j) acc[i][j] = 0.0f;

    float4 pa0;
    float2 pb[3];

    auto load_chunk = [&](int k0) {
        int row = tid >> 2;
        int c4 = (tid & 3) * 4;
        pa0 = *(const float4*)(A + (size_t)(m0 + row) * Cn + k0 + c4);
#pragma unroll
        for (int u = 0; u < 3; ++u) {
            int f = tid + u * 256;
            int r2 = f >> 3;
            int c2 = (f & 7) * 2;
            pb[u] = *(const float2*)(B + (size_t)(j0 + r2) * Cn + k0 + c2);
        }
    };
    auto store_chunk = [&](int buf) {
        int row = tid >> 2;
        int c4 = (tid & 3) * 4;
        As[buf][c4 + 0][row] = pa0.x; As[buf][c4 + 1][row] = pa0.y;
        As[buf][c4 + 2][row] = pa0.z; As[buf][c4 + 3][row] = pa0.w;
#pragma unroll
        for (int u = 0; u < 3; ++u) {
            int f = tid + u * 256;
            int r2 = f >> 3;
            int c2 = (f & 7) * 2;
            Bs[buf][c2][r2] = pb[u].x; Bs[buf][c2 + 1][r2] = pb[u].y;
        }
    };
    auto compute_chunk = [&](int buf) {
#pragma unroll
        for (int k = 0; k < 16; ++k) {
            alignas(16) float a[4];
            alignas(8)  float b[6];
            *(float4*)(a) = *(const float4*)&As[buf][k][ty * 4];
#pragma unroll
            for (int u = 0; u < 3; ++u) {
                float2 t = *(const float2*)&Bs[buf][k][tx * 2 + 32 * u];
                b[2 * u] = t.x; b[2 * u + 1] = t.y;
            }
#pragma unroll
            for (int i = 0; i < 4; ++i)
#pragma unroll
                for (int j = 0; j < 6; ++j)
                    acc[i][j] = fmaf(a[i], b[j], acc[i][j]);
        }
    };

    load_chunk(0);
    store_chunk(0);
    __syncthreads();
    int cur = 0;
    for (int k0 = 16; k0 < Cn; k0 += 16) {
        load_chunk(k0);
        compute_chunk(cur);
        store_chunk(cur ^ 1);
        __syncthreads();
        cur ^= 1;
    }
    compute_chunk(cur);

#pragma unroll
    for (int i = 0; i < 4; ++i) {
        float* cp = g_proj + (size_t)(m0 + ty * 4 + i) * Cn + j0 + tx * 2;
#pragma unroll
        for (int u = 0; u < 3; ++u) {
            float2 t; t.x = acc[i][2 * u]; t.y = acc[i][2 * u + 1];
            *(float2*)(cp + 32 * u) = t;
        }
    }
}

// ---------------- q/k/v IF step + build bf16 operands ----------------------
__global__ __launch_bounds__(256) void if_qkv() {
    int idx = blockIdx.x * 256 + threadIdx.x;   // [0, BHND)
    int d = idx & 63;
    int n = (idx >> 6) & 511;
    int bh = idx >> 15;
    int b = bh / 12, h = bh - b * 12;
    size_t qrow = ((size_t)(b * Nn + n)) * C3n + h * 64 + d;

    float xq = g_qkvt[qrow];
    float xk = g_qkvt[qrow + 768];
    float xv = g_qkvt[qrow + 1536];

    float fq = g_qq[idx]; int8_t aq = g_qa[idx];
    float so_q = if_sym(xq, fq, aq);
    g_qq[idx] = fq; g_qa[idx] = aq;

    float fk = g_kq[idx]; int8_t ak = g_ka[idx];
    float so_k = if_sym(xk, fk, ak);
    g_kq[idx] = fk; g_ka[idx] = ak;

    float fv = g_vq[idx]; int8_t av = g_va[idx];
    float so_v = if_sym(xv, fv, av);
    g_vq[idx] = fv; g_va[idx] = av;

    // attn operands (K=128): A1 = [acc_q | q_spike], B1 = [k_spike | k_acc-k]
    size_t a1b = ((size_t)bh * Nn + n) * 128 + d;
    g_A1[a1b]      = f2bf((float)aq);
    g_A1[a1b + 64] = f2bf(so_q);
    g_B1[a1b]      = f2bf(so_k);
    g_B1[a1b + 64] = f2bf((float)ak - so_k);

    // PV B operand transposed: vT[bh][d][k]: k<512 v spike, k>=512 v_acc-v
    size_t vtb = ((size_t)bh * Dn + d) * 1024 + n;
    g_vT[vtb]       = f2bf(so_v);
    g_vT[vtb + 512] = f2bf((float)av - so_v);
}

// ---------------- attn logits: S = accq@k^T + q@(kacc-k)^T (exact ints) -----
__global__ __launch_bounds__(256) void gemm_attn() {
    int bh = blockIdx.y;
    int tm = blockIdx.x >> 3, tn = blockIdx.x & 7;
    int wave = threadIdx.x >> 6, lane = threadIdx.x & 63;
    int wr = wave >> 1, wc = wave & 1;
    int row0 = tm * 64 + wr * 32, col0 = tn * 64 + wc * 32;
    const u16* Ab = g_A1 + (size_t)bh * Nn * 128;
    const u16* Bb = g_B1 + (size_t)bh * Nn * 128;
    int lr = lane & 15, kg = (lane >> 4) * 8;
    f32x4 acc[2][2] = {};
#pragma unroll
    for (int kk = 0; kk < 128; kk += 32) {
        s16x8 a0 = *(const s16x8*)&Ab[(row0 + lr) * 128 + kk + kg];
        s16x8 a1 = *(const s16x8*)&Ab[(row0 + 16 + lr) * 128 + kk + kg];
        s16x8 b0 = *(const s16x8*)&Bb[(col0 + lr) * 128 + kk + kg];
        s16x8 b1 = *(const s16x8*)&Bb[(col0 + 16 + lr) * 128 + kk + kg];
        acc[0][0] = __builtin_amdgcn_mfma_f32_16x16x32_bf16(a0, b0, acc[0][0], 0, 0, 0);
        acc[0][1] = __builtin_amdgcn_mfma_f32_16x16x32_bf16(a0, b1, acc[0][1], 0, 0, 0);
        acc[1][0] = __builtin_amdgcn_mfma_f32_16x16x32_bf16(a1, b0, acc[1][0], 0, 0, 0);
        acc[1][1] = __builtin_amdgcn_mfma_f32_16x16x32_bf16(a1, b1, acc[1][1], 0, 0, 0);
    }
    short* Sb = g_S16 + (size_t)bh * Nn * Nn;
#pragma unroll
    for (int i = 0; i < 2; ++i)
#pragma unroll
        for (int j = 0; j < 2; ++j)
#pragma unroll
            for (int q = 0; q < 4; ++q) {
                int row = row0 + i * 16 + (lane >> 4) * 4 + q;
                int col = col0 + j * 16 + lr;
                Sb[row * Nn + col] = (short)(int)acc[i][j][q];
            }
}

// ---------------- aif IF (int) + spiking softmax + sif IF -------------------
__global__ __launch_bounds__(256) void attn_pipeline(float scale_t) {
    size_t base = (size_t)blockIdx.x * Nn;   // row = bh*512 + n
    int tid = threadIdx.x;
    __shared__ int   redI[4];
    __shared__ float redF[4];

    int X[2];
    int myMax = -128;
#pragma unroll
    for (int u = 0; u < 2; ++u) {
        int c = tid + u * 256;
        int s  = g_S16[base + c];
        int q8 = g_aifq[base + c] + s;      // q*8 integer arithmetic, exact
        int a  = g_aifa[base + c];
        bool pos = (q8 >= 8) && (a < 7);
        bool neg = (q8 < 0) && (a > -8);
        int o = pos ? 1 : (neg ? -1 : 0);
        g_aifq[base + c] = (short)(q8 - (o << 3));
        a += o;
        g_aifa[base + c] = (int8_t)a;
        X[u] = a;                            // == smX_new (exact identity)
        myMax = max(myMax, a);
    }
    for (int off = 32; off; off >>= 1) myMax = max(myMax, __shfl_xor(myMax, off));
    if ((tid & 63) == 0) redI[tid >> 6] = myMax;
    __syncthreads();
    int M = max(max(redI[0], redI[1]), max(redI[2], redI[3]));

    float e[2];
    float mySum = 0.0f;
#pragma unroll
    for (int u = 0; u < 2; ++u) { e[u] = expf((float)(X[u] - M)); mySum += e[u]; }
    for (int off = 32; off; off >>= 1) mySum += __shfl_xor(mySum, off);
    if ((tid & 63) == 0) redF[tid >> 6] = mySum;
    __syncthreads();
    float Ssum = (redF[0] + redF[1]) + (redF[2] + redF[3]);

#pragma unroll
    for (int u = 0; u < 2; ++u) {
        int c = tid + u * 256;
        float y = (e[u] / Ssum) * scale_t;
        float dlt = y - g_smY[base + c];
        g_smY[base + c] = y;
        float q = g_sifq[base + c] + dlt;
        int a = g_sifa[base + c];
        bool pos = ((q - 1.0f) >= 0.0f) && (a < 7);
        bool neg = (q < 0.0f) && (a > 0);   // neg_min = 0 (unsym)
        float o = pos ? 1.0f : (neg ? -1.0f : 0.0f);
        g_sifq[base + c] = q - o;
        g_sifa[base + c] = (int8_t)(a + (int)o);
        g_spk[base + c]  = f2bf(o);          // PV spike operand (acc half == sifa)
    }
}

// ---------------- PV: out[n][d] = sifa@v + spk@(vacc-v) (exact ints) --------
__global__ __launch_bounds__(256) void gemm_pv() {
    int bh = blockIdx.y;
    int tm = blockIdx.x;
    int wave = threadIdx.x >> 6, lane = threadIdx.x & 63;
    int wr = wave >> 1, wc = wave & 1;
    int row0 = tm * 64 + wr * 32, col0 = wc * 32;
    const int8_t* Aa  = g_sifa + (size_t)bh * Nn * Nn;   // [n][512] int8
    const u16*    Asp = g_spk  + (size_t)bh * Nn * Nn;   // [n][512] bf16
    const u16*    Bb  = g_vT   + (size_t)bh * Dn * 1024; // [d][1024]
    int lr = lane & 15, kg = (lane >> 4) * 8;
    f32x4 acc[2][2] = {};
    for (int kk = 0; kk < 512; kk += 32) {
        s16x8 a0 = cvt_i8_bf16x8(Aa + (size_t)(row0 + lr) * 512 + kk + kg);
        s16x8 a1 = cvt_i8_bf16x8(Aa + (size_t)(row0 + 16 + lr) * 512 + kk + kg);
        s16x8 b0 = *(const s16x8*)&Bb[(col0 + lr) * 1024 + kk + kg];
        s16x8 b1 = *(const s16x8*)&Bb[(col0 + 16 + lr) * 1024 + kk + kg];
        acc[0][0] = __builtin_amdgcn_mfma_f32_16x16x32_bf16(a0, b0, acc[0][0], 0, 0, 0);
        acc[0][1] = __builtin_amdgcn_mfma_f32_16x16x32_bf16(a0, b1, acc[0][1], 0, 0, 0);
        acc[1][0] = __builtin_amdgcn_mfma_f32_16x16x32_bf16(a1, b0, acc[1][0], 0, 0, 0);
        acc[1][1] = __builtin_amdgcn_mfma_f32_16x16x32_bf16(a1, b1, acc[1][1], 0, 0, 0);
    }
    for (int kk = 0; kk < 512; kk += 32) {
        s16x8 a0 = *(const s16x8*)&Asp[(size_t)(row0 + lr) * 512 + kk + kg];
        s16x8 a1 = *(const s16x8*)&Asp[(size_t)(row0 + 16 + lr) * 512 + kk + kg];
        s16x8 b0 = *(const s16x8*)&Bb[(col0 + lr) * 1024 + 512 + kk + kg];
        s16x8 b1 = *(const s16x8*)&Bb[(col0 + 16 + lr) * 1024 + 512 + kk + kg];
        acc[0][0] = __builtin_amdgcn_mfma_f32_16x16x32_bf16(a0, b0, acc[0][0], 0, 0, 0);
        acc[0][1] = __builtin_amdgcn_mfma_f32_16x16x32_bf16(a0, b1, acc[0][1], 0, 0, 0);
        acc[1][0] = __builtin_amdgcn_mfma_f32_16x16x32_bf16(a1, b0, acc[1][0], 0, 0, 0);
        acc[1][1] = __builtin_amdgcn_mfma_f32_16x16x32_bf16(a1, b1, acc[1][1], 0, 0, 0);
    }
    float* Pb = g_pv + (size_t)bh * Nn * Dn;
#pragma unroll
    for (int i = 0; i < 2; ++i)
#pragma unroll
        for (int j = 0; j < 2; ++j)
#pragma unroll
            for (int q = 0; q < 4; ++q) {
                int row = row0 + i * 16 + (lane >> 4) * 4 + q;
                int col = col0 + j * 16 + lr;
                Pb[row * Dn + col] = acc[i][j][q];
            }
}

// ---------------- oif IF + write proj-input spikes [B,N,C] ------------------
__global__ __launch_bounds__(256) void oif_kernel() {
    int idx = blockIdx.x * 256 + threadIdx.x;
    float x = g_pv[idx];
    float q = g_oq[idx]; int8_t a = g_oa[idx];
    float o = if_sym(x, q, a);
    g_oq[idx] = q; g_oa[idx] = a;
    int d = idx & 63;
    int n = (idx >> 6) & 511;
    int bh = idx >> 15;
    int b = bh / 12, h = bh - b * 12;
    g_osp[((size_t)(b * Nn + n)) * Cn + h * 64 + d] = o;
}

// ---------------- pif IF + write output spikes ------------------------------
__global__ __launch_bounds__(256) void pif_kernel(float* __restrict__ outp) {
    int idx = blockIdx.x * 256 + threadIdx.x;
    float x = g_proj[idx];
    float q = g_pq[idx]; int8_t a = g_pa[idx];
    float o = if_sym(x, q, a);
    g_pq[idx] = q; g_pa[idx] = a;
    outp[idx] = o;
}

extern "C" void kernel_launch(void* const* d_in, const int* in_sizes, int n_in,
                              void* d_out, int out_size, void* d_ws, size_t ws_size,
                              hipStream_t stream) {
    (void)in_sizes; (void)n_in; (void)out_size; (void)d_ws; (void)ws_size;
    const float* x      = (const float*)d_in[0];
    const float* w_qkv  = (const float*)d_in[1];
    const float* w_proj = (const float*)d_in[2];
    float* outp = (float*)d_out;

    init_states<<<2048, 256, 0, stream>>>();

    for (int t = 0; t < Tn; ++t) {
        const float* xt = x + (size_t)t * BNC;
        // qkv = x_t @ w_qkv^T  [4096 x 2304], K=768: tile 128x96, 768 blocks
        gemm_qkv_128x96<<<dim3(C3n / 96, BNn / 128), 256, 0, stream>>>(xt, w_qkv);
        if_qkv<<<(int)(BHND / 256), 256, 0, stream>>>();
        gemm_attn<<<dim3(64, BHn), 256, 0, stream>>>();
        float st = (t + 1) < 6 ? (float)(t + 1) / 6.0f : 1.0f;
        attn_pipeline<<<BHn * Nn, 256, 0, stream>>>(st);
        gemm_pv<<<dim3(8, BHn), 256, 0, stream>>>();
        oif_kernel<<<(int)(BHND / 256), 256, 0, stream>>>();
        // proj = ospike @ w_proj^T  [4096 x 768], K=768: tile 64x96, 512 blocks
        gemm_proj_64x96<<<dim3(Cn / 96, BNn / 64), 256, 0, stream>>>(w_proj);
        pif_kernel<<<(int)(BNC / 256), 256, 0, stream>>>(outp + (size_t)t * BNC);
    }
}

// Round 8
// 4999.112 us; speedup vs baseline: 1.1868x; 1.0013x over previous
//
#include <hip/hip_runtime.h>
#include <stdint.h>

typedef __attribute__((ext_vector_type(4))) float f32x4;
typedef __attribute__((ext_vector_type(8))) short s16x8;
typedef __attribute__((ext_vector_type(8))) char  s8x8;
typedef unsigned short u16;

constexpr int    Tn  = 8;
constexpr int    Nn  = 512;
constexpr int    Cn  = 768;
constexpr int    Dn  = 64;
constexpr int    BHn = 96;
constexpr int    BNn = 4096;
constexpr int    C3n = 2304;
constexpr size_t BHND = 3145728;     // B*H*N*D
constexpr size_t BHNN = 25165824;    // B*H*N*N
constexpr size_t BNC  = 3145728;     // B*N*C

// ---- all state lives in device globals (zero-init -> NOBITS) ----
__device__ float  g_qkvt[(size_t)BNn * C3n];
__device__ float  g_qq[BHND];
__device__ float  g_kq[BHND];
__device__ float  g_vq[BHND];
__device__ int8_t g_qa[BHND];
__device__ int8_t g_ka[BHND];
__device__ int8_t g_va[BHND];
__device__ u16    g_A1[BHND * 2];                  // [bh][n][128]
__device__ u16    g_B1[BHND * 2];
__device__ short  g_S16[BHNN];
__device__ short  g_aifq[BHNN];                    // q*8, exact int
__device__ int8_t g_aifa[BHNN];                    // == smX (proven identical)
__device__ int    g_smM[(size_t)BHn * Nn];         // per-row max of X (prev step)
__device__ float  g_smS[(size_t)BHn * Nn];         // per-row exp-sum (prev step)
__device__ float  g_sifq[BHNN];
__device__ int8_t g_sifa[BHNN];
__device__ int8_t g_spk[BHNN];                     // sif spike, PV A upper half
__device__ u16    g_vT[(size_t)BHn * Dn * 1024];   // [bh][d][1024]
__device__ float  g_pv[BHND];
__device__ float  g_oq[BHND];
__device__ int8_t g_oa[BHND];
__device__ float  g_osp[BNC];
__device__ float  g_proj[BNC];
__device__ float  g_pq[BNC];
__device__ int8_t g_pa[BNC];

static __device__ __forceinline__ u16 f2bf(float f) {
    union { float f; unsigned int u; } v; v.f = f;
    return (u16)(v.u >> 16);   // exact for small-integer-valued floats
}

static __device__ __forceinline__ s16x8 cvt_i8_bf16x8(const int8_t* p) {
    s8x8 v = *(const s8x8*)p;
    s16x8 r;
#pragma unroll
    for (int j = 0; j < 8; ++j) r[j] = (short)f2bf((float)v[j]);
    return r;
}

// symmetric IF neuron step (pos_max=7, neg_min=-8)
static __device__ __forceinline__ float if_sym(float x, float& q, int8_t& a8) {
    float q2 = q + x;
    int a = a8;
    bool pos = ((q2 - 1.0f) >= 0.0f) && (a < 7);
    bool neg = (q2 < 0.0f) && (a > -8);
    float out = pos ? 1.0f : (neg ? -1.0f : 0.0f);
    q = q2 - out;
    a8 = (int8_t)(a + (int)out);
    return out;
}

// ---------------- init all persistent states ----------------
__global__ __launch_bounds__(256) void init_states() {
    size_t i0 = (size_t)blockIdx.x * blockDim.x + threadIdx.x;
    size_t stride = (size_t)gridDim.x * blockDim.x;
    for (size_t i = i0; i < BHNN; i += stride) {
        if (i < BHND) {
            g_qq[i] = 0.5f; g_kq[i] = 0.5f; g_vq[i] = 0.5f;
            g_qa[i] = 0; g_ka[i] = 0; g_va[i] = 0;
            g_oq[i] = 0.5f; g_oa[i] = 0;
            g_pq[i] = 0.5f; g_pa[i] = 0;       // BNC == BHND
        }
        g_aifq[i] = 4;       // q=0.5 stored as q*8
        g_aifa[i] = 0;
        g_sifq[i] = 0.5f;
        g_sifa[i] = 0;
    }
}

// ---------------- fp32 NT GEMMs: C[m][j] = sum_k A[m][k]*B[j][k] ------------
// ONE fp32 fmaf chain per output, k strictly ascending -> bit-identical.
// Double-buffered LDS, one barrier per 16-k chunk. A-fragment split 4+4
// (stride 64) -> ds_read_b128 bank pattern 2-way (free), was 4-way.

// qkv: [4096 x 2304], K=768. Tile 128x96, 8x6/thread, grid 24x32 = 768 blocks.
__global__ __launch_bounds__(256) void gemm_qkv_128x96(
    const float* __restrict__ A, const float* __restrict__ B)
{
    __shared__ __align__(16) float As[2][16][132];   // 128+4: stride%32 == 4
    __shared__ __align__(16) float Bs[2][16][100];   // 96+4 : stride%32 == 4
    const int tid = threadIdx.x;
    const int m0 = blockIdx.y * 128;
    const int j0 = blockIdx.x * 96;
    const int ty = tid >> 4, tx = tid & 15;

    float acc[8][6];
#pragma unroll
    for (int i = 0; i < 8; ++i)
#pragma unroll
        for (int j = 0; j < 6; ++j) acc[i][j] = 0.0f;

    float4 pa[2];
    float2 pb[3];

    auto load_chunk = [&](int k0) {
#pragma unroll
        for (int u = 0; u < 2; ++u) {
            int f = tid + u * 256;
            int row = f >> 2;
            int c4 = (f & 3) * 4;
            pa[u] = *(const float4*)(A + (size_t)(m0 + row) * Cn + k0 + c4);
        }
#pragma unroll
        for (int u = 0; u < 3; ++u) {
            int f = tid + u * 256;
            int row = f >> 3;
            int c2 = (f & 7) * 2;
            pb[u] = *(const float2*)(B + (size_t)(j0 + row) * Cn + k0 + c2);
        }
    };
    auto store_chunk = [&](int buf) {
#pragma unroll
        for (int u = 0; u < 2; ++u) {
            int f = tid + u * 256;
            int row = f >> 2;
            int c4 = (f & 3) * 4;
            As[buf][c4 + 0][row] = pa[u].x; As[buf][c4 + 1][row] = pa[u].y;
            As[buf][c4 + 2][row] = pa[u].z; As[buf][c4 + 3][row] = pa[u].w;
        }
#pragma unroll
        for (int u = 0; u < 3; ++u) {
            int f = tid + u * 256;
            int row = f >> 3;
            int c2 = (f & 7) * 2;
            Bs[buf][c2][row] = pb[u].x; Bs[buf][c2 + 1][row] = pb[u].y;
        }
    };
    // thread rows: {ty*4 .. ty*4+3} and {64+ty*4 .. 64+ty*4+3}
    auto compute_chunk = [&](int buf) {
#pragma unroll
        for (int k = 0; k < 16; ++k) {
            alignas(16) float a[8];
            alignas(8)  float b[6];
            *(float4*)(a)     = *(const float4*)&As[buf][k][ty * 4];
            *(float4*)(a + 4) = *(const float4*)&As[buf][k][64 + ty * 4];
#pragma unroll
            for (int u = 0; u < 3; ++u) {
                float2 t = *(const float2*)&Bs[buf][k][tx * 2 + 32 * u];
                b[2 * u] = t.x; b[2 * u + 1] = t.y;
            }
#pragma unroll
            for (int i = 0; i < 8; ++i)
#pragma unroll
                for (int j = 0; j < 6; ++j)
                    acc[i][j] = fmaf(a[i], b[j], acc[i][j]);
        }
    };

    load_chunk(0);
    store_chunk(0);
    __syncthreads();
    int cur = 0;
    for (int k0 = 16; k0 < Cn; k0 += 16) {
        load_chunk(k0);          // global loads in flight during compute
        compute_chunk(cur);
        store_chunk(cur ^ 1);    // other buffer: no pre-store barrier needed
        __syncthreads();
        cur ^= 1;
    }
    compute_chunk(cur);

#pragma unroll
    for (int i = 0; i < 8; ++i) {
        int row = m0 + (i < 4 ? ty * 4 + i : 64 + ty * 4 + (i - 4));
        float* cp = g_qkvt + (size_t)row * C3n + j0 + tx * 2;
#pragma unroll
        for (int u = 0; u < 3; ++u) {
            float2 t; t.x = acc[i][2 * u]; t.y = acc[i][2 * u + 1];
            *(float2*)(cp + 32 * u) = t;
        }
    }
}

// proj: [4096 x 768], K=768. Tile 64x96, 4x6/thread, grid 8x64 = 512 blocks.
__global__ __launch_bounds__(256) void gemm_proj_64x96(const float* __restrict__ B)
{
    __shared__ __align__(16) float As[2][16][68];    // 64+4
    __shared__ __align__(16) float Bs[2][16][100];
    const int tid = threadIdx.x;
    const int m0 = blockIdx.y * 64;
    const int j0 = blockIdx.x * 96;
    const int ty = tid >> 4, tx = tid & 15;
    const float* A = g_osp;

    float acc[4][6];
#pragma unroll
    for (int i = 0; i < 4; ++i)
#pragma unroll
        for (int j = 0; j < 6; ++j) acc[i][j] = 0.0f;

    float4 pa0;
    float2 pb[3];

    auto load_chunk = [&](int k0) {
        int row = tid >> 2;
        int c4 = (tid & 3) * 4;
        pa0 = *(const float4*)(A + (size_t)(m0 + row) * Cn + k0 + c4);
#pragma unroll
        for (int u = 0; u < 3; ++u) {
            int f = tid + u * 256;
            int r2 = f >> 3;
            int c2 = (f & 7) * 2;
            pb[u] = *(const float2*)(B + (size_t)(j0 + r2) * Cn + k0 + c2);
        }
    };
    auto store_chunk = [&](int buf) {
        int row = tid >> 2;
        int c4 = (tid & 3) * 4;
        As[buf][c4 + 0][row] = pa0.x; As[buf][c4 + 1][row] = pa0.y;
        As[buf][c4 + 2][row] = pa0.z; As[buf][c4 + 3][row] = pa0.w;
#pragma unroll
        for (int u = 0; u < 3; ++u) {
            int f = tid + u * 256;
            int r2 = f >> 3;
            int c2 = (f & 7) * 2;
            Bs[buf][c2][r2] = pb[u].x; Bs[buf][c2 + 1][r2] = pb[u].y;
        }
    };
    auto compute_chunk = [&](int buf) {
#pragma unroll
        for (int k = 0; k < 16; ++k) {
            alignas(16) float a[4];
            alignas(8)  float b[6];
            *(float4*)(a) = *(const float4*)&As[buf][k][ty * 4];
#pragma unroll
            for (int u = 0; u < 3; ++u) {
                float2 t = *(const float2*)&Bs[buf][k][tx * 2 + 32 * u];
                b[2 * u] = t.x; b[2 * u + 1] = t.y;
            }
#pragma unroll
            for (int i = 0; i < 4; ++i)
#pragma unroll
                for (int j = 0; j < 6; ++j)
                    acc[i][j] = fmaf(a[i], b[j], acc[i][j]);
        }
    };

    load_chunk(0);
    store_chunk(0);
    __syncthreads();
    int cur = 0;
    for (int k0 = 16; k0 < Cn; k0 += 16) {
        load_chunk(k0);
        compute_chunk(cur);
        store_chunk(cur ^ 1);
        __syncthreads();
        cur ^= 1;
    }
    compute_chunk(cur);

#pragma unroll
    for (int i = 0; i < 4; ++i) {
        float* cp = g_proj + (size_t)(m0 + ty * 4 + i) * Cn + j0 + tx * 2;
#pragma unroll
        for (int u = 0; u < 3; ++u) {
            float2 t; t.x = acc[i][2 * u]; t.y = acc[i][2 * u + 1];
            *(float2*)(cp + 32 * u) = t;
        }
    }
}

// ---------------- q/k/v IF step + build bf16 operands ----------------------
__global__ __launch_bounds__(256) void if_qkv() {
    int idx = blockIdx.x * 256 + threadIdx.x;   // [0, BHND)
    int d = idx & 63;
    int n = (idx >> 6) & 511;
    int bh = idx >> 15;
    int b = bh / 12, h = bh - b * 12;
    size_t qrow = ((size_t)(b * Nn + n)) * C3n + h * 64 + d;

    float xq = g_qkvt[qrow];
    float xk = g_qkvt[qrow + 768];
    float xv = g_qkvt[qrow + 1536];

    float fq = g_qq[idx]; int8_t aq = g_qa[idx];
    float so_q = if_sym(xq, fq, aq);
    g_qq[idx] = fq; g_qa[idx] = aq;

    float fk = g_kq[idx]; int8_t ak = g_ka[idx];
    float so_k = if_sym(xk, fk, ak);
    g_kq[idx] = fk; g_ka[idx] = ak;

    float fv = g_vq[idx]; int8_t av = g_va[idx];
    float so_v = if_sym(xv, fv, av);
    g_vq[idx] = fv; g_va[idx] = av;

    // attn operands (K=128): A1 = [acc_q | q_spike], B1 = [k_spike | k_acc-k]
    size_t a1b = ((size_t)bh * Nn + n) * 128 + d;
    g_A1[a1b]      = f2bf((float)aq);
    g_A1[a1b + 64] = f2bf(so_q);
    g_B1[a1b]      = f2bf(so_k);
    g_B1[a1b + 64] = f2bf((float)ak - so_k);

    // PV B operand transposed: vT[bh][d][k]: k<512 v spike, k>=512 v_acc-v
    size_t vtb = ((size_t)bh * Dn + d) * 1024 + n;
    g_vT[vtb]       = f2bf(so_v);
    g_vT[vtb + 512] = f2bf((float)av - so_v);
}

// ---------------- attn logits: S = accq@k^T + q@(kacc-k)^T (exact ints) -----
__global__ __launch_bounds__(256) void gemm_attn() {
    int bh = blockIdx.y;
    int tm = blockIdx.x >> 3, tn = blockIdx.x & 7;
    int wave = threadIdx.x >> 6, lane = threadIdx.x & 63;
    int wr = wave >> 1, wc = wave & 1;
    int row0 = tm * 64 + wr * 32, col0 = tn * 64 + wc * 32;
    const u16* Ab = g_A1 + (size_t)bh * Nn * 128;
    const u16* Bb = g_B1 + (size_t)bh * Nn * 128;
    int lr = lane & 15, kg = (lane >> 4) * 8;
    f32x4 acc[2][2] = {};
#pragma unroll
    for (int kk = 0; kk < 128; kk += 32) {
        s16x8 a0 = *(const s16x8*)&Ab[(row0 + lr) * 128 + kk + kg];
        s16x8 a1 = *(const s16x8*)&Ab[(row0 + 16 + lr) * 128 + kk + kg];
        s16x8 b0 = *(const s16x8*)&Bb[(col0 + lr) * 128 + kk + kg];
        s16x8 b1 = *(const s16x8*)&Bb[(col0 + 16 + lr) * 128 + kk + kg];
        acc[0][0] = __builtin_amdgcn_mfma_f32_16x16x32_bf16(a0, b0, acc[0][0], 0, 0, 0);
        acc[0][1] = __builtin_amdgcn_mfma_f32_16x16x32_bf16(a0, b1, acc[0][1], 0, 0, 0);
        acc[1][0] = __builtin_amdgcn_mfma_f32_16x16x32_bf16(a1, b0, acc[1][0], 0, 0, 0);
        acc[1][1] = __builtin_amdgcn_mfma_f32_16x16x32_bf16(a1, b1, acc[1][1], 0, 0, 0);
    }
    short* Sb = g_S16 + (size_t)bh * Nn * Nn;
#pragma unroll
    for (int i = 0; i < 2; ++i)
#pragma unroll
        for (int j = 0; j < 2; ++j)
#pragma unroll
            for (int q = 0; q < 4; ++q) {
                int row = row0 + i * 16 + (lane >> 4) * 4 + q;
                int col = col0 + j * 16 + lr;
                Sb[row * Nn + col] = (short)(int)acc[i][j][q];
            }
}

// ---------------- aif IF (int) + spiking softmax + sif IF -------------------
// smY eliminated: y_old recomputed from per-row (M_old, Ssum_old) + X_old with
// the exact same op sequence the previous step used -> bit-identical dlt.
__global__ __launch_bounds__(256) void attn_pipeline(float scale_t, float scale_prev) {
    int rowid = blockIdx.x;
    size_t base = (size_t)rowid * Nn;   // row = bh*512 + n
    int tid = threadIdx.x;
    __shared__ int   redI[4];
    __shared__ float redF[4];

    int X[2], Xold[2];
    int myMax = -128;
#pragma unroll
    for (int u = 0; u < 2; ++u) {
        int c = tid + u * 256;
        int s  = g_S16[base + c];
        int q8 = g_aifq[base + c] + s;      // q*8 integer arithmetic, exact
        int a  = g_aifa[base + c];
        bool pos = (q8 >= 8) && (a < 7);
        bool neg = (q8 < 0) && (a > -8);
        int o = pos ? 1 : (neg ? -1 : 0);
        g_aifq[base + c] = (short)(q8 - (o << 3));
        Xold[u] = a;
        a += o;
        g_aifa[base + c] = (int8_t)a;
        X[u] = a;                            // == smX_new (exact identity)
        myMax = max(myMax, a);
    }
    int  Mold = g_smM[rowid];
    float Sold = g_smS[rowid];
    for (int off = 32; off; off >>= 1) myMax = max(myMax, __shfl_xor(myMax, off));
    if ((tid & 63) == 0) redI[tid >> 6] = myMax;
    __syncthreads();
    int M = max(max(redI[0], redI[1]), max(redI[2], redI[3]));

    float e[2];
    float mySum = 0.0f;
#pragma unroll
    for (int u = 0; u < 2; ++u) { e[u] = expf((float)(X[u] - M)); mySum += e[u]; }
    for (int off = 32; off; off >>= 1) mySum += __shfl_xor(mySum, off);
    if ((tid & 63) == 0) redF[tid >> 6] = mySum;
    __syncthreads();
    float Ssum = (redF[0] + redF[1]) + (redF[2] + redF[3]);
    if (tid == 0) { g_smM[rowid] = M; g_smS[rowid] = Ssum; }

#pragma unroll
    for (int u = 0; u < 2; ++u) {
        int c = tid + u * 256;
        float y = (e[u] / Ssum) * scale_t;
        float yold = 0.0f;
        if (scale_prev >= 0.0f)
            yold = (expf((float)(Xold[u] - Mold)) / Sold) * scale_prev;
        float dlt = y - yold;
        float q = g_sifq[base + c] + dlt;
        int a = g_sifa[base + c];
        bool pos = ((q - 1.0f) >= 0.0f) && (a < 7);
        bool neg = (q < 0.0f) && (a > 0);   // neg_min = 0 (unsym)
        float o = pos ? 1.0f : (neg ? -1.0f : 0.0f);
        g_sifq[base + c] = q - o;
        g_sifa[base + c] = (int8_t)(a + (int)o);
        g_spk[base + c]  = (int8_t)o;        // PV spike operand (acc half == sifa)
    }
}

// ---------------- PV: out[n][d] = sifa@v + spk@(vacc-v) (exact ints) --------
__global__ __launch_bounds__(256) void gemm_pv() {
    int bh = blockIdx.y;
    int tm = blockIdx.x;
    int wave = threadIdx.x >> 6, lane = threadIdx.x & 63;
    int wr = wave >> 1, wc = wave & 1;
    int row0 = tm * 64 + wr * 32, col0 = wc * 32;
    const int8_t* Aa  = g_sifa + (size_t)bh * Nn * Nn;   // [n][512] int8
    const int8_t* Asp = g_spk  + (size_t)bh * Nn * Nn;   // [n][512] int8
    const u16*    Bb  = g_vT   + (size_t)bh * Dn * 1024; // [d][1024]
    int lr = lane & 15, kg = (lane >> 4) * 8;
    f32x4 acc[2][2] = {};
    for (int kk = 0; kk < 512; kk += 32) {
        s16x8 a0 = cvt_i8_bf16x8(Aa + (size_t)(row0 + lr) * 512 + kk + kg);
        s16x8 a1 = cvt_i8_bf16x8(Aa + (size_t)(row0 + 16 + lr) * 512 + kk + kg);
        s16x8 b0 = *(const s16x8*)&Bb[(col0 + lr) * 1024 + kk + kg];
        s16x8 b1 = *(const s16x8*)&Bb[(col0 + 16 + lr) * 1024 + kk + kg];
        acc[0][0] = __builtin_amdgcn_mfma_f32_16x16x32_bf16(a0, b0, acc[0][0], 0, 0, 0);
        acc[0][1] = __builtin_amdgcn_mfma_f32_16x16x32_bf16(a0, b1, acc[0][1], 0, 0, 0);
        acc[1][0] = __builtin_amdgcn_mfma_f32_16x16x32_bf16(a1, b0, acc[1][0], 0, 0, 0);
        acc[1][1] = __builtin_amdgcn_mfma_f32_16x16x32_bf16(a1, b1, acc[1][1], 0, 0, 0);
    }
    for (int kk = 0; kk < 512; kk += 32) {
        s16x8 a0 = cvt_i8_bf16x8(Asp + (size_t)(row0 + lr) * 512 + kk + kg);
        s16x8 a1 = cvt_i8_bf16x8(Asp + (size_t)(row0 + 16 + lr) * 512 + kk + kg);
        s16x8 b0 = *(const s16x8*)&Bb[(col0 + lr) * 1024 + 512 + kk + kg];
        s16x8 b1 = *(const s16x8*)&Bb[(col0 + 16 + lr) * 1024 + 512 + kk + kg];
        acc[0][0] = __builtin_amdgcn_mfma_f32_16x16x32_bf16(a0, b0, acc[0][0], 0, 0, 0);
        acc[0][1] = __builtin_amdgcn_mfma_f32_16x16x32_bf16(a0, b1, acc[0][1], 0, 0, 0);
        acc[1][0] = __builtin_amdgcn_mfma_f32_16x16x32_bf16(a1, b0, acc[1][0], 0, 0, 0);
        acc[1][1] = __builtin_amdgcn_mfma_f32_16x16x32_bf16(a1, b1, acc[1][1], 0, 0, 0);
    }
    float* Pb = g_pv + (size_t)bh * Nn * Dn;
#pragma unroll
    for (int i = 0; i < 2; ++i)
#pragma unroll
        for (int j = 0; j < 2; ++j)
#pragma unroll
            for (int q = 0; q < 4; ++q) {
                int row = row0 + i * 16 + (lane >> 4) * 4 + q;
                int col = col0 + j * 16 + lr;
                Pb[row * Dn + col] = acc[i][j][q];
            }
}

// ---------------- oif IF + write proj-input spikes [B,N,C] ------------------
__global__ __launch_bounds__(256) void oif_kernel() {
    int idx = blockIdx.x * 256 + threadIdx.x;
    float x = g_pv[idx];
    float q = g_oq[idx]; int8_t a = g_oa[idx];
    float o = if_sym(x, q, a);
    g_oq[idx] = q; g_oa[idx] = a;
    int d = idx & 63;
    int n = (idx >> 6) & 511;
    int bh = idx >> 15;
    int b = bh / 12, h = bh - b * 12;
    g_osp[((size_t)(b * Nn + n)) * Cn + h * 64 + d] = o;
}

// ---------------- pif IF + write output spikes ------------------------------
__global__ __launch_bounds__(256) void pif_kernel(float* __restrict__ outp) {
    int idx = blockIdx.x * 256 + threadIdx.x;
    float x = g_proj[idx];
    float q = g_pq[idx]; int8_t a = g_pa[idx];
    float o = if_sym(x, q, a);
    g_pq[idx] = q; g_pa[idx] = a;
    outp[idx] = o;
}

extern "C" void kernel_launch(void* const* d_in, const int* in_sizes, int n_in,
                              void* d_out, int out_size, void* d_ws, size_t ws_size,
                              hipStream_t stream) {
    (void)in_sizes; (void)n_in; (void)out_size; (void)d_ws; (void)ws_size;
    const float* x      = (const float*)d_in[0];
    const float* w_qkv  = (const float*)d_in[1];
    const float* w_proj = (const float*)d_in[2];
    float* outp = (float*)d_out;

    init_states<<<2048, 256, 0, stream>>>();

    for (int t = 0; t < Tn; ++t) {
        const float* xt = x + (size_t)t * BNC;
        // qkv = x_t @ w_qkv^T  [4096 x 2304], K=768: tile 128x96, 768 blocks
        gemm_qkv_128x96<<<dim3(C3n / 96, BNn / 128), 256, 0, stream>>>(xt, w_qkv);
        if_qkv<<<(int)(BHND / 256), 256, 0, stream>>>();
        gemm_attn<<<dim3(64, BHn), 256, 0, stream>>>();
        float st = (t + 1) < 6 ? (float)(t + 1) / 6.0f : 1.0f;
        float sp = (t == 0) ? -1.0f : ((t < 6) ? (float)t / 6.0f : 1.0f);
        attn_pipeline<<<BHn * Nn, 256, 0, stream>>>(st, sp);
        gemm_pv<<<dim3(8, BHn), 256, 0, stream>>>();
        oif_kernel<<<(int)(BHND / 256), 256, 0, stream>>>();
        // proj = ospike @ w_proj^T  [4096 x 768], K=768: tile 64x96, 512 blocks
        gemm_proj_64x96<<<dim3(Cn / 96, BNn / 64), 256, 0, stream>>>(w_proj);
        pif_kernel<<<(int)(BNC / 256), 256, 0, stream>>>(outp + (size_t)t * BNC);
    }
}

// Round 9
// 4777.329 us; speedup vs baseline: 1.2419x; 1.0464x over previous
//
#include <hip/hip_runtime.h>
#include <stdint.h>

typedef __attribute__((ext_vector_type(4))) float f32x4;
typedef __attribute__((ext_vector_type(8))) short s16x8;
typedef __attribute__((ext_vector_type(8))) char  s8x8;
typedef unsigned short u16;

constexpr int    Tn  = 8;
constexpr int    Nn  = 512;
constexpr int    Cn  = 768;
constexpr int    Dn  = 64;
constexpr int    BHn = 96;
constexpr int    BNn = 4096;
constexpr int    C3n = 2304;
constexpr size_t BHND = 3145728;     // B*H*N*D
constexpr size_t BHNN = 25165824;    // B*H*N*N
constexpr size_t BNC  = 3145728;     // B*N*C

// ---- all state lives in device globals (zero-init -> NOBITS) ----
__device__ float  g_qkvt8[(size_t)Tn * BNn * C3n];   // all-t qkv output (302MB)
__device__ u16    g_A1[(size_t)Tn * BHND * 2];       // [t][bh][n][128]
__device__ u16    g_B1[(size_t)Tn * BHND * 2];
__device__ short  g_S16[(size_t)Tn * BHNN];          // [t][bh][n][n]
__device__ u16    g_vT[(size_t)Tn * BHn * Dn * 1024];// [t][bh][d][1024]
__device__ short  g_aifq[BHNN];                      // q*8, exact int
__device__ int8_t g_aifa[BHNN];                      // == smX (proven identical)
__device__ int    g_smM[(size_t)BHn * Nn];           // per-row max of X (prev step)
__device__ float  g_smS[(size_t)BHn * Nn];           // per-row exp-sum (prev step)
__device__ float  g_sifq[BHNN];
__device__ int8_t g_sifa[BHNN];
__device__ int8_t g_spk[BHNN];                       // sif spike, PV A upper half
__device__ float  g_pv[BHND];
__device__ float  g_oq[BHND];
__device__ int8_t g_oa[BHND];
__device__ float  g_osp[BNC];
__device__ float  g_proj[BNC];
__device__ float  g_pq[BNC];
__device__ int8_t g_pa[BNC];

static __device__ __forceinline__ u16 f2bf(float f) {
    union { float f; unsigned int u; } v; v.f = f;
    return (u16)(v.u >> 16);   // exact for small-integer-valued floats
}

static __device__ __forceinline__ s16x8 cvt_i8_bf16x8(const int8_t* p) {
    s8x8 v = *(const s8x8*)p;
    s16x8 r;
#pragma unroll
    for (int j = 0; j < 8; ++j) r[j] = (short)f2bf((float)v[j]);
    return r;
}

// symmetric IF neuron step (pos_max=7, neg_min=-8)
static __device__ __forceinline__ float if_sym(float x, float& q, int& a) {
    float q2 = q + x;
    bool pos = ((q2 - 1.0f) >= 0.0f) && (a < 7);
    bool neg = (q2 < 0.0f) && (a > -8);
    float out = pos ? 1.0f : (neg ? -1.0f : 0.0f);
    q = q2 - out;
    a += (int)out;
    return out;
}

// ---------------- init persistent states (attn/sif/oif/pif only) ------------
__global__ __launch_bounds__(256) void init_states() {
    size_t i0 = (size_t)blockIdx.x * blockDim.x + threadIdx.x;
    size_t stride = (size_t)gridDim.x * blockDim.x;
    for (size_t i = i0; i < BHNN; i += stride) {
        if (i < BHND) {
            g_oq[i] = 0.5f; g_oa[i] = 0;
            g_pq[i] = 0.5f; g_pa[i] = 0;       // BNC == BHND
        }
        g_aifq[i] = 4;       // q=0.5 stored as q*8
        g_aifa[i] = 0;
        g_sifq[i] = 0.5f;
        g_sifa[i] = 0;
    }
}

// ---------------- fp32 NT GEMM (round-5 structure, bit-exact chain) ---------
// qkv for ALL t: [32768 x 2304], K=768. Tile 128x96, grid 24x256 = 6144 blocks.
__global__ __launch_bounds__(256) void gemm_qkv_big(
    const float* __restrict__ A, const float* __restrict__ B)
{
    __shared__ __align__(16) float As[16][132];   // 128+4
    __shared__ __align__(16) float Bs[16][100];   // 96+4
    const int tid = threadIdx.x;
    const int m0 = blockIdx.y * 128;
    const int j0 = blockIdx.x * 96;
    const int ty = tid >> 4, tx = tid & 15;

    float acc[8][6];
#pragma unroll
    for (int i = 0; i < 8; ++i)
#pragma unroll
        for (int j = 0; j < 6; ++j) acc[i][j] = 0.0f;

    for (int k0 = 0; k0 < Cn; k0 += 16) {
#pragma unroll
        for (int u = 0; u < 2; ++u) {
            int f = tid + u * 256;
            int row = f >> 2;
            int c4 = (f & 3) * 4;
            float4 av = *(const float4*)(A + (size_t)(m0 + row) * Cn + k0 + c4);
            As[c4 + 0][row] = av.x; As[c4 + 1][row] = av.y;
            As[c4 + 2][row] = av.z; As[c4 + 3][row] = av.w;
        }
#pragma unroll
        for (int u = 0; u < 3; ++u) {
            int f = tid + u * 256;
            int row = f >> 3;
            int c2 = (f & 7) * 2;
            float2 bv = *(const float2*)(B + (size_t)(j0 + row) * Cn + k0 + c2);
            Bs[c2][row] = bv.x; Bs[c2 + 1][row] = bv.y;
        }
        __syncthreads();
#pragma unroll
        for (int k = 0; k < 16; ++k) {
            alignas(16) float a[8];
            alignas(8)  float b[6];
            *(float4*)(a)     = *(const float4*)&As[k][ty * 8];
            *(float4*)(a + 4) = *(const float4*)&As[k][ty * 8 + 4];
#pragma unroll
            for (int u = 0; u < 3; ++u) {
                float2 t = *(const float2*)&Bs[k][tx * 2 + 32 * u];
                b[2 * u] = t.x; b[2 * u + 1] = t.y;
            }
#pragma unroll
            for (int i = 0; i < 8; ++i)
#pragma unroll
                for (int j = 0; j < 6; ++j)
                    acc[i][j] = fmaf(a[i], b[j], acc[i][j]);
        }
        __syncthreads();
    }
#pragma unroll
    for (int i = 0; i < 8; ++i) {
        float* cp = g_qkvt8 + (size_t)(m0 + ty * 8 + i) * C3n + j0 + tx * 2;
#pragma unroll
        for (int u = 0; u < 3; ++u) {
            float2 t; t.x = acc[i][2 * u]; t.y = acc[i][2 * u + 1];
            *(float2*)(cp + 32 * u) = t;
        }
    }
}

// proj: [4096 x 768], K=768. Tile 64x96 (round-5 structure), grid 8x64.
__global__ __launch_bounds__(256) void gemm_proj_64x96(const float* __restrict__ B)
{
    __shared__ __align__(16) float As[16][68];    // 64+4
    __shared__ __align__(16) float Bs[16][100];
    const int tid = threadIdx.x;
    const int m0 = blockIdx.y * 64;
    const int j0 = blockIdx.x * 96;
    const int ty = tid >> 4, tx = tid & 15;
    const float* A = g_osp;

    float acc[4][6];
#pragma unroll
    for (int i = 0; i < 4; ++i)
#pragma unroll
        for (int j = 0; j < 6; ++j) acc[i][j] = 0.0f;

    for (int k0 = 0; k0 < Cn; k0 += 16) {
        {
            int row = tid >> 2;
            int c4 = (tid & 3) * 4;
            float4 av = *(const float4*)(A + (size_t)(m0 + row) * Cn + k0 + c4);
            As[c4 + 0][row] = av.x; As[c4 + 1][row] = av.y;
            As[c4 + 2][row] = av.z; As[c4 + 3][row] = av.w;
        }
#pragma unroll
        for (int u = 0; u < 3; ++u) {
            int f = tid + u * 256;
            int r2 = f >> 3;
            int c2 = (f & 7) * 2;
            float2 bv = *(const float2*)(B + (size_t)(j0 + r2) * Cn + k0 + c2);
            Bs[c2][r2] = bv.x; Bs[c2 + 1][r2] = bv.y;
        }
        __syncthreads();
#pragma unroll
        for (int k = 0; k < 16; ++k) {
            alignas(16) float a[4];
            alignas(8)  float b[6];
            *(float4*)(a) = *(const float4*)&As[k][ty * 4];
#pragma unroll
            for (int u = 0; u < 3; ++u) {
                float2 t = *(const float2*)&Bs[k][tx * 2 + 32 * u];
                b[2 * u] = t.x; b[2 * u + 1] = t.y;
            }
#pragma unroll
            for (int i = 0; i < 4; ++i)
#pragma unroll
                for (int j = 0; j < 6; ++j)
                    acc[i][j] = fmaf(a[i], b[j], acc[i][j]);
        }
        __syncthreads();
    }
#pragma unroll
    for (int i = 0; i < 4; ++i) {
        float* cp = g_proj + (size_t)(m0 + ty * 4 + i) * Cn + j0 + tx * 2;
#pragma unroll
        for (int u = 0; u < 3; ++u) {
            float2 t; t.x = acc[i][2 * u]; t.y = acc[i][2 * u + 1];
            *(float2*)(cp + 32 * u) = t;
        }
    }
}

// ---------------- q/k/v IF for ALL t (states live in registers) -------------
__global__ __launch_bounds__(256) void if_qkv_all() {
    int idx = blockIdx.x * 256 + threadIdx.x;   // [0, BHND)
    int d = idx & 63;
    int n = (idx >> 6) & 511;
    int bh = idx >> 15;
    int b = bh / 12, h = bh - b * 12;

    float fq = 0.5f, fk = 0.5f, fv = 0.5f;
    int aq = 0, ak = 0, av = 0;

    for (int t = 0; t < Tn; ++t) {
        size_t qrow = ((size_t)((t * 8 + b) * Nn + n)) * C3n + h * 64 + d;
        float xq = g_qkvt8[qrow];
        float xk = g_qkvt8[qrow + 768];
        float xv = g_qkvt8[qrow + 1536];

        float so_q = if_sym(xq, fq, aq);
        float so_k = if_sym(xk, fk, ak);
        float so_v = if_sym(xv, fv, av);

        // attn operands (K=128): A1 = [acc_q | q_spike], B1 = [k_spike | k_acc-k]
        size_t a1b = (((size_t)t * BHn + bh) * Nn + n) * 128 + d;
        g_A1[a1b]      = f2bf((float)aq);
        g_A1[a1b + 64] = f2bf(so_q);
        g_B1[a1b]      = f2bf(so_k);
        g_B1[a1b + 64] = f2bf((float)ak - so_k);

        // PV B operand transposed: vT[t][bh][d][k]: k<512 v, k>=512 v_acc-v
        size_t vtb = (((size_t)t * BHn + bh) * Dn + d) * 1024 + n;
        g_vT[vtb]       = f2bf(so_v);
        g_vT[vtb + 512] = f2bf((float)av - so_v);
    }
}

// ---------------- attn logits for ALL t: S = accq@k^T + q@(kacc-k)^T --------
__global__ __launch_bounds__(256) void gemm_attn_all() {
    int t = blockIdx.z;
    int bh = blockIdx.y;
    int tm = blockIdx.x >> 3, tn = blockIdx.x & 7;
    int wave = threadIdx.x >> 6, lane = threadIdx.x & 63;
    int wr = wave >> 1, wc = wave & 1;
    int row0 = tm * 64 + wr * 32, col0 = tn * 64 + wc * 32;
    const u16* Ab = g_A1 + ((size_t)t * BHn + bh) * Nn * 128;
    const u16* Bb = g_B1 + ((size_t)t * BHn + bh) * Nn * 128;
    int lr = lane & 15, kg = (lane >> 4) * 8;
    f32x4 acc[2][2] = {};
#pragma unroll
    for (int kk = 0; kk < 128; kk += 32) {
        s16x8 a0 = *(const s16x8*)&Ab[(row0 + lr) * 128 + kk + kg];
        s16x8 a1 = *(const s16x8*)&Ab[(row0 + 16 + lr) * 128 + kk + kg];
        s16x8 b0 = *(const s16x8*)&Bb[(col0 + lr) * 128 + kk + kg];
        s16x8 b1 = *(const s16x8*)&Bb[(col0 + 16 + lr) * 128 + kk + kg];
        acc[0][0] = __builtin_amdgcn_mfma_f32_16x16x32_bf16(a0, b0, acc[0][0], 0, 0, 0);
        acc[0][1] = __builtin_amdgcn_mfma_f32_16x16x32_bf16(a0, b1, acc[0][1], 0, 0, 0);
        acc[1][0] = __builtin_amdgcn_mfma_f32_16x16x32_bf16(a1, b0, acc[1][0], 0, 0, 0);
        acc[1][1] = __builtin_amdgcn_mfma_f32_16x16x32_bf16(a1, b1, acc[1][1], 0, 0, 0);
    }
    short* Sb = g_S16 + (size_t)t * BHNN + (size_t)bh * Nn * Nn;
#pragma unroll
    for (int i = 0; i < 2; ++i)
#pragma unroll
        for (int j = 0; j < 2; ++j)
#pragma unroll
            for (int q = 0; q < 4; ++q) {
                int row = row0 + i * 16 + (lane >> 4) * 4 + q;
                int col = col0 + j * 16 + lr;
                Sb[row * Nn + col] = (short)(int)acc[i][j][q];
            }
}

// ---------------- aif IF (int) + spiking softmax + sif IF -------------------
__global__ __launch_bounds__(256) void attn_pipeline(float scale_t, float scale_prev, int t) {
    int rowid = blockIdx.x;
    size_t base = (size_t)rowid * Nn;   // row = bh*512 + n
    const short* S = g_S16 + (size_t)t * BHNN;
    int tid = threadIdx.x;
    __shared__ int   redI[4];
    __shared__ float redF[4];

    int X[2], Xold[2];
    int myMax = -128;
#pragma unroll
    for (int u = 0; u < 2; ++u) {
        int c = tid + u * 256;
        int s  = S[base + c];
        int q8 = g_aifq[base + c] + s;      // q*8 integer arithmetic, exact
        int a  = g_aifa[base + c];
        bool pos = (q8 >= 8) && (a < 7);
        bool neg = (q8 < 0) && (a > -8);
        int o = pos ? 1 : (neg ? -1 : 0);
        g_aifq[base + c] = (short)(q8 - (o << 3));
        Xold[u] = a;
        a += o;
        g_aifa[base + c] = (int8_t)a;
        X[u] = a;                            // == smX_new (exact identity)
        myMax = max(myMax, a);
    }
    int  Mold = g_smM[rowid];
    float Sold = g_smS[rowid];
    for (int off = 32; off; off >>= 1) myMax = max(myMax, __shfl_xor(myMax, off));
    if ((tid & 63) == 0) redI[tid >> 6] = myMax;
    __syncthreads();
    int M = max(max(redI[0], redI[1]), max(redI[2], redI[3]));

    float e[2];
    float mySum = 0.0f;
#pragma unroll
    for (int u = 0; u < 2; ++u) { e[u] = expf((float)(X[u] - M)); mySum += e[u]; }
    for (int off = 32; off; off >>= 1) mySum += __shfl_xor(mySum, off);
    if ((tid & 63) == 0) redF[tid >> 6] = mySum;
    __syncthreads();
    float Ssum = (redF[0] + redF[1]) + (redF[2] + redF[3]);
    if (tid == 0) { g_smM[rowid] = M; g_smS[rowid] = Ssum; }

#pragma unroll
    for (int u = 0; u < 2; ++u) {
        int c = tid + u * 256;
        float y = (e[u] / Ssum) * scale_t;
        float yold = 0.0f;
        if (scale_prev >= 0.0f)
            yold = (expf((float)(Xold[u] - Mold)) / Sold) * scale_prev;
        float dlt = y - yold;
        float q = g_sifq[base + c] + dlt;
        int a = g_sifa[base + c];
        bool pos = ((q - 1.0f) >= 0.0f) && (a < 7);
        bool neg = (q < 0.0f) && (a > 0);   // neg_min = 0 (unsym)
        float o = pos ? 1.0f : (neg ? -1.0f : 0.0f);
        g_sifq[base + c] = q - o;
        g_sifa[base + c] = (int8_t)(a + (int)o);
        g_spk[base + c]  = (int8_t)o;        // PV spike operand (acc half == sifa)
    }
}

// ---------------- PV: out[n][d] = sifa@v + spk@(vacc-v) (exact ints) --------
__global__ __launch_bounds__(256) void gemm_pv(int t) {
    int bh = blockIdx.y;
    int tm = blockIdx.x;
    int wave = threadIdx.x >> 6, lane = threadIdx.x & 63;
    int wr = wave >> 1, wc = wave & 1;
    int row0 = tm * 64 + wr * 32, col0 = wc * 32;
    const int8_t* Aa  = g_sifa + (size_t)bh * Nn * Nn;   // [n][512] int8
    const int8_t* Asp = g_spk  + (size_t)bh * Nn * Nn;   // [n][512] int8
    const u16*    Bb  = g_vT + ((size_t)t * BHn + bh) * Dn * 1024; // [d][1024]
    int lr = lane & 15, kg = (lane >> 4) * 8;
    f32x4 acc[2][2] = {};
    for (int kk = 0; kk < 512; kk += 32) {
        s16x8 a0 = cvt_i8_bf16x8(Aa + (size_t)(row0 + lr) * 512 + kk + kg);
        s16x8 a1 = cvt_i8_bf16x8(Aa + (size_t)(row0 + 16 + lr) * 512 + kk + kg);
        s16x8 b0 = *(const s16x8*)&Bb[(col0 + lr) * 1024 + kk + kg];
        s16x8 b1 = *(const s16x8*)&Bb[(col0 + 16 + lr) * 1024 + kk + kg];
        acc[0][0] = __builtin_amdgcn_mfma_f32_16x16x32_bf16(a0, b0, acc[0][0], 0, 0, 0);
        acc[0][1] = __builtin_amdgcn_mfma_f32_16x16x32_bf16(a0, b1, acc[0][1], 0, 0, 0);
        acc[1][0] = __builtin_amdgcn_mfma_f32_16x16x32_bf16(a1, b0, acc[1][0], 0, 0, 0);
        acc[1][1] = __builtin_amdgcn_mfma_f32_16x16x32_bf16(a1, b1, acc[1][1], 0, 0, 0);
    }
    for (int kk = 0; kk < 512; kk += 32) {
        s16x8 a0 = cvt_i8_bf16x8(Asp + (size_t)(row0 + lr) * 512 + kk + kg);
        s16x8 a1 = cvt_i8_bf16x8(Asp + (size_t)(row0 + 16 + lr) * 512 + kk + kg);
        s16x8 b0 = *(const s16x8*)&Bb[(col0 + lr) * 1024 + 512 + kk + kg];
        s16x8 b1 = *(const s16x8*)&Bb[(col0 + 16 + lr) * 1024 + 512 + kk + kg];
        acc[0][0] = __builtin_amdgcn_mfma_f32_16x16x32_bf16(a0, b0, acc[0][0], 0, 0, 0);
        acc[0][1] = __builtin_amdgcn_mfma_f32_16x16x32_bf16(a0, b1, acc[0][1], 0, 0, 0);
        acc[1][0] = __builtin_amdgcn_mfma_f32_16x16x32_bf16(a1, b0, acc[1][0], 0, 0, 0);
        acc[1][1] = __builtin_amdgcn_mfma_f32_16x16x32_bf16(a1, b1, acc[1][1], 0, 0, 0);
    }
    float* Pb = g_pv + (size_t)bh * Nn * Dn;
#pragma unroll
    for (int i = 0; i < 2; ++i)
#pragma unroll
        for (int j = 0; j < 2; ++j)
#pragma unroll
            for (int q = 0; q < 4; ++q) {
                int row = row0 + i * 16 + (lane >> 4) * 4 + q;
                int col = col0 + j * 16 + lr;
                Pb[row * Dn + col] = acc[i][j][q];
            }
}

// ---------------- oif IF + write proj-input spikes [B,N,C] ------------------
__global__ __launch_bounds__(256) void oif_kernel() {
    int idx = blockIdx.x * 256 + threadIdx.x;
    float x = g_pv[idx];
    float q = g_oq[idx]; int a = g_oa[idx];
    float o = if_sym(x, q, a);
    g_oq[idx] = q; g_oa[idx] = (int8_t)a;
    int d = idx & 63;
    int n = (idx >> 6) & 511;
    int bh = idx >> 15;
    int b = bh / 12, h = bh - b * 12;
    g_osp[((size_t)(b * Nn + n)) * Cn + h * 64 + d] = o;
}

// ---------------- pif IF + write output spikes ------------------------------
__global__ __launch_bounds__(256) void pif_kernel(float* __restrict__ outp) {
    int idx = blockIdx.x * 256 + threadIdx.x;
    float x = g_proj[idx];
    float q = g_pq[idx]; int a = g_pa[idx];
    float o = if_sym(x, q, a);
    g_pq[idx] = q; g_pa[idx] = (int8_t)a;
    outp[idx] = o;
}

extern "C" void kernel_launch(void* const* d_in, const int* in_sizes, int n_in,
                              void* d_out, int out_size, void* d_ws, size_t ws_size,
                              hipStream_t stream) {
    (void)in_sizes; (void)n_in; (void)out_size; (void)d_ws; (void)ws_size;
    const float* x      = (const float*)d_in[0];
    const float* w_qkv  = (const float*)d_in[1];
    const float* w_proj = (const float*)d_in[2];
    float* outp = (float*)d_out;

    init_states<<<2048, 256, 0, stream>>>();

    // all-t qkv = x @ w_qkv^T  [32768 x 2304], K=768 (state-independent!)
    gemm_qkv_big<<<dim3(C3n / 96, (Tn * BNn) / 128), 256, 0, stream>>>(x, w_qkv);
    // all-t q/k/v IF + operand build, states in registers
    if_qkv_all<<<(int)(BHND / 256), 256, 0, stream>>>();
    // all-t attn logits
    gemm_attn_all<<<dim3(64, BHn, Tn), 256, 0, stream>>>();

    for (int t = 0; t < Tn; ++t) {
        float st = (t + 1) < 6 ? (float)(t + 1) / 6.0f : 1.0f;
        float sp = (t == 0) ? -1.0f : ((t < 6) ? (float)t / 6.0f : 1.0f);
        attn_pipeline<<<BHn * Nn, 256, 0, stream>>>(st, sp, t);
        gemm_pv<<<dim3(8, BHn), 256, 0, stream>>>(t);
        oif_kernel<<<(int)(BHND / 256), 256, 0, stream>>>();
        gemm_proj_64x96<<<dim3(Cn / 96, BNn / 64), 256, 0, stream>>>(w_proj);
        pif_kernel<<<(int)(BNC / 256), 256, 0, stream>>>(outp + (size_t)t * BNC);
    }
}

// Round 10
// 4274.274 us; speedup vs baseline: 1.3881x; 1.1177x over previous
//
#include <hip/hip_runtime.h>
#include <stdint.h>

typedef __attribute__((ext_vector_type(4))) float f32x4;
typedef __attribute__((ext_vector_type(8))) short s16x8;
typedef __attribute__((ext_vector_type(8))) char  s8x8;
typedef unsigned short u16;

constexpr int    Tn  = 8;
constexpr int    Nn  = 512;
constexpr int    Cn  = 768;
constexpr int    Dn  = 64;
constexpr int    BHn = 96;
constexpr int    BNn = 4096;
constexpr int    C3n = 2304;
constexpr size_t BHND = 3145728;     // B*H*N*D
constexpr size_t BHNN = 25165824;    // B*H*N*N
constexpr size_t BNC  = 3145728;     // B*N*C

// ---- all state lives in device globals (zero-init -> NOBITS) ----
__device__ float  g_qkvt8[(size_t)Tn * BNn * C3n];   // all-t qkv output (302MB)
__device__ int8_t g_A1[(size_t)Tn * BHND * 2];       // [t][bh][n][128] int8
__device__ int8_t g_B1[(size_t)Tn * BHND * 2];
__device__ short  g_S16[(size_t)Tn * BHNN];          // [t][bh][n][n]
__device__ int8_t g_vT[(size_t)Tn * BHn * Dn * 1024];// [t][bh][d][1024] int8
__device__ short  g_aifq[BHNN];                      // q*8, exact int
__device__ int8_t g_aifa[BHNN];                      // == smX (proven identical)
__device__ int    g_smM[(size_t)BHn * Nn];           // per-row max of X (prev step)
__device__ float  g_smS[(size_t)BHn * Nn];           // per-row exp-sum (prev step)
__device__ float  g_sifq[BHNN];
__device__ int8_t g_sifa[BHNN];
__device__ int8_t g_spk[BHNN];                       // sif spike, PV A upper half
__device__ float  g_oq[BHND];
__device__ int8_t g_oa[BHND];
__device__ float  g_osp[BNC];
__device__ float  g_pq[BNC];
__device__ int8_t g_pa[BNC];

static __device__ __forceinline__ u16 f2bf(float f) {
    union { float f; unsigned int u; } v; v.f = f;
    return (u16)(v.u >> 16);   // exact for small-integer-valued floats
}

static __device__ __forceinline__ s16x8 cvt_i8_bf16x8(const int8_t* p) {
    s8x8 v = *(const s8x8*)p;
    s16x8 r;
#pragma unroll
    for (int j = 0; j < 8; ++j) r[j] = (short)f2bf((float)v[j]);
    return r;
}

// symmetric IF neuron step (pos_max=7, neg_min=-8)
static __device__ __forceinline__ float if_sym(float x, float& q, int& a) {
    float q2 = q + x;
    bool pos = ((q2 - 1.0f) >= 0.0f) && (a < 7);
    bool neg = (q2 < 0.0f) && (a > -8);
    float out = pos ? 1.0f : (neg ? -1.0f : 0.0f);
    q = q2 - out;
    a += (int)out;
    return out;
}

// ---------------- init persistent states ----------------
__global__ __launch_bounds__(256) void init_states() {
    size_t i0 = (size_t)blockIdx.x * blockDim.x + threadIdx.x;
    size_t stride = (size_t)gridDim.x * blockDim.x;
    for (size_t i = i0; i < BHNN; i += stride) {
        if (i < BHND) {
            g_oq[i] = 0.5f; g_oa[i] = 0;
            g_pq[i] = 0.5f; g_pa[i] = 0;       // BNC == BHND
        }
        g_aifq[i] = 4;       // q=0.5 stored as q*8
        g_aifa[i] = 0;
        g_sifq[i] = 0.5f;
        g_sifa[i] = 0;
    }
}

// ---------------- fp32 NT GEMM (frozen round-9 structure, bit-exact chain) --
// qkv for ALL t: [32768 x 2304], K=768. Tile 128x96, grid 24x256 = 6144 blocks.
__global__ __launch_bounds__(256) void gemm_qkv_big(
    const float* __restrict__ A, const float* __restrict__ B)
{
    __shared__ __align__(16) float As[16][132];   // 128+4
    __shared__ __align__(16) float Bs[16][100];   // 96+4
    const int tid = threadIdx.x;
    const int m0 = blockIdx.y * 128;
    const int j0 = blockIdx.x * 96;
    const int ty = tid >> 4, tx = tid & 15;

    float acc[8][6];
#pragma unroll
    for (int i = 0; i < 8; ++i)
#pragma unroll
        for (int j = 0; j < 6; ++j) acc[i][j] = 0.0f;

    for (int k0 = 0; k0 < Cn; k0 += 16) {
#pragma unroll
        for (int u = 0; u < 2; ++u) {
            int f = tid + u * 256;
            int row = f >> 2;
            int c4 = (f & 3) * 4;
            float4 av = *(const float4*)(A + (size_t)(m0 + row) * Cn + k0 + c4);
            As[c4 + 0][row] = av.x; As[c4 + 1][row] = av.y;
            As[c4 + 2][row] = av.z; As[c4 + 3][row] = av.w;
        }
#pragma unroll
        for (int u = 0; u < 3; ++u) {
            int f = tid + u * 256;
            int row = f >> 3;
            int c2 = (f & 7) * 2;
            float2 bv = *(const float2*)(B + (size_t)(j0 + row) * Cn + k0 + c2);
            Bs[c2][row] = bv.x; Bs[c2 + 1][row] = bv.y;
        }
        __syncthreads();
#pragma unroll
        for (int k = 0; k < 16; ++k) {
            alignas(16) float a[8];
            alignas(8)  float b[6];
            *(float4*)(a)     = *(const float4*)&As[k][ty * 8];
            *(float4*)(a + 4) = *(const float4*)&As[k][ty * 8 + 4];
#pragma unroll
            for (int u = 0; u < 3; ++u) {
                float2 t = *(const float2*)&Bs[k][tx * 2 + 32 * u];
                b[2 * u] = t.x; b[2 * u + 1] = t.y;
            }
#pragma unroll
            for (int i = 0; i < 8; ++i)
#pragma unroll
                for (int j = 0; j < 6; ++j)
                    acc[i][j] = fmaf(a[i], b[j], acc[i][j]);
        }
        __syncthreads();
    }
#pragma unroll
    for (int i = 0; i < 8; ++i) {
        float* cp = g_qkvt8 + (size_t)(m0 + ty * 8 + i) * C3n + j0 + tx * 2;
#pragma unroll
        for (int u = 0; u < 3; ++u) {
            float2 t; t.x = acc[i][2 * u]; t.y = acc[i][2 * u + 1];
            *(float2*)(cp + 32 * u) = t;
        }
    }
}

// proj: [4096 x 768], K=768. Tile 64x96 + fused pif epilogue.
__global__ __launch_bounds__(256) void gemm_proj_pif(
    const float* __restrict__ B, float* __restrict__ outp)
{
    __shared__ __align__(16) float As[16][68];    // 64+4
    __shared__ __align__(16) float Bs[16][100];
    const int tid = threadIdx.x;
    const int m0 = blockIdx.y * 64;
    const int j0 = blockIdx.x * 96;
    const int ty = tid >> 4, tx = tid & 15;
    const float* A = g_osp;

    float acc[4][6];
#pragma unroll
    for (int i = 0; i < 4; ++i)
#pragma unroll
        for (int j = 0; j < 6; ++j) acc[i][j] = 0.0f;

    for (int k0 = 0; k0 < Cn; k0 += 16) {
        {
            int row = tid >> 2;
            int c4 = (tid & 3) * 4;
            float4 av = *(const float4*)(A + (size_t)(m0 + row) * Cn + k0 + c4);
            As[c4 + 0][row] = av.x; As[c4 + 1][row] = av.y;
            As[c4 + 2][row] = av.z; As[c4 + 3][row] = av.w;
        }
#pragma unroll
        for (int u = 0; u < 3; ++u) {
            int f = tid + u * 256;
            int r2 = f >> 3;
            int c2 = (f & 7) * 2;
            float2 bv = *(const float2*)(B + (size_t)(j0 + r2) * Cn + k0 + c2);
            Bs[c2][r2] = bv.x; Bs[c2 + 1][r2] = bv.y;
        }
        __syncthreads();
#pragma unroll
        for (int k = 0; k < 16; ++k) {
            alignas(16) float a[4];
            alignas(8)  float b[6];
            *(float4*)(a) = *(const float4*)&As[k][ty * 4];
#pragma unroll
            for (int u = 0; u < 3; ++u) {
                float2 t = *(const float2*)&Bs[k][tx * 2 + 32 * u];
                b[2 * u] = t.x; b[2 * u + 1] = t.y;
            }
#pragma unroll
            for (int i = 0; i < 4; ++i)
#pragma unroll
                for (int j = 0; j < 6; ++j)
                    acc[i][j] = fmaf(a[i], b[j], acc[i][j]);
        }
        __syncthreads();
    }
    // fused pif epilogue: IF state update + spike write directly to output
#pragma unroll
    for (int i = 0; i < 4; ++i) {
        size_t rbase = (size_t)(m0 + ty * 4 + i) * Cn + j0 + tx * 2;
#pragma unroll
        for (int u = 0; u < 3; ++u) {
#pragma unroll
            for (int c = 0; c < 2; ++c) {
                size_t idx = rbase + 32 * u + c;
                float x = acc[i][2 * u + c];
                float qd = g_pq[idx]; int a = g_pa[idx];
                float o = if_sym(x, qd, a);
                g_pq[idx] = qd; g_pa[idx] = (int8_t)a;
                outp[idx] = o;
            }
        }
    }
}

// ---------------- q/k/v IF for ALL t (states in registers, int8 operands) ---
__global__ __launch_bounds__(256) void if_qkv_all() {
    int idx = blockIdx.x * 256 + threadIdx.x;   // [0, BHND)
    int d = idx & 63;
    int n = (idx >> 6) & 511;
    int bh = idx >> 15;
    int b = bh / 12, h = bh - b * 12;

    float fq = 0.5f, fk = 0.5f, fv = 0.5f;
    int aq = 0, ak = 0, av = 0;

    for (int t = 0; t < Tn; ++t) {
        size_t qrow = ((size_t)((t * 8 + b) * Nn + n)) * C3n + h * 64 + d;
        float xq = g_qkvt8[qrow];
        float xk = g_qkvt8[qrow + 768];
        float xv = g_qkvt8[qrow + 1536];

        float so_q = if_sym(xq, fq, aq);
        float so_k = if_sym(xk, fk, ak);
        float so_v = if_sym(xv, fv, av);

        // attn operands (K=128): A1 = [acc_q | q_spike], B1 = [k_spike | k_acc-k]
        size_t a1b = (((size_t)t * BHn + bh) * Nn + n) * 128 + d;
        g_A1[a1b]      = (int8_t)aq;
        g_A1[a1b + 64] = (int8_t)so_q;
        g_B1[a1b]      = (int8_t)so_k;
        g_B1[a1b + 64] = (int8_t)(ak - (int)so_k);

        // PV B operand transposed: vT[t][bh][d][k]: k<512 v, k>=512 v_acc-v
        size_t vtb = (((size_t)t * BHn + bh) * Dn + d) * 1024 + n;
        g_vT[vtb]       = (int8_t)so_v;
        g_vT[vtb + 512] = (int8_t)(av - (int)so_v);
    }
}

// ---------------- attn logits for ALL t: S = accq@k^T + q@(kacc-k)^T --------
__global__ __launch_bounds__(256) void gemm_attn_all() {
    int t = blockIdx.z;
    int bh = blockIdx.y;
    int tm = blockIdx.x >> 3, tn = blockIdx.x & 7;
    int wave = threadIdx.x >> 6, lane = threadIdx.x & 63;
    int wr = wave >> 1, wc = wave & 1;
    int row0 = tm * 64 + wr * 32, col0 = tn * 64 + wc * 32;
    const int8_t* Ab = g_A1 + ((size_t)t * BHn + bh) * Nn * 128;
    const int8_t* Bb = g_B1 + ((size_t)t * BHn + bh) * Nn * 128;
    int lr = lane & 15, kg = (lane >> 4) * 8;
    f32x4 acc[2][2] = {};
#pragma unroll
    for (int kk = 0; kk < 128; kk += 32) {
        s16x8 a0 = cvt_i8_bf16x8(Ab + (size_t)(row0 + lr) * 128 + kk + kg);
        s16x8 a1 = cvt_i8_bf16x8(Ab + (size_t)(row0 + 16 + lr) * 128 + kk + kg);
        s16x8 b0 = cvt_i8_bf16x8(Bb + (size_t)(col0 + lr) * 128 + kk + kg);
        s16x8 b1 = cvt_i8_bf16x8(Bb + (size_t)(col0 + 16 + lr) * 128 + kk + kg);
        acc[0][0] = __builtin_amdgcn_mfma_f32_16x16x32_bf16(a0, b0, acc[0][0], 0, 0, 0);
        acc[0][1] = __builtin_amdgcn_mfma_f32_16x16x32_bf16(a0, b1, acc[0][1], 0, 0, 0);
        acc[1][0] = __builtin_amdgcn_mfma_f32_16x16x32_bf16(a1, b0, acc[1][0], 0, 0, 0);
        acc[1][1] = __builtin_amdgcn_mfma_f32_16x16x32_bf16(a1, b1, acc[1][1], 0, 0, 0);
    }
    short* Sb = g_S16 + (size_t)t * BHNN + (size_t)bh * Nn * Nn;
#pragma unroll
    for (int i = 0; i < 2; ++i)
#pragma unroll
        for (int j = 0; j < 2; ++j)
#pragma unroll
            for (int q = 0; q < 4; ++q) {
                int row = row0 + i * 16 + (lane >> 4) * 4 + q;
                int col = col0 + j * 16 + lr;
                Sb[row * Nn + col] = (short)(int)acc[i][j][q];
            }
}

// ---------------- aif IF (int) + spiking softmax + sif IF -------------------
__global__ __launch_bounds__(256) void attn_pipeline(float scale_t, float scale_prev, int t) {
    int rowid = blockIdx.x;
    size_t base = (size_t)rowid * Nn;   // row = bh*512 + n
    const short* S = g_S16 + (size_t)t * BHNN;
    int tid = threadIdx.x;
    __shared__ int   redI[4];
    __shared__ float redF[4];

    int X[2], Xold[2];
    int myMax = -128;
#pragma unroll
    for (int u = 0; u < 2; ++u) {
        int c = tid + u * 256;
        int s  = S[base + c];
        int q8 = g_aifq[base + c] + s;      // q*8 integer arithmetic, exact
        int a  = g_aifa[base + c];
        bool pos = (q8 >= 8) && (a < 7);
        bool neg = (q8 < 0) && (a > -8);
        int o = pos ? 1 : (neg ? -1 : 0);
        g_aifq[base + c] = (short)(q8 - (o << 3));
        Xold[u] = a;
        a += o;
        g_aifa[base + c] = (int8_t)a;
        X[u] = a;                            // == smX_new (exact identity)
        myMax = max(myMax, a);
    }
    int  Mold = g_smM[rowid];
    float Sold = g_smS[rowid];
    for (int off = 32; off; off >>= 1) myMax = max(myMax, __shfl_xor(myMax, off));
    if ((tid & 63) == 0) redI[tid >> 6] = myMax;
    __syncthreads();
    int M = max(max(redI[0], redI[1]), max(redI[2], redI[3]));

    float e[2];
    float mySum = 0.0f;
#pragma unroll
    for (int u = 0; u < 2; ++u) { e[u] = expf((float)(X[u] - M)); mySum += e[u]; }
    for (int off = 32; off; off >>= 1) mySum += __shfl_xor(mySum, off);
    if ((tid & 63) == 0) redF[tid >> 6] = mySum;
    __syncthreads();
    float Ssum = (redF[0] + redF[1]) + (redF[2] + redF[3]);
    if (tid == 0) { g_smM[rowid] = M; g_smS[rowid] = Ssum; }

#pragma unroll
    for (int u = 0; u < 2; ++u) {
        int c = tid + u * 256;
        float y = (e[u] / Ssum) * scale_t;
        float yold = 0.0f;
        if (scale_prev >= 0.0f)
            yold = (expf((float)(Xold[u] - Mold)) / Sold) * scale_prev;
        float dlt = y - yold;
        float q = g_sifq[base + c] + dlt;
        int a = g_sifa[base + c];
        bool pos = ((q - 1.0f) >= 0.0f) && (a < 7);
        bool neg = (q < 0.0f) && (a > 0);   // neg_min = 0 (unsym)
        float o = pos ? 1.0f : (neg ? -1.0f : 0.0f);
        g_sifq[base + c] = q - o;
        g_sifa[base + c] = (int8_t)(a + (int)o);
        g_spk[base + c]  = (int8_t)o;        // PV spike operand (acc half == sifa)
    }
}

// ---------------- PV + fused oif: osp = IF(sifa@v + spk@(vacc-v)) -----------
__global__ __launch_bounds__(256) void gemm_pv_oif(int t) {
    int bh = blockIdx.y;
    int tm = blockIdx.x;
    int wave = threadIdx.x >> 6, lane = threadIdx.x & 63;
    int wr = wave >> 1, wc = wave & 1;
    int row0 = tm * 64 + wr * 32, col0 = wc * 32;
    const int8_t* Aa  = g_sifa + (size_t)bh * Nn * Nn;   // [n][512] int8
    const int8_t* Asp = g_spk  + (size_t)bh * Nn * Nn;   // [n][512] int8
    const int8_t* Bb  = g_vT + ((size_t)t * BHn + bh) * Dn * 1024; // [d][1024]
    int lr = lane & 15, kg = (lane >> 4) * 8;
    f32x4 acc[2][2] = {};
    for (int kk = 0; kk < 512; kk += 32) {
        s16x8 a0 = cvt_i8_bf16x8(Aa + (size_t)(row0 + lr) * 512 + kk + kg);
        s16x8 a1 = cvt_i8_bf16x8(Aa + (size_t)(row0 + 16 + lr) * 512 + kk + kg);
        s16x8 b0 = cvt_i8_bf16x8(Bb + (size_t)(col0 + lr) * 1024 + kk + kg);
        s16x8 b1 = cvt_i8_bf16x8(Bb + (size_t)(col0 + 16 + lr) * 1024 + kk + kg);
        acc[0][0] = __builtin_amdgcn_mfma_f32_16x16x32_bf16(a0, b0, acc[0][0], 0, 0, 0);
        acc[0][1] = __builtin_amdgcn_mfma_f32_16x16x32_bf16(a0, b1, acc[0][1], 0, 0, 0);
        acc[1][0] = __builtin_amdgcn_mfma_f32_16x16x32_bf16(a1, b0, acc[1][0], 0, 0, 0);
        acc[1][1] = __builtin_amdgcn_mfma_f32_16x16x32_bf16(a1, b1, acc[1][1], 0, 0, 0);
    }
    for (int kk = 0; kk < 512; kk += 32) {
        s16x8 a0 = cvt_i8_bf16x8(Asp + (size_t)(row0 + lr) * 512 + kk + kg);
        s16x8 a1 = cvt_i8_bf16x8(Asp + (size_t)(row0 + 16 + lr) * 512 + kk + kg);
        s16x8 b0 = cvt_i8_bf16x8(Bb + (size_t)(col0 + lr) * 1024 + 512 + kk + kg);
        s16x8 b1 = cvt_i8_bf16x8(Bb + (size_t)(col0 + 16 + lr) * 1024 + 512 + kk + kg);
        acc[0][0] = __builtin_amdgcn_mfma_f32_16x16x32_bf16(a0, b0, acc[0][0], 0, 0, 0);
        acc[0][1] = __builtin_amdgcn_mfma_f32_16x16x32_bf16(a0, b1, acc[0][1], 0, 0, 0);
        acc[1][0] = __builtin_amdgcn_mfma_f32_16x16x32_bf16(a1, b0, acc[1][0], 0, 0, 0);
        acc[1][1] = __builtin_amdgcn_mfma_f32_16x16x32_bf16(a1, b1, acc[1][1], 0, 0, 0);
    }
    // fused oif epilogue
    int b = bh / 12, h = bh - b * 12;
#pragma unroll
    for (int i = 0; i < 2; ++i)
#pragma unroll
        for (int j = 0; j < 2; ++j)
#pragma unroll
            for (int q = 0; q < 4; ++q) {
                int row = row0 + i * 16 + (lane >> 4) * 4 + q;
                int col = col0 + j * 16 + lr;
                size_t idx = (size_t)bh * Nn * Dn + (size_t)row * Dn + col;
                float x = acc[i][j][q];
                float qd = g_oq[idx]; int a = g_oa[idx];
                float o = if_sym(x, qd, a);
                g_oq[idx] = qd; g_oa[idx] = (int8_t)a;
                g_osp[((size_t)(b * Nn + row)) * Cn + h * 64 + col] = o;
            }
}

extern "C" void kernel_launch(void* const* d_in, const int* in_sizes, int n_in,
                              void* d_out, int out_size, void* d_ws, size_t ws_size,
                              hipStream_t stream) {
    (void)in_sizes; (void)n_in; (void)out_size; (void)d_ws; (void)ws_size;
    const float* x      = (const float*)d_in[0];
    const float* w_qkv  = (const float*)d_in[1];
    const float* w_proj = (const float*)d_in[2];
    float* outp = (float*)d_out;

    init_states<<<2048, 256, 0, stream>>>();

    // all-t qkv = x @ w_qkv^T  [32768 x 2304], K=768 (state-independent!)
    gemm_qkv_big<<<dim3(C3n / 96, (Tn * BNn) / 128), 256, 0, stream>>>(x, w_qkv);
    // all-t q/k/v IF + int8 operand build, states in registers
    if_qkv_all<<<(int)(BHND / 256), 256, 0, stream>>>();
    // all-t attn logits
    gemm_attn_all<<<dim3(64, BHn, Tn), 256, 0, stream>>>();

    for (int t = 0; t < Tn; ++t) {
        float st = (t + 1) < 6 ? (float)(t + 1) / 6.0f : 1.0f;
        float sp = (t == 0) ? -1.0f : ((t < 6) ? (float)t / 6.0f : 1.0f);
        attn_pipeline<<<BHn * Nn, 256, 0, stream>>>(st, sp, t);
        gemm_pv_oif<<<dim3(8, BHn), 256, 0, stream>>>(t);
        gemm_proj_pif<<<dim3(Cn / 96, BNn / 64), 256, 0, stream>>>(
            w_proj, outp + (size_t)t * BNC);
    }
}

// Round 11
// 3726.741 us; speedup vs baseline: 1.5921x; 1.1469x over previous
//
#include <hip/hip_runtime.h>
#include <stdint.h>

typedef __attribute__((ext_vector_type(4))) float f32x4;
typedef __attribute__((ext_vector_type(8))) short s16x8;
typedef __attribute__((ext_vector_type(8))) char  s8x8;
typedef unsigned short u16;

constexpr int    Tn  = 8;
constexpr int    Nn  = 512;
constexpr int    Cn  = 768;
constexpr int    Dn  = 64;
constexpr int    BHn = 96;
constexpr int    BNn = 4096;
constexpr int    C3n = 2304;
constexpr size_t BHND = 3145728;     // B*H*N*D
constexpr size_t BHNN = 25165824;    // B*H*N*N
constexpr size_t BNC  = 3145728;     // B*N*C

// ---- all state lives in device globals (zero-init -> NOBITS) ----
__device__ float  g_qkvt8[(size_t)Tn * BNn * C3n];   // all-t qkv output (302MB)
__device__ int8_t g_A1[(size_t)Tn * BHND * 2];       // [t][bh][n][128] int8
__device__ int8_t g_B1[(size_t)Tn * BHND * 2];
__device__ short  g_S16[(size_t)Tn * BHNN];          // [t][bh][n][n]
__device__ int8_t g_vT[(size_t)Tn * BHn * Dn * 1024];// [t][bh][d][1024] int8
__device__ int8_t g_sifa8[(size_t)Tn * BHNN];        // sif acc after step t (PV A lower)
__device__ int8_t g_spk8[(size_t)Tn * BHNN];         // sif spike at step t (PV A upper)
__device__ float  g_oq[BHND];
__device__ int8_t g_oa[BHND];
__device__ float  g_osp[BNC];
__device__ float  g_pq[BNC];
__device__ int8_t g_pa[BNC];

static __device__ __forceinline__ u16 f2bf(float f) {
    union { float f; unsigned int u; } v; v.f = f;
    return (u16)(v.u >> 16);   // exact for small-integer-valued floats
}

static __device__ __forceinline__ s16x8 cvt_i8_bf16x8(const int8_t* p) {
    s8x8 v = *(const s8x8*)p;
    s16x8 r;
#pragma unroll
    for (int j = 0; j < 8; ++j) r[j] = (short)f2bf((float)v[j]);
    return r;
}

// symmetric IF neuron step (pos_max=7, neg_min=-8)
static __device__ __forceinline__ float if_sym(float x, float& q, int& a) {
    float q2 = q + x;
    bool pos = ((q2 - 1.0f) >= 0.0f) && (a < 7);
    bool neg = (q2 < 0.0f) && (a > -8);
    float out = pos ? 1.0f : (neg ? -1.0f : 0.0f);
    q = q2 - out;
    a += (int)out;
    return out;
}

// ---------------- init persistent states (oif/pif only) ----------------
__global__ __launch_bounds__(256) void init_states() {
    size_t i = (size_t)blockIdx.x * 256 + threadIdx.x;   // [0, BHND)
    g_oq[i] = 0.5f; g_oa[i] = 0;
    g_pq[i] = 0.5f; g_pa[i] = 0;       // BNC == BHND
}

// ---------------- fp32 NT GEMM (frozen round-9 structure, bit-exact chain) --
// qkv for ALL t: [32768 x 2304], K=768. Tile 128x96, grid 24x256 = 6144 blocks.
__global__ __launch_bounds__(256) void gemm_qkv_big(
    const float* __restrict__ A, const float* __restrict__ B)
{
    __shared__ __align__(16) float As[16][132];   // 128+4
    __shared__ __align__(16) float Bs[16][100];   // 96+4
    const int tid = threadIdx.x;
    const int m0 = blockIdx.y * 128;
    const int j0 = blockIdx.x * 96;
    const int ty = tid >> 4, tx = tid & 15;

    float acc[8][6];
#pragma unroll
    for (int i = 0; i < 8; ++i)
#pragma unroll
        for (int j = 0; j < 6; ++j) acc[i][j] = 0.0f;

    for (int k0 = 0; k0 < Cn; k0 += 16) {
#pragma unroll
        for (int u = 0; u < 2; ++u) {
            int f = tid + u * 256;
            int row = f >> 2;
            int c4 = (f & 3) * 4;
            float4 av = *(const float4*)(A + (size_t)(m0 + row) * Cn + k0 + c4);
            As[c4 + 0][row] = av.x; As[c4 + 1][row] = av.y;
            As[c4 + 2][row] = av.z; As[c4 + 3][row] = av.w;
        }
#pragma unroll
        for (int u = 0; u < 3; ++u) {
            int f = tid + u * 256;
            int row = f >> 3;
            int c2 = (f & 7) * 2;
            float2 bv = *(const float2*)(B + (size_t)(j0 + row) * Cn + k0 + c2);
            Bs[c2][row] = bv.x; Bs[c2 + 1][row] = bv.y;
        }
        __syncthreads();
#pragma unroll
        for (int k = 0; k < 16; ++k) {
            alignas(16) float a[8];
            alignas(8)  float b[6];
            *(float4*)(a)     = *(const float4*)&As[k][ty * 8];
            *(float4*)(a + 4) = *(const float4*)&As[k][ty * 8 + 4];
#pragma unroll
            for (int u = 0; u < 3; ++u) {
                float2 t = *(const float2*)&Bs[k][tx * 2 + 32 * u];
                b[2 * u] = t.x; b[2 * u + 1] = t.y;
            }
#pragma unroll
            for (int i = 0; i < 8; ++i)
#pragma unroll
                for (int j = 0; j < 6; ++j)
                    acc[i][j] = fmaf(a[i], b[j], acc[i][j]);
        }
        __syncthreads();
    }
#pragma unroll
    for (int i = 0; i < 8; ++i) {
        float* cp = g_qkvt8 + (size_t)(m0 + ty * 8 + i) * C3n + j0 + tx * 2;
#pragma unroll
        for (int u = 0; u < 3; ++u) {
            float2 t; t.x = acc[i][2 * u]; t.y = acc[i][2 * u + 1];
            *(float2*)(cp + 32 * u) = t;
        }
    }
}

// proj: [4096 x 768], K=768. Tile 64x96 + fused pif epilogue.
__global__ __launch_bounds__(256) void gemm_proj_pif(
    const float* __restrict__ B, float* __restrict__ outp)
{
    __shared__ __align__(16) float As[16][68];    // 64+4
    __shared__ __align__(16) float Bs[16][100];
    const int tid = threadIdx.x;
    const int m0 = blockIdx.y * 64;
    const int j0 = blockIdx.x * 96;
    const int ty = tid >> 4, tx = tid & 15;
    const float* A = g_osp;

    float acc[4][6];
#pragma unroll
    for (int i = 0; i < 4; ++i)
#pragma unroll
        for (int j = 0; j < 6; ++j) acc[i][j] = 0.0f;

    for (int k0 = 0; k0 < Cn; k0 += 16) {
        {
            int row = tid >> 2;
            int c4 = (tid & 3) * 4;
            float4 av = *(const float4*)(A + (size_t)(m0 + row) * Cn + k0 + c4);
            As[c4 + 0][row] = av.x; As[c4 + 1][row] = av.y;
            As[c4 + 2][row] = av.z; As[c4 + 3][row] = av.w;
        }
#pragma unroll
        for (int u = 0; u < 3; ++u) {
            int f = tid + u * 256;
            int r2 = f >> 3;
            int c2 = (f & 7) * 2;
            float2 bv = *(const float2*)(B + (size_t)(j0 + r2) * Cn + k0 + c2);
            Bs[c2][r2] = bv.x; Bs[c2 + 1][r2] = bv.y;
        }
        __syncthreads();
#pragma unroll
        for (int k = 0; k < 16; ++k) {
            alignas(16) float a[4];
            alignas(8)  float b[6];
            *(float4*)(a) = *(const float4*)&As[k][ty * 4];
#pragma unroll
            for (int u = 0; u < 3; ++u) {
                float2 t = *(const float2*)&Bs[k][tx * 2 + 32 * u];
                b[2 * u] = t.x; b[2 * u + 1] = t.y;
            }
#pragma unroll
            for (int i = 0; i < 4; ++i)
#pragma unroll
                for (int j = 0; j < 6; ++j)
                    acc[i][j] = fmaf(a[i], b[j], acc[i][j]);
        }
        __syncthreads();
    }
    // fused pif epilogue: IF state update + spike write directly to output
#pragma unroll
    for (int i = 0; i < 4; ++i) {
        size_t rbase = (size_t)(m0 + ty * 4 + i) * Cn + j0 + tx * 2;
#pragma unroll
        for (int u = 0; u < 3; ++u) {
#pragma unroll
            for (int c = 0; c < 2; ++c) {
                size_t idx = rbase + 32 * u + c;
                float x = acc[i][2 * u + c];
                float qd = g_pq[idx]; int a = g_pa[idx];
                float o = if_sym(x, qd, a);
                g_pq[idx] = qd; g_pa[idx] = (int8_t)a;
                outp[idx] = o;
            }
        }
    }
}

// ---------------- q/k/v IF for ALL t (states in registers, int8 operands) ---
__global__ __launch_bounds__(256) void if_qkv_all() {
    int idx = blockIdx.x * 256 + threadIdx.x;   // [0, BHND)
    int d = idx & 63;
    int n = (idx >> 6) & 511;
    int bh = idx >> 15;
    int b = bh / 12, h = bh - b * 12;

    float fq = 0.5f, fk = 0.5f, fv = 0.5f;
    int aq = 0, ak = 0, av = 0;

    for (int t = 0; t < Tn; ++t) {
        size_t qrow = ((size_t)((t * 8 + b) * Nn + n)) * C3n + h * 64 + d;
        float xq = g_qkvt8[qrow];
        float xk = g_qkvt8[qrow + 768];
        float xv = g_qkvt8[qrow + 1536];

        float so_q = if_sym(xq, fq, aq);
        float so_k = if_sym(xk, fk, ak);
        float so_v = if_sym(xv, fv, av);

        // attn operands (K=128): A1 = [acc_q | q_spike], B1 = [k_spike | k_acc-k]
        size_t a1b = (((size_t)t * BHn + bh) * Nn + n) * 128 + d;
        g_A1[a1b]      = (int8_t)aq;
        g_A1[a1b + 64] = (int8_t)so_q;
        g_B1[a1b]      = (int8_t)so_k;
        g_B1[a1b + 64] = (int8_t)(ak - (int)so_k);

        // PV B operand transposed: vT[t][bh][d][k]: k<512 v, k>=512 v_acc-v
        size_t vtb = (((size_t)t * BHn + bh) * Dn + d) * 1024 + n;
        g_vT[vtb]       = (int8_t)so_v;
        g_vT[vtb + 512] = (int8_t)(av - (int)so_v);
    }
}

// ---------------- attn logits for ALL t: S = accq@k^T + q@(kacc-k)^T --------
__global__ __launch_bounds__(256) void gemm_attn_all() {
    int t = blockIdx.z;
    int bh = blockIdx.y;
    int tm = blockIdx.x >> 3, tn = blockIdx.x & 7;
    int wave = threadIdx.x >> 6, lane = threadIdx.x & 63;
    int wr = wave >> 1, wc = wave & 1;
    int row0 = tm * 64 + wr * 32, col0 = tn * 64 + wc * 32;
    const int8_t* Ab = g_A1 + ((size_t)t * BHn + bh) * Nn * 128;
    const int8_t* Bb = g_B1 + ((size_t)t * BHn + bh) * Nn * 128;
    int lr = lane & 15, kg = (lane >> 4) * 8;
    f32x4 acc[2][2] = {};
#pragma unroll
    for (int kk = 0; kk < 128; kk += 32) {
        s16x8 a0 = cvt_i8_bf16x8(Ab + (size_t)(row0 + lr) * 128 + kk + kg);
        s16x8 a1 = cvt_i8_bf16x8(Ab + (size_t)(row0 + 16 + lr) * 128 + kk + kg);
        s16x8 b0 = cvt_i8_bf16x8(Bb + (size_t)(col0 + lr) * 128 + kk + kg);
        s16x8 b1 = cvt_i8_bf16x8(Bb + (size_t)(col0 + 16 + lr) * 128 + kk + kg);
        acc[0][0] = __builtin_amdgcn_mfma_f32_16x16x32_bf16(a0, b0, acc[0][0], 0, 0, 0);
        acc[0][1] = __builtin_amdgcn_mfma_f32_16x16x32_bf16(a0, b1, acc[0][1], 0, 0, 0);
        acc[1][0] = __builtin_amdgcn_mfma_f32_16x16x32_bf16(a1, b0, acc[1][0], 0, 0, 0);
        acc[1][1] = __builtin_amdgcn_mfma_f32_16x16x32_bf16(a1, b1, acc[1][1], 0, 0, 0);
    }
    short* Sb = g_S16 + (size_t)t * BHNN + (size_t)bh * Nn * Nn;
#pragma unroll
    for (int i = 0; i < 2; ++i)
#pragma unroll
        for (int j = 0; j < 2; ++j)
#pragma unroll
            for (int q = 0; q < 4; ++q) {
                int row = row0 + i * 16 + (lane >> 4) * 4 + q;
                int col = col0 + j * 16 + lr;
                Sb[row * Nn + col] = (short)(int)acc[i][j][q];
            }
}

// ---------------- ALL-t aif IF + spiking softmax + sif IF (reg state) -------
// One block per attention row; runs the full 8-step recurrence with aif/sif
// state and y_old (== reference sm_Y) in registers. Reduction code identical
// per t to the previously-passing per-step kernel.
__global__ __launch_bounds__(256) void attn_pipeline_all() {
    int rowid = blockIdx.x;                  // bh*512 + n
    size_t base = (size_t)rowid * Nn;
    int tid = threadIdx.x;
    __shared__ int   redI[4];
    __shared__ float redF[4];

    int   aq8[2]  = {4, 4};                  // aif q*8 (q=0.5)
    int   aac[2]  = {0, 0};                  // aif acc == smX
    float sq[2]   = {0.5f, 0.5f};            // sif q
    int   sa[2]   = {0, 0};                  // sif acc
    float yold[2] = {0.0f, 0.0f};            // sm_Y

    for (int t = 0; t < Tn; ++t) {
        float st = (t + 1) < 6 ? (float)(t + 1) / 6.0f : 1.0f;
        const short* S = g_S16 + (size_t)t * BHNN;

        int X[2];
        int myMax = -128;
#pragma unroll
        for (int u = 0; u < 2; ++u) {
            int c = tid + u * 256;
            int s  = S[base + c];
            int q8 = aq8[u] + s;
            int a  = aac[u];
            bool pos = (q8 >= 8) && (a < 7);
            bool neg = (q8 < 0) && (a > -8);
            int o = pos ? 1 : (neg ? -1 : 0);
            aq8[u] = q8 - (o << 3);
            a += o;
            aac[u] = a;
            X[u] = a;
            myMax = max(myMax, a);
        }
        for (int off = 32; off; off >>= 1) myMax = max(myMax, __shfl_xor(myMax, off));
        if ((tid & 63) == 0) redI[tid >> 6] = myMax;
        __syncthreads();
        int M = max(max(redI[0], redI[1]), max(redI[2], redI[3]));

        float e[2];
        float mySum = 0.0f;
#pragma unroll
        for (int u = 0; u < 2; ++u) { e[u] = expf((float)(X[u] - M)); mySum += e[u]; }
        for (int off = 32; off; off >>= 1) mySum += __shfl_xor(mySum, off);
        if ((tid & 63) == 0) redF[tid >> 6] = mySum;
        __syncthreads();
        float Ssum = (redF[0] + redF[1]) + (redF[2] + redF[3]);

#pragma unroll
        for (int u = 0; u < 2; ++u) {
            int c = tid + u * 256;
            float y = (e[u] / Ssum) * st;
            float dlt = y - yold[u];
            yold[u] = y;
            float q = sq[u] + dlt;
            int a = sa[u];
            bool pos = ((q - 1.0f) >= 0.0f) && (a < 7);
            bool neg = (q < 0.0f) && (a > 0);   // neg_min = 0 (unsym)
            float o = pos ? 1.0f : (neg ? -1.0f : 0.0f);
            sq[u] = q - o;
            a += (int)o;
            sa[u] = a;
            g_sifa8[(size_t)t * BHNN + base + c] = (int8_t)a;
            g_spk8[(size_t)t * BHNN + base + c]  = (int8_t)o;
        }
    }
}

// ---------------- PV + fused oif: osp = IF(sifa@v + spk@(vacc-v)) -----------
__global__ __launch_bounds__(256) void gemm_pv_oif(int t) {
    int bh = blockIdx.y;
    int tm = blockIdx.x;
    int wave = threadIdx.x >> 6, lane = threadIdx.x & 63;
    int wr = wave >> 1, wc = wave & 1;
    int row0 = tm * 64 + wr * 32, col0 = wc * 32;
    const int8_t* Aa  = g_sifa8 + (size_t)t * BHNN + (size_t)bh * Nn * Nn;
    const int8_t* Asp = g_spk8  + (size_t)t * BHNN + (size_t)bh * Nn * Nn;
    const int8_t* Bb  = g_vT + ((size_t)t * BHn + bh) * Dn * 1024; // [d][1024]
    int lr = lane & 15, kg = (lane >> 4) * 8;
    f32x4 acc[2][2] = {};
    for (int kk = 0; kk < 512; kk += 32) {
        s16x8 a0 = cvt_i8_bf16x8(Aa + (size_t)(row0 + lr) * 512 + kk + kg);
        s16x8 a1 = cvt_i8_bf16x8(Aa + (size_t)(row0 + 16 + lr) * 512 + kk + kg);
        s16x8 b0 = cvt_i8_bf16x8(Bb + (size_t)(col0 + lr) * 1024 + kk + kg);
        s16x8 b1 = cvt_i8_bf16x8(Bb + (size_t)(col0 + 16 + lr) * 1024 + kk + kg);
        acc[0][0] = __builtin_amdgcn_mfma_f32_16x16x32_bf16(a0, b0, acc[0][0], 0, 0, 0);
        acc[0][1] = __builtin_amdgcn_mfma_f32_16x16x32_bf16(a0, b1, acc[0][1], 0, 0, 0);
        acc[1][0] = __builtin_amdgcn_mfma_f32_16x16x32_bf16(a1, b0, acc[1][0], 0, 0, 0);
        acc[1][1] = __builtin_amdgcn_mfma_f32_16x16x32_bf16(a1, b1, acc[1][1], 0, 0, 0);
    }
    for (int kk = 0; kk < 512; kk += 32) {
        s16x8 a0 = cvt_i8_bf16x8(Asp + (size_t)(row0 + lr) * 512 + kk + kg);
        s16x8 a1 = cvt_i8_bf16x8(Asp + (size_t)(row0 + 16 + lr) * 512 + kk + kg);
        s16x8 b0 = cvt_i8_bf16x8(Bb + (size_t)(col0 + lr) * 1024 + 512 + kk + kg);
        s16x8 b1 = cvt_i8_bf16x8(Bb + (size_t)(col0 + 16 + lr) * 1024 + 512 + kk + kg);
        acc[0][0] = __builtin_amdgcn_mfma_f32_16x16x32_bf16(a0, b0, acc[0][0], 0, 0, 0);
        acc[0][1] = __builtin_amdgcn_mfma_f32_16x16x32_bf16(a0, b1, acc[0][1], 0, 0, 0);
        acc[1][0] = __builtin_amdgcn_mfma_f32_16x16x32_bf16(a1, b0, acc[1][0], 0, 0, 0);
        acc[1][1] = __builtin_amdgcn_mfma_f32_16x16x32_bf16(a1, b1, acc[1][1], 0, 0, 0);
    }
    // fused oif epilogue
    int b = bh / 12, h = bh - b * 12;
#pragma unroll
    for (int i = 0; i < 2; ++i)
#pragma unroll
        for (int j = 0; j < 2; ++j)
#pragma unroll
            for (int q = 0; q < 4; ++q) {
                int row = row0 + i * 16 + (lane >> 4) * 4 + q;
                int col = col0 + j * 16 + lr;
                size_t idx = (size_t)bh * Nn * Dn + (size_t)row * Dn + col;
                float x = acc[i][j][q];
                float qd = g_oq[idx]; int a = g_oa[idx];
                float o = if_sym(x, qd, a);
                g_oq[idx] = qd; g_oa[idx] = (int8_t)a;
                g_osp[((size_t)(b * Nn + row)) * Cn + h * 64 + col] = o;
            }
}

extern "C" void kernel_launch(void* const* d_in, const int* in_sizes, int n_in,
                              void* d_out, int out_size, void* d_ws, size_t ws_size,
                              hipStream_t stream) {
    (void)in_sizes; (void)n_in; (void)out_size; (void)d_ws; (void)ws_size;
    const float* x      = (const float*)d_in[0];
    const float* w_qkv  = (const float*)d_in[1];
    const float* w_proj = (const float*)d_in[2];
    float* outp = (float*)d_out;

    init_states<<<(int)(BHND / 256), 256, 0, stream>>>();

    // all-t qkv = x @ w_qkv^T  [32768 x 2304], K=768 (state-independent!)
    gemm_qkv_big<<<dim3(C3n / 96, (Tn * BNn) / 128), 256, 0, stream>>>(x, w_qkv);
    // all-t q/k/v IF + int8 operand build, states in registers
    if_qkv_all<<<(int)(BHND / 256), 256, 0, stream>>>();
    // all-t attn logits
    gemm_attn_all<<<dim3(64, BHn, Tn), 256, 0, stream>>>();
    // all-t aif + softmax + sif recurrence, state in registers
    attn_pipeline_all<<<BHn * Nn, 256, 0, stream>>>();

    for (int t = 0; t < Tn; ++t) {
        gemm_pv_oif<<<dim3(8, BHn), 256, 0, stream>>>(t);
        gemm_proj_pif<<<dim3(Cn / 96, BNn / 64), 256, 0, stream>>>(
            w_proj, outp + (size_t)t * BNC);
    }
}

// Round 12
// 3484.975 us; speedup vs baseline: 1.7025x; 1.0694x over previous
//
#include <hip/hip_runtime.h>
#include <stdint.h>

typedef __attribute__((ext_vector_type(4))) float f32x4;
typedef __attribute__((ext_vector_type(8))) short s16x8;
typedef __attribute__((ext_vector_type(8))) char  s8x8;
typedef unsigned short u16;

constexpr int    Tn  = 8;
constexpr int    Nn  = 512;
constexpr int    Cn  = 768;
constexpr int    Dn  = 64;
constexpr int    BHn = 96;
constexpr int    BNn = 4096;
constexpr int    C3n = 2304;
constexpr size_t BHND = 3145728;     // B*H*N*D
constexpr size_t BHNN = 25165824;    // B*H*N*N
constexpr size_t BNC  = 3145728;     // B*N*C

// ---- all buffers are produced-before-consumed each call (no persistent state,
// ---- no init kernel needed; zero-init globals -> NOBITS) ----
__device__ float  g_qkvt8[(size_t)Tn * BNn * C3n];   // all-t qkv output (302MB)
__device__ int8_t g_A1[(size_t)Tn * BHND * 2];       // [t][bh][n][128] int8
__device__ int8_t g_B1[(size_t)Tn * BHND * 2];
__device__ short  g_S16[(size_t)Tn * BHNN];          // [t][bh][n][n]
__device__ int8_t g_vT[(size_t)Tn * BHn * Dn * 1024];// [t][bh][d][1024] int8
__device__ int8_t g_sifa8[(size_t)Tn * BHNN];        // sif acc after step t
__device__ int8_t g_spk8[(size_t)Tn * BHNN];         // sif spike at step t
__device__ float  g_pv8[(size_t)Tn * BHND];          // all-t PV output
__device__ float  g_osp8[(size_t)Tn * BNC];          // all-t oif spikes [t][b*n][C]
__device__ float  g_proj8[(size_t)Tn * BNC];         // all-t proj output

static __device__ __forceinline__ u16 f2bf(float f) {
    union { float f; unsigned int u; } v; v.f = f;
    return (u16)(v.u >> 16);   // exact for small-integer-valued floats
}

static __device__ __forceinline__ s16x8 cvt_i8_bf16x8(const int8_t* p) {
    s8x8 v = *(const s8x8*)p;
    s16x8 r;
#pragma unroll
    for (int j = 0; j < 8; ++j) r[j] = (short)f2bf((float)v[j]);
    return r;
}

// symmetric IF neuron step (pos_max=7, neg_min=-8)
static __device__ __forceinline__ float if_sym(float x, float& q, int& a) {
    float q2 = q + x;
    bool pos = ((q2 - 1.0f) >= 0.0f) && (a < 7);
    bool neg = (q2 < 0.0f) && (a > -8);
    float out = pos ? 1.0f : (neg ? -1.0f : 0.0f);
    q = q2 - out;
    a += (int)out;
    return out;
}

// ---------------- fp32 NT GEMM (frozen structure, bit-exact chain) ----------
// qkv for ALL t: [32768 x 2304], K=768. Tile 128x96, grid 24x256 = 6144 blocks.
__global__ __launch_bounds__(256) void gemm_qkv_big(
    const float* __restrict__ A, const float* __restrict__ B)
{
    __shared__ __align__(16) float As[16][132];   // 128+4
    __shared__ __align__(16) float Bs[16][100];   // 96+4
    const int tid = threadIdx.x;
    const int m0 = blockIdx.y * 128;
    const int j0 = blockIdx.x * 96;
    const int ty = tid >> 4, tx = tid & 15;

    float acc[8][6];
#pragma unroll
    for (int i = 0; i < 8; ++i)
#pragma unroll
        for (int j = 0; j < 6; ++j) acc[i][j] = 0.0f;

    for (int k0 = 0; k0 < Cn; k0 += 16) {
#pragma unroll
        for (int u = 0; u < 2; ++u) {
            int f = tid + u * 256;
            int row = f >> 2;
            int c4 = (f & 3) * 4;
            float4 av = *(const float4*)(A + (size_t)(m0 + row) * Cn + k0 + c4);
            As[c4 + 0][row] = av.x; As[c4 + 1][row] = av.y;
            As[c4 + 2][row] = av.z; As[c4 + 3][row] = av.w;
        }
#pragma unroll
        for (int u = 0; u < 3; ++u) {
            int f = tid + u * 256;
            int row = f >> 3;
            int c2 = (f & 7) * 2;
            float2 bv = *(const float2*)(B + (size_t)(j0 + row) * Cn + k0 + c2);
            Bs[c2][row] = bv.x; Bs[c2 + 1][row] = bv.y;
        }
        __syncthreads();
#pragma unroll
        for (int k = 0; k < 16; ++k) {
            alignas(16) float a[8];
            alignas(8)  float b[6];
            *(float4*)(a)     = *(const float4*)&As[k][ty * 8];
            *(float4*)(a + 4) = *(const float4*)&As[k][ty * 8 + 4];
#pragma unroll
            for (int u = 0; u < 3; ++u) {
                float2 t = *(const float2*)&Bs[k][tx * 2 + 32 * u];
                b[2 * u] = t.x; b[2 * u + 1] = t.y;
            }
#pragma unroll
            for (int i = 0; i < 8; ++i)
#pragma unroll
                for (int j = 0; j < 6; ++j)
                    acc[i][j] = fmaf(a[i], b[j], acc[i][j]);
        }
        __syncthreads();
    }
#pragma unroll
    for (int i = 0; i < 8; ++i) {
        float* cp = g_qkvt8 + (size_t)(m0 + ty * 8 + i) * C3n + j0 + tx * 2;
#pragma unroll
        for (int u = 0; u < 3; ++u) {
            float2 t; t.x = acc[i][2 * u]; t.y = acc[i][2 * u + 1];
            *(float2*)(cp + 32 * u) = t;
        }
    }
}

// proj for ALL t: [32768 x 768], K=768. Same frozen structure, grid 8x256.
__global__ __launch_bounds__(256) void gemm_proj_all(const float* __restrict__ B)
{
    __shared__ __align__(16) float As[16][132];
    __shared__ __align__(16) float Bs[16][100];
    const int tid = threadIdx.x;
    const int m0 = blockIdx.y * 128;
    const int j0 = blockIdx.x * 96;
    const int ty = tid >> 4, tx = tid & 15;
    const float* A = g_osp8;

    float acc[8][6];
#pragma unroll
    for (int i = 0; i < 8; ++i)
#pragma unroll
        for (int j = 0; j < 6; ++j) acc[i][j] = 0.0f;

    for (int k0 = 0; k0 < Cn; k0 += 16) {
#pragma unroll
        for (int u = 0; u < 2; ++u) {
            int f = tid + u * 256;
            int row = f >> 2;
            int c4 = (f & 3) * 4;
            float4 av = *(const float4*)(A + (size_t)(m0 + row) * Cn + k0 + c4);
            As[c4 + 0][row] = av.x; As[c4 + 1][row] = av.y;
            As[c4 + 2][row] = av.z; As[c4 + 3][row] = av.w;
        }
#pragma unroll
        for (int u = 0; u < 3; ++u) {
            int f = tid + u * 256;
            int row = f >> 3;
            int c2 = (f & 7) * 2;
            float2 bv = *(const float2*)(B + (size_t)(j0 + row) * Cn + k0 + c2);
            Bs[c2][row] = bv.x; Bs[c2 + 1][row] = bv.y;
        }
        __syncthreads();
#pragma unroll
        for (int k = 0; k < 16; ++k) {
            alignas(16) float a[8];
            alignas(8)  float b[6];
            *(float4*)(a)     = *(const float4*)&As[k][ty * 8];
            *(float4*)(a + 4) = *(const float4*)&As[k][ty * 8 + 4];
#pragma unroll
            for (int u = 0; u < 3; ++u) {
                float2 t = *(const float2*)&Bs[k][tx * 2 + 32 * u];
                b[2 * u] = t.x; b[2 * u + 1] = t.y;
            }
#pragma unroll
            for (int i = 0; i < 8; ++i)
#pragma unroll
                for (int j = 0; j < 6; ++j)
                    acc[i][j] = fmaf(a[i], b[j], acc[i][j]);
        }
        __syncthreads();
    }
#pragma unroll
    for (int i = 0; i < 8; ++i) {
        float* cp = g_proj8 + (size_t)(m0 + ty * 8 + i) * Cn + j0 + tx * 2;
#pragma unroll
        for (int u = 0; u < 3; ++u) {
            float2 t; t.x = acc[i][2 * u]; t.y = acc[i][2 * u + 1];
            *(float2*)(cp + 32 * u) = t;
        }
    }
}

// ---------------- q/k/v IF for ALL t (states in registers, int8 operands) ---
__global__ __launch_bounds__(256) void if_qkv_all() {
    int idx = blockIdx.x * 256 + threadIdx.x;   // [0, BHND)
    int d = idx & 63;
    int n = (idx >> 6) & 511;
    int bh = idx >> 15;
    int b = bh / 12, h = bh - b * 12;

    float fq = 0.5f, fk = 0.5f, fv = 0.5f;
    int aq = 0, ak = 0, av = 0;

    for (int t = 0; t < Tn; ++t) {
        size_t qrow = ((size_t)((t * 8 + b) * Nn + n)) * C3n + h * 64 + d;
        float xq = g_qkvt8[qrow];
        float xk = g_qkvt8[qrow + 768];
        float xv = g_qkvt8[qrow + 1536];

        float so_q = if_sym(xq, fq, aq);
        float so_k = if_sym(xk, fk, ak);
        float so_v = if_sym(xv, fv, av);

        // attn operands (K=128): A1 = [acc_q | q_spike], B1 = [k_spike | k_acc-k]
        size_t a1b = (((size_t)t * BHn + bh) * Nn + n) * 128 + d;
        g_A1[a1b]      = (int8_t)aq;
        g_A1[a1b + 64] = (int8_t)so_q;
        g_B1[a1b]      = (int8_t)so_k;
        g_B1[a1b + 64] = (int8_t)(ak - (int)so_k);

        // PV B operand transposed: vT[t][bh][d][k]: k<512 v, k>=512 v_acc-v
        size_t vtb = (((size_t)t * BHn + bh) * Dn + d) * 1024 + n;
        g_vT[vtb]       = (int8_t)so_v;
        g_vT[vtb + 512] = (int8_t)(av - (int)so_v);
    }
}

// ---------------- attn logits for ALL t: S = accq@k^T + q@(kacc-k)^T --------
__global__ __launch_bounds__(256) void gemm_attn_all() {
    int t = blockIdx.z;
    int bh = blockIdx.y;
    int tm = blockIdx.x >> 3, tn = blockIdx.x & 7;
    int wave = threadIdx.x >> 6, lane = threadIdx.x & 63;
    int wr = wave >> 1, wc = wave & 1;
    int row0 = tm * 64 + wr * 32, col0 = tn * 64 + wc * 32;
    const int8_t* Ab = g_A1 + ((size_t)t * BHn + bh) * Nn * 128;
    const int8_t* Bb = g_B1 + ((size_t)t * BHn + bh) * Nn * 128;
    int lr = lane & 15, kg = (lane >> 4) * 8;
    f32x4 acc[2][2] = {};
#pragma unroll
    for (int kk = 0; kk < 128; kk += 32) {
        s16x8 a0 = cvt_i8_bf16x8(Ab + (size_t)(row0 + lr) * 128 + kk + kg);
        s16x8 a1 = cvt_i8_bf16x8(Ab + (size_t)(row0 + 16 + lr) * 128 + kk + kg);
        s16x8 b0 = cvt_i8_bf16x8(Bb + (size_t)(col0 + lr) * 128 + kk + kg);
        s16x8 b1 = cvt_i8_bf16x8(Bb + (size_t)(col0 + 16 + lr) * 128 + kk + kg);
        acc[0][0] = __builtin_amdgcn_mfma_f32_16x16x32_bf16(a0, b0, acc[0][0], 0, 0, 0);
        acc[0][1] = __builtin_amdgcn_mfma_f32_16x16x32_bf16(a0, b1, acc[0][1], 0, 0, 0);
        acc[1][0] = __builtin_amdgcn_mfma_f32_16x16x32_bf16(a1, b0, acc[1][0], 0, 0, 0);
        acc[1][1] = __builtin_amdgcn_mfma_f32_16x16x32_bf16(a1, b1, acc[1][1], 0, 0, 0);
    }
    short* Sb = g_S16 + (size_t)t * BHNN + (size_t)bh * Nn * Nn;
#pragma unroll
    for (int i = 0; i < 2; ++i)
#pragma unroll
        for (int j = 0; j < 2; ++j)
#pragma unroll
            for (int q = 0; q < 4; ++q) {
                int row = row0 + i * 16 + (lane >> 4) * 4 + q;
                int col = col0 + j * 16 + lr;
                Sb[row * Nn + col] = (short)(int)acc[i][j][q];
            }
}

// ---------------- ALL-t aif IF + spiking softmax + sif IF (reg state) -------
__global__ __launch_bounds__(256) void attn_pipeline_all() {
    int rowid = blockIdx.x;                  // bh*512 + n
    size_t base = (size_t)rowid * Nn;
    int tid = threadIdx.x;
    __shared__ int   redI[4];
    __shared__ float redF[4];

    int   aq8[2]  = {4, 4};                  // aif q*8 (q=0.5)
    int   aac[2]  = {0, 0};                  // aif acc == smX
    float sq[2]   = {0.5f, 0.5f};            // sif q
    int   sa[2]   = {0, 0};                  // sif acc
    float yold[2] = {0.0f, 0.0f};            // sm_Y

    for (int t = 0; t < Tn; ++t) {
        float st = (t + 1) < 6 ? (float)(t + 1) / 6.0f : 1.0f;
        const short* S = g_S16 + (size_t)t * BHNN;

        int X[2];
        int myMax = -128;
#pragma unroll
        for (int u = 0; u < 2; ++u) {
            int c = tid + u * 256;
            int s  = S[base + c];
            int q8 = aq8[u] + s;
            int a  = aac[u];
            bool pos = (q8 >= 8) && (a < 7);
            bool neg = (q8 < 0) && (a > -8);
            int o = pos ? 1 : (neg ? -1 : 0);
            aq8[u] = q8 - (o << 3);
            a += o;
            aac[u] = a;
            X[u] = a;
            myMax = max(myMax, a);
        }
        for (int off = 32; off; off >>= 1) myMax = max(myMax, __shfl_xor(myMax, off));
        if ((tid & 63) == 0) redI[tid >> 6] = myMax;
        __syncthreads();
        int M = max(max(redI[0], redI[1]), max(redI[2], redI[3]));

        float e[2];
        float mySum = 0.0f;
#pragma unroll
        for (int u = 0; u < 2; ++u) { e[u] = expf((float)(X[u] - M)); mySum += e[u]; }
        for (int off = 32; off; off >>= 1) mySum += __shfl_xor(mySum, off);
        if ((tid & 63) == 0) redF[tid >> 6] = mySum;
        __syncthreads();
        float Ssum = (redF[0] + redF[1]) + (redF[2] + redF[3]);

#pragma unroll
        for (int u = 0; u < 2; ++u) {
            int c = tid + u * 256;
            float y = (e[u] / Ssum) * st;
            float dlt = y - yold[u];
            yold[u] = y;
            float q = sq[u] + dlt;
            int a = sa[u];
            bool pos = ((q - 1.0f) >= 0.0f) && (a < 7);
            bool neg = (q < 0.0f) && (a > 0);   // neg_min = 0 (unsym)
            float o = pos ? 1.0f : (neg ? -1.0f : 0.0f);
            sq[u] = q - o;
            a += (int)o;
            sa[u] = a;
            g_sifa8[(size_t)t * BHNN + base + c] = (int8_t)a;
            g_spk8[(size_t)t * BHNN + base + c]  = (int8_t)o;
        }
    }
}

// ---------------- PV for ALL t: pv8 = sifa@v + spk@(vacc-v) (exact ints) ----
__global__ __launch_bounds__(256) void gemm_pv_all() {
    int t = blockIdx.z;
    int bh = blockIdx.y;
    int tm = blockIdx.x;
    int wave = threadIdx.x >> 6, lane = threadIdx.x & 63;
    int wr = wave >> 1, wc = wave & 1;
    int row0 = tm * 64 + wr * 32, col0 = wc * 32;
    const int8_t* Aa  = g_sifa8 + (size_t)t * BHNN + (size_t)bh * Nn * Nn;
    const int8_t* Asp = g_spk8  + (size_t)t * BHNN + (size_t)bh * Nn * Nn;
    const int8_t* Bb  = g_vT + ((size_t)t * BHn + bh) * Dn * 1024; // [d][1024]
    int lr = lane & 15, kg = (lane >> 4) * 8;
    f32x4 acc[2][2] = {};
    for (int kk = 0; kk < 512; kk += 32) {
        s16x8 a0 = cvt_i8_bf16x8(Aa + (size_t)(row0 + lr) * 512 + kk + kg);
        s16x8 a1 = cvt_i8_bf16x8(Aa + (size_t)(row0 + 16 + lr) * 512 + kk + kg);
        s16x8 b0 = cvt_i8_bf16x8(Bb + (size_t)(col0 + lr) * 1024 + kk + kg);
        s16x8 b1 = cvt_i8_bf16x8(Bb + (size_t)(col0 + 16 + lr) * 1024 + kk + kg);
        acc[0][0] = __builtin_amdgcn_mfma_f32_16x16x32_bf16(a0, b0, acc[0][0], 0, 0, 0);
        acc[0][1] = __builtin_amdgcn_mfma_f32_16x16x32_bf16(a0, b1, acc[0][1], 0, 0, 0);
        acc[1][0] = __builtin_amdgcn_mfma_f32_16x16x32_bf16(a1, b0, acc[1][0], 0, 0, 0);
        acc[1][1] = __builtin_amdgcn_mfma_f32_16x16x32_bf16(a1, b1, acc[1][1], 0, 0, 0);
    }
    for (int kk = 0; kk < 512; kk += 32) {
        s16x8 a0 = cvt_i8_bf16x8(Asp + (size_t)(row0 + lr) * 512 + kk + kg);
        s16x8 a1 = cvt_i8_bf16x8(Asp + (size_t)(row0 + 16 + lr) * 512 + kk + kg);
        s16x8 b0 = cvt_i8_bf16x8(Bb + (size_t)(col0 + lr) * 1024 + 512 + kk + kg);
        s16x8 b1 = cvt_i8_bf16x8(Bb + (size_t)(col0 + 16 + lr) * 1024 + 512 + kk + kg);
        acc[0][0] = __builtin_amdgcn_mfma_f32_16x16x32_bf16(a0, b0, acc[0][0], 0, 0, 0);
        acc[0][1] = __builtin_amdgcn_mfma_f32_16x16x32_bf16(a0, b1, acc[0][1], 0, 0, 0);
        acc[1][0] = __builtin_amdgcn_mfma_f32_16x16x32_bf16(a1, b0, acc[1][0], 0, 0, 0);
        acc[1][1] = __builtin_amdgcn_mfma_f32_16x16x32_bf16(a1, b1, acc[1][1], 0, 0, 0);
    }
    float* Pb = g_pv8 + (size_t)t * BHND + (size_t)bh * Nn * Dn;
#pragma unroll
    for (int i = 0; i < 2; ++i)
#pragma unroll
        for (int j = 0; j < 2; ++j)
#pragma unroll
            for (int q = 0; q < 4; ++q) {
                int row = row0 + i * 16 + (lane >> 4) * 4 + q;
                int col = col0 + j * 16 + lr;
                Pb[row * Dn + col] = acc[i][j][q];
            }
}

// ---------------- oif IF for ALL t (reg state) ------------------------------
__global__ __launch_bounds__(256) void oif_all() {
    int idx = blockIdx.x * 256 + threadIdx.x;   // [0, BHND)
    int d = idx & 63;
    int n = (idx >> 6) & 511;
    int bh = idx >> 15;
    int b = bh / 12, h = bh - b * 12;
    size_t obase = ((size_t)(b * Nn + n)) * Cn + h * 64 + d;

    float q = 0.5f; int a = 0;
    for (int t = 0; t < Tn; ++t) {
        float x = g_pv8[(size_t)t * BHND + idx];
        float o = if_sym(x, q, a);
        g_osp8[(size_t)t * BNC + obase] = o;
    }
}

// ---------------- pif IF for ALL t (reg state) → output ---------------------
__global__ __launch_bounds__(256) void pif_all(float* __restrict__ outp) {
    int idx = blockIdx.x * 256 + threadIdx.x;   // [0, BNC)
    float q = 0.5f; int a = 0;
    for (int t = 0; t < Tn; ++t) {
        float x = g_proj8[(size_t)t * BNC + idx];
        float o = if_sym(x, q, a);
        outp[(size_t)t * BNC + idx] = o;
    }
}

extern "C" void kernel_launch(void* const* d_in, const int* in_sizes, int n_in,
                              void* d_out, int out_size, void* d_ws, size_t ws_size,
                              hipStream_t stream) {
    (void)in_sizes; (void)n_in; (void)out_size; (void)d_ws; (void)ws_size;
    const float* x      = (const float*)d_in[0];
    const float* w_qkv  = (const float*)d_in[1];
    const float* w_proj = (const float*)d_in[2];
    float* outp = (float*)d_out;

    // all-t qkv = x @ w_qkv^T  [32768 x 2304], K=768 (state-independent)
    gemm_qkv_big<<<dim3(C3n / 96, (Tn * BNn) / 128), 256, 0, stream>>>(x, w_qkv);
    // all-t q/k/v IF + int8 operand build (reg state)
    if_qkv_all<<<(int)(BHND / 256), 256, 0, stream>>>();
    // all-t attn logits
    gemm_attn_all<<<dim3(64, BHn, Tn), 256, 0, stream>>>();
    // all-t aif + softmax + sif recurrence (reg state)
    attn_pipeline_all<<<BHn * Nn, 256, 0, stream>>>();
    // all-t PV (state-free now)
    gemm_pv_all<<<dim3(8, BHn, Tn), 256, 0, stream>>>();
    // all-t oif (reg state)
    oif_all<<<(int)(BHND / 256), 256, 0, stream>>>();
    // all-t proj = osp8 @ w_proj^T  [32768 x 768], K=768 (state-free)
    gemm_proj_all<<<dim3(Cn / 96, (Tn * BNn) / 128), 256, 0, stream>>>(w_proj);
    // all-t pif (reg state) → final spike output
    pif_all<<<(int)(BNC / 256), 256, 0, stream>>>(outp);
}

// Round 13
// 3143.283 us; speedup vs baseline: 1.8876x; 1.1087x over previous
//
#include <hip/hip_runtime.h>
#include <stdint.h>

typedef __attribute__((ext_vector_type(4))) float f32x4;
typedef __attribute__((ext_vector_type(8))) short s16x8;
typedef __attribute__((ext_vector_type(8))) char  s8x8;
typedef __attribute__((ext_vector_type(16))) char s8x16;
typedef unsigned short u16;

constexpr int    Tn  = 8;
constexpr int    Nn  = 512;
constexpr int    Cn  = 768;
constexpr int    Dn  = 64;
constexpr int    BHn = 96;
constexpr int    BNn = 4096;
constexpr int    C3n = 2304;
constexpr size_t BHND = 3145728;     // B*H*N*D
constexpr size_t BHNN = 25165824;    // B*H*N*N
constexpr size_t BNC  = 3145728;     // B*N*C

// ---- all buffers are produced-before-consumed each call (no persistent state) ----
__device__ float  g_qkvt8[(size_t)Tn * BNn * C3n];   // all-t qkv output (302MB)
__device__ int8_t g_A1[(size_t)Tn * BHND * 2];       // [t][bh][n][128] int8
__device__ int8_t g_B1[(size_t)Tn * BHND * 2];
__device__ short  g_S16[(size_t)Tn * BHNN];          // [t][bh][n][n]
__device__ int8_t g_v8 [(size_t)Tn * BHND];          // [t][bh][n][d] v spike (coalesced)
__device__ int8_t g_vd8[(size_t)Tn * BHND];          // [t][bh][n][d] v_acc - v
__device__ int8_t g_vT[(size_t)Tn * BHn * Dn * 1024];// [t][bh][d][1024] (transposed)
__device__ int8_t g_sifa8[(size_t)Tn * BHNN];        // sif acc after step t
__device__ int8_t g_spk8[(size_t)Tn * BHNN];         // sif spike at step t
__device__ short  g_pv16[(size_t)Tn * BHND];         // all-t PV output (exact ints)
__device__ float  g_osp8[(size_t)Tn * BNC];          // all-t oif spikes [t][b*n][C]
__device__ float  g_proj8[(size_t)Tn * BNC];         // all-t proj output

static __device__ __forceinline__ u16 f2bf(float f) {
    union { float f; unsigned int u; } v; v.f = f;
    return (u16)(v.u >> 16);   // exact for small-integer-valued floats
}

static __device__ __forceinline__ s16x8 cvt_i8_bf16x8(const int8_t* p) {
    s8x8 v = *(const s8x8*)p;
    s16x8 r;
#pragma unroll
    for (int j = 0; j < 8; ++j) r[j] = (short)f2bf((float)v[j]);
    return r;
}

// symmetric IF neuron step (pos_max=7, neg_min=-8)
static __device__ __forceinline__ float if_sym(float x, float& q, int& a) {
    float q2 = q + x;
    bool pos = ((q2 - 1.0f) >= 0.0f) && (a < 7);
    bool neg = (q2 < 0.0f) && (a > -8);
    float out = pos ? 1.0f : (neg ? -1.0f : 0.0f);
    q = q2 - out;
    a += (int)out;
    return out;
}

// ---------------- fp32 NT GEMM (frozen structure, bit-exact chain) ----------
// qkv for ALL t: [32768 x 2304], K=768. Tile 128x96, grid 24x256 = 6144 blocks.
__global__ __launch_bounds__(256) void gemm_qkv_big(
    const float* __restrict__ A, const float* __restrict__ B)
{
    __shared__ __align__(16) float As[16][132];   // 128+4
    __shared__ __align__(16) float Bs[16][100];   // 96+4
    const int tid = threadIdx.x;
    const int m0 = blockIdx.y * 128;
    const int j0 = blockIdx.x * 96;
    const int ty = tid >> 4, tx = tid & 15;

    float acc[8][6];
#pragma unroll
    for (int i = 0; i < 8; ++i)
#pragma unroll
        for (int j = 0; j < 6; ++j) acc[i][j] = 0.0f;

    for (int k0 = 0; k0 < Cn; k0 += 16) {
#pragma unroll
        for (int u = 0; u < 2; ++u) {
            int f = tid + u * 256;
            int row = f >> 2;
            int c4 = (f & 3) * 4;
            float4 av = *(const float4*)(A + (size_t)(m0 + row) * Cn + k0 + c4);
            As[c4 + 0][row] = av.x; As[c4 + 1][row] = av.y;
            As[c4 + 2][row] = av.z; As[c4 + 3][row] = av.w;
        }
#pragma unroll
        for (int u = 0; u < 3; ++u) {
            int f = tid + u * 256;
            int row = f >> 3;
            int c2 = (f & 7) * 2;
            float2 bv = *(const float2*)(B + (size_t)(j0 + row) * Cn + k0 + c2);
            Bs[c2][row] = bv.x; Bs[c2 + 1][row] = bv.y;
        }
        __syncthreads();
#pragma unroll
        for (int k = 0; k < 16; ++k) {
            alignas(16) float a[8];
            alignas(8)  float b[6];
            *(float4*)(a)     = *(const float4*)&As[k][ty * 8];
            *(float4*)(a + 4) = *(const float4*)&As[k][ty * 8 + 4];
#pragma unroll
            for (int u = 0; u < 3; ++u) {
                float2 t = *(const float2*)&Bs[k][tx * 2 + 32 * u];
                b[2 * u] = t.x; b[2 * u + 1] = t.y;
            }
#pragma unroll
            for (int i = 0; i < 8; ++i)
#pragma unroll
                for (int j = 0; j < 6; ++j)
                    acc[i][j] = fmaf(a[i], b[j], acc[i][j]);
        }
        __syncthreads();
    }
#pragma unroll
    for (int i = 0; i < 8; ++i) {
        float* cp = g_qkvt8 + (size_t)(m0 + ty * 8 + i) * C3n + j0 + tx * 2;
#pragma unroll
        for (int u = 0; u < 3; ++u) {
            float2 t; t.x = acc[i][2 * u]; t.y = acc[i][2 * u + 1];
            *(float2*)(cp + 32 * u) = t;
        }
    }
}

// proj for ALL t: [32768 x 768], K=768. Same frozen structure, grid 8x256.
__global__ __launch_bounds__(256) void gemm_proj_all(const float* __restrict__ B)
{
    __shared__ __align__(16) float As[16][132];
    __shared__ __align__(16) float Bs[16][100];
    const int tid = threadIdx.x;
    const int m0 = blockIdx.y * 128;
    const int j0 = blockIdx.x * 96;
    const int ty = tid >> 4, tx = tid & 15;
    const float* A = g_osp8;

    float acc[8][6];
#pragma unroll
    for (int i = 0; i < 8; ++i)
#pragma unroll
        for (int j = 0; j < 6; ++j) acc[i][j] = 0.0f;

    for (int k0 = 0; k0 < Cn; k0 += 16) {
#pragma unroll
        for (int u = 0; u < 2; ++u) {
            int f = tid + u * 256;
            int row = f >> 2;
            int c4 = (f & 3) * 4;
            float4 av = *(const float4*)(A + (size_t)(m0 + row) * Cn + k0 + c4);
            As[c4 + 0][row] = av.x; As[c4 + 1][row] = av.y;
            As[c4 + 2][row] = av.z; As[c4 + 3][row] = av.w;
        }
#pragma unroll
        for (int u = 0; u < 3; ++u) {
            int f = tid + u * 256;
            int row = f >> 3;
            int c2 = (f & 7) * 2;
            float2 bv = *(const float2*)(B + (size_t)(j0 + row) * Cn + k0 + c2);
            Bs[c2][row] = bv.x; Bs[c2 + 1][row] = bv.y;
        }
        __syncthreads();
#pragma unroll
        for (int k = 0; k < 16; ++k) {
            alignas(16) float a[8];
            alignas(8)  float b[6];
            *(float4*)(a)     = *(const float4*)&As[k][ty * 8];
            *(float4*)(a + 4) = *(const float4*)&As[k][ty * 8 + 4];
#pragma unroll
            for (int u = 0; u < 3; ++u) {
                float2 t = *(const float2*)&Bs[k][tx * 2 + 32 * u];
                b[2 * u] = t.x; b[2 * u + 1] = t.y;
            }
#pragma unroll
            for (int i = 0; i < 8; ++i)
#pragma unroll
                for (int j = 0; j < 6; ++j)
                    acc[i][j] = fmaf(a[i], b[j], acc[i][j]);
        }
        __syncthreads();
    }
#pragma unroll
    for (int i = 0; i < 8; ++i) {
        float* cp = g_proj8 + (size_t)(m0 + ty * 8 + i) * Cn + j0 + tx * 2;
#pragma unroll
        for (int u = 0; u < 3; ++u) {
            float2 t; t.x = acc[i][2 * u]; t.y = acc[i][2 * u + 1];
            *(float2*)(cp + 32 * u) = t;
        }
    }
}

// ---------------- q/k/v IF for ALL t (reg state; all writes coalesced) ------
__global__ __launch_bounds__(256) void if_qkv_all() {
    int idx = blockIdx.x * 256 + threadIdx.x;   // [0, BHND) = (bh*512+n)*64+d
    int d = idx & 63;
    int n = (idx >> 6) & 511;
    int bh = idx >> 15;
    int b = bh / 12, h = bh - b * 12;

    float fq = 0.5f, fk = 0.5f, fv = 0.5f;
    int aq = 0, ak = 0, av = 0;

    for (int t = 0; t < Tn; ++t) {
        size_t qrow = ((size_t)((t * 8 + b) * Nn + n)) * C3n + h * 64 + d;
        float xq = g_qkvt8[qrow];
        float xk = g_qkvt8[qrow + 768];
        float xv = g_qkvt8[qrow + 1536];

        float so_q = if_sym(xq, fq, aq);
        float so_k = if_sym(xk, fk, ak);
        float so_v = if_sym(xv, fv, av);

        // attn operands (K=128): A1 = [acc_q | q_spike], B1 = [k_spike | k_acc-k]
        size_t a1b = (((size_t)t * BHn + bh) * Nn + n) * 128 + d;
        g_A1[a1b]      = (int8_t)aq;
        g_A1[a1b + 64] = (int8_t)so_q;
        g_B1[a1b]      = (int8_t)so_k;
        g_B1[a1b + 64] = (int8_t)(ak - (int)so_k);

        // v operands in NATURAL [n][d] layout (coalesced); transposed later
        size_t vb = (size_t)t * BHND + (size_t)idx;
        g_v8[vb]  = (int8_t)so_v;
        g_vd8[vb] = (int8_t)(av - (int)so_v);
    }
}

// ---------------- build vT[t][bh][d][1024] from v8/vd8 (LDS-tiled transpose) -
__global__ __launch_bounds__(256) void vT_build() {
    int bh = blockIdx.x % BHn;
    int t  = blockIdx.x / BHn;
    const int8_t* src0 = g_v8  + (size_t)t * BHND + (size_t)bh * Nn * Dn;
    const int8_t* src1 = g_vd8 + (size_t)t * BHND + (size_t)bh * Nn * Dn;
    int8_t* dst = g_vT + ((size_t)t * BHn + bh) * Dn * 1024;
    __shared__ __align__(16) int8_t tile[64][80];   // 80: 16-aligned rows
    int tid = threadIdx.x;

    for (int s = 0; s < 2; ++s) {
        const int8_t* src = s ? src1 : src0;
        int koff = s * 512;
        for (int nb = 0; nb < Nn; nb += 64) {
            {   // load [64 n][64 d] coalesced, 16B per thread
                int n  = tid >> 2;
                int d0 = (tid & 3) * 16;
                s8x16 v = *(const s8x16*)(src + (size_t)(nb + n) * Dn + d0);
                *(s8x16*)&tile[n][d0] = v;
            }
            __syncthreads();
            {   // store transposed: 16 n per thread, contiguous in n
                int d  = tid >> 2;
                int n0 = (tid & 3) * 16;
                s8x16 o;
#pragma unroll
                for (int j = 0; j < 16; ++j) o[j] = tile[n0 + j][d];
                *(s8x16*)(dst + (size_t)d * 1024 + koff + nb + n0) = o;
            }
            __syncthreads();
        }
    }
}

// ---------------- attn logits for ALL t: S = accq@k^T + q@(kacc-k)^T --------
__global__ __launch_bounds__(256) void gemm_attn_all() {
    int t = blockIdx.z;
    int bh = blockIdx.y;
    int tm = blockIdx.x >> 3, tn = blockIdx.x & 7;
    int wave = threadIdx.x >> 6, lane = threadIdx.x & 63;
    int wr = wave >> 1, wc = wave & 1;
    int row0 = tm * 64 + wr * 32, col0 = tn * 64 + wc * 32;
    const int8_t* Ab = g_A1 + ((size_t)t * BHn + bh) * Nn * 128;
    const int8_t* Bb = g_B1 + ((size_t)t * BHn + bh) * Nn * 128;
    int lr = lane & 15, kg = (lane >> 4) * 8;
    f32x4 acc[2][2] = {};
#pragma unroll
    for (int kk = 0; kk < 128; kk += 32) {
        s16x8 a0 = cvt_i8_bf16x8(Ab + (size_t)(row0 + lr) * 128 + kk + kg);
        s16x8 a1 = cvt_i8_bf16x8(Ab + (size_t)(row0 + 16 + lr) * 128 + kk + kg);
        s16x8 b0 = cvt_i8_bf16x8(Bb + (size_t)(col0 + lr) * 128 + kk + kg);
        s16x8 b1 = cvt_i8_bf16x8(Bb + (size_t)(col0 + 16 + lr) * 128 + kk + kg);
        acc[0][0] = __builtin_amdgcn_mfma_f32_16x16x32_bf16(a0, b0, acc[0][0], 0, 0, 0);
        acc[0][1] = __builtin_amdgcn_mfma_f32_16x16x32_bf16(a0, b1, acc[0][1], 0, 0, 0);
        acc[1][0] = __builtin_amdgcn_mfma_f32_16x16x32_bf16(a1, b0, acc[1][0], 0, 0, 0);
        acc[1][1] = __builtin_amdgcn_mfma_f32_16x16x32_bf16(a1, b1, acc[1][1], 0, 0, 0);
    }
    short* Sb = g_S16 + (size_t)t * BHNN + (size_t)bh * Nn * Nn;
#pragma unroll
    for (int i = 0; i < 2; ++i)
#pragma unroll
        for (int j = 0; j < 2; ++j)
#pragma unroll
            for (int q = 0; q < 4; ++q) {
                int row = row0 + i * 16 + (lane >> 4) * 4 + q;
                int col = col0 + j * 16 + lr;
                Sb[row * Nn + col] = (short)(int)acc[i][j][q];
            }
}

// ---------------- ALL-t aif IF + spiking softmax + sif IF (reg state) -------
__global__ __launch_bounds__(256) void attn_pipeline_all() {
    int rowid = blockIdx.x;                  // bh*512 + n
    size_t base = (size_t)rowid * Nn;
    int tid = threadIdx.x;
    __shared__ int   redI[4];
    __shared__ float redF[4];

    int   aq8[2]  = {4, 4};                  // aif q*8 (q=0.5)
    int   aac[2]  = {0, 0};                  // aif acc == smX
    float sq[2]   = {0.5f, 0.5f};            // sif q
    int   sa[2]   = {0, 0};                  // sif acc
    float yold[2] = {0.0f, 0.0f};            // sm_Y

    for (int t = 0; t < Tn; ++t) {
        float st = (t + 1) < 6 ? (float)(t + 1) / 6.0f : 1.0f;
        const short* S = g_S16 + (size_t)t * BHNN;

        int X[2];
        int myMax = -128;
#pragma unroll
        for (int u = 0; u < 2; ++u) {
            int c = tid + u * 256;
            int s  = S[base + c];
            int q8 = aq8[u] + s;
            int a  = aac[u];
            bool pos = (q8 >= 8) && (a < 7);
            bool neg = (q8 < 0) && (a > -8);
            int o = pos ? 1 : (neg ? -1 : 0);
            aq8[u] = q8 - (o << 3);
            a += o;
            aac[u] = a;
            X[u] = a;
            myMax = max(myMax, a);
        }
        for (int off = 32; off; off >>= 1) myMax = max(myMax, __shfl_xor(myMax, off));
        if ((tid & 63) == 0) redI[tid >> 6] = myMax;
        __syncthreads();
        int M = max(max(redI[0], redI[1]), max(redI[2], redI[3]));

        float e[2];
        float mySum = 0.0f;
#pragma unroll
        for (int u = 0; u < 2; ++u) { e[u] = expf((float)(X[u] - M)); mySum += e[u]; }
        for (int off = 32; off; off >>= 1) mySum += __shfl_xor(mySum, off);
        if ((tid & 63) == 0) redF[tid >> 6] = mySum;
        __syncthreads();
        float Ssum = (redF[0] + redF[1]) + (redF[2] + redF[3]);

#pragma unroll
        for (int u = 0; u < 2; ++u) {
            int c = tid + u * 256;
            float y = (e[u] / Ssum) * st;
            float dlt = y - yold[u];
            yold[u] = y;
            float q = sq[u] + dlt;
            int a = sa[u];
            bool pos = ((q - 1.0f) >= 0.0f) && (a < 7);
            bool neg = (q < 0.0f) && (a > 0);   // neg_min = 0 (unsym)
            float o = pos ? 1.0f : (neg ? -1.0f : 0.0f);
            sq[u] = q - o;
            a += (int)o;
            sa[u] = a;
            g_sifa8[(size_t)t * BHNN + base + c] = (int8_t)a;
            g_spk8[(size_t)t * BHNN + base + c]  = (int8_t)o;
        }
    }
}

// ---------------- PV for ALL t: pv16 = sifa@v + spk@(vacc-v) (exact ints) ---
__global__ __launch_bounds__(256) void gemm_pv_all() {
    int t = blockIdx.z;
    int bh = blockIdx.y;
    int tm = blockIdx.x;
    int wave = threadIdx.x >> 6, lane = threadIdx.x & 63;
    int wr = wave >> 1, wc = wave & 1;
    int row0 = tm * 64 + wr * 32, col0 = wc * 32;
    const int8_t* Aa  = g_sifa8 + (size_t)t * BHNN + (size_t)bh * Nn * Nn;
    const int8_t* Asp = g_spk8  + (size_t)t * BHNN + (size_t)bh * Nn * Nn;
    const int8_t* Bb  = g_vT + ((size_t)t * BHn + bh) * Dn * 1024; // [d][1024]
    int lr = lane & 15, kg = (lane >> 4) * 8;
    f32x4 acc[2][2] = {};
    for (int kk = 0; kk < 512; kk += 32) {
        s16x8 a0 = cvt_i8_bf16x8(Aa + (size_t)(row0 + lr) * 512 + kk + kg);
        s16x8 a1 = cvt_i8_bf16x8(Aa + (size_t)(row0 + 16 + lr) * 512 + kk + kg);
        s16x8 b0 = cvt_i8_bf16x8(Bb + (size_t)(col0 + lr) * 1024 + kk + kg);
        s16x8 b1 = cvt_i8_bf16x8(Bb + (size_t)(col0 + 16 + lr) * 1024 + kk + kg);
        acc[0][0] = __builtin_amdgcn_mfma_f32_16x16x32_bf16(a0, b0, acc[0][0], 0, 0, 0);
        acc[0][1] = __builtin_amdgcn_mfma_f32_16x16x32_bf16(a0, b1, acc[0][1], 0, 0, 0);
        acc[1][0] = __builtin_amdgcn_mfma_f32_16x16x32_bf16(a1, b0, acc[1][0], 0, 0, 0);
        acc[1][1] = __builtin_amdgcn_mfma_f32_16x16x32_bf16(a1, b1, acc[1][1], 0, 0, 0);
    }
    for (int kk = 0; kk < 512; kk += 32) {
        s16x8 a0 = cvt_i8_bf16x8(Asp + (size_t)(row0 + lr) * 512 + kk + kg);
        s16x8 a1 = cvt_i8_bf16x8(Asp + (size_t)(row0 + 16 + lr) * 512 + kk + kg);
        s16x8 b0 = cvt_i8_bf16x8(Bb + (size_t)(col0 + lr) * 1024 + 512 + kk + kg);
        s16x8 b1 = cvt_i8_bf16x8(Bb + (size_t)(col0 + 16 + lr) * 1024 + 512 + kk + kg);
        acc[0][0] = __builtin_amdgcn_mfma_f32_16x16x32_bf16(a0, b0, acc[0][0], 0, 0, 0);
        acc[0][1] = __builtin_amdgcn_mfma_f32_16x16x32_bf16(a0, b1, acc[0][1], 0, 0, 0);
        acc[1][0] = __builtin_amdgcn_mfma_f32_16x16x32_bf16(a1, b0, acc[1][0], 0, 0, 0);
        acc[1][1] = __builtin_amdgcn_mfma_f32_16x16x32_bf16(a1, b1, acc[1][1], 0, 0, 0);
    }
    short* Pb = g_pv16 + (size_t)t * BHND + (size_t)bh * Nn * Dn;
#pragma unroll
    for (int i = 0; i < 2; ++i)
#pragma unroll
        for (int j = 0; j < 2; ++j)
#pragma unroll
            for (int q = 0; q < 4; ++q) {
                int row = row0 + i * 16 + (lane >> 4) * 4 + q;
                int col = col0 + j * 16 + lr;
                Pb[row * Dn + col] = (short)(int)acc[i][j][q];
            }
}

// ---------------- oif IF for ALL t (reg state) ------------------------------
__global__ __launch_bounds__(256) void oif_all() {
    int idx = blockIdx.x * 256 + threadIdx.x;   // [0, BHND)
    int d = idx & 63;
    int n = (idx >> 6) & 511;
    int bh = idx >> 15;
    int b = bh / 12, h = bh - b * 12;
    size_t obase = ((size_t)(b * Nn + n)) * Cn + h * 64 + d;

    float q = 0.5f; int a = 0;
    for (int t = 0; t < Tn; ++t) {
        float x = (float)g_pv16[(size_t)t * BHND + idx];   // exact int -> f32
        float o = if_sym(x, q, a);
        g_osp8[(size_t)t * BNC + obase] = o;
    }
}

// ---------------- pif IF for ALL t (reg state) → output ---------------------
__global__ __launch_bounds__(256) void pif_all(float* __restrict__ outp) {
    int idx = blockIdx.x * 256 + threadIdx.x;   // [0, BNC)
    float q = 0.5f; int a = 0;
    for (int t = 0; t < Tn; ++t) {
        float x = g_proj8[(size_t)t * BNC + idx];
        float o = if_sym(x, q, a);
        outp[(size_t)t * BNC + idx] = o;
    }
}

extern "C" void kernel_launch(void* const* d_in, const int* in_sizes, int n_in,
                              void* d_out, int out_size, void* d_ws, size_t ws_size,
                              hipStream_t stream) {
    (void)in_sizes; (void)n_in; (void)out_size; (void)d_ws; (void)ws_size;
    const float* x      = (const float*)d_in[0];
    const float* w_qkv  = (const float*)d_in[1];
    const float* w_proj = (const float*)d_in[2];
    float* outp = (float*)d_out;

    // all-t qkv = x @ w_qkv^T  [32768 x 2304], K=768 (state-independent)
    gemm_qkv_big<<<dim3(C3n / 96, (Tn * BNn) / 128), 256, 0, stream>>>(x, w_qkv);
    // all-t q/k/v IF + int8 operand build (reg state, coalesced writes)
    if_qkv_all<<<(int)(BHND / 256), 256, 0, stream>>>();
    // build transposed V operand (both sides coalesced)
    vT_build<<<Tn * BHn, 256, 0, stream>>>();
    // all-t attn logits
    gemm_attn_all<<<dim3(64, BHn, Tn), 256, 0, stream>>>();
    // all-t aif + softmax + sif recurrence (reg state)
    attn_pipeline_all<<<BHn * Nn, 256, 0, stream>>>();
    // all-t PV (state-free)
    gemm_pv_all<<<dim3(8, BHn, Tn), 256, 0, stream>>>();
    // all-t oif (reg state)
    oif_all<<<(int)(BHND / 256), 256, 0, stream>>>();
    // all-t proj = osp8 @ w_proj^T  [32768 x 768], K=768 (state-free)
    gemm_proj_all<<<dim3(Cn / 96, (Tn * BNn) / 128), 256, 0, stream>>>(w_proj);
    // all-t pif (reg state) → final spike output
    pif_all<<<(int)(BNC / 256), 256, 0, stream>>>(outp);
}

// Round 14
// 2994.414 us; speedup vs baseline: 1.9814x; 1.0497x over previous
//
#include <hip/hip_runtime.h>
#include <stdint.h>

typedef __attribute__((ext_vector_type(4))) float f32x4;
typedef __attribute__((ext_vector_type(8))) short s16x8;
typedef __attribute__((ext_vector_type(8))) char  s8x8;
typedef __attribute__((ext_vector_type(16))) char s8x16;
typedef unsigned short u16;

constexpr int    Tn  = 8;
constexpr int    Nn  = 512;
constexpr int    Cn  = 768;
constexpr int    Dn  = 64;
constexpr int    BHn = 96;
constexpr int    BNn = 4096;
constexpr int    C3n = 2304;
constexpr size_t BHND = 3145728;     // B*H*N*D
constexpr size_t BHNN = 25165824;    // B*H*N*N
constexpr size_t BNC  = 3145728;     // B*N*C

// ---- all buffers produced-before-consumed each call (no persistent state) ----
__device__ int8_t g_A1[(size_t)Tn * BHND * 2];       // [t][bh][n][128] int8
__device__ int8_t g_B1[(size_t)Tn * BHND * 2];
__device__ short  g_S16[(size_t)Tn * BHNN];          // [t][bh][n][n]
__device__ int8_t g_v8 [(size_t)Tn * BHND];          // [t][bh][n][d] v spike
__device__ int8_t g_vd8[(size_t)Tn * BHND];          // [t][bh][n][d] v_acc - v
__device__ int8_t g_vT[(size_t)Tn * BHn * Dn * 1024];// [t][bh][d][1024]
__device__ int8_t g_sifa8[(size_t)Tn * BHNN];        // sif acc after step t
__device__ int8_t g_spk8[(size_t)Tn * BHNN];         // sif spike at step t
__device__ short  g_pv16[(size_t)Tn * BHND];         // all-t PV output (exact ints)
__device__ int8_t g_osp8i[(size_t)BNn * Tn * Cn];    // oif spikes [bn*8+t][C] int8

static __device__ __forceinline__ u16 f2bf(float f) {
    union { float f; unsigned int u; } v; v.f = f;
    return (u16)(v.u >> 16);   // exact for small-integer-valued floats
}

static __device__ __forceinline__ s16x8 cvt_i8_bf16x8(const int8_t* p) {
    s8x8 v = *(const s8x8*)p;
    s16x8 r;
#pragma unroll
    for (int j = 0; j < 8; ++j) r[j] = (short)f2bf((float)v[j]);
    return r;
}

static __device__ __forceinline__ void st2i8(int8_t* p, int v0, int v1) {
    *(short*)p = (short)((v0 & 0xff) | (v1 << 8));
}

// symmetric IF neuron step (pos_max=7, neg_min=-8)
static __device__ __forceinline__ float if_sym(float x, float& q, int& a) {
    float q2 = q + x;
    bool pos = ((q2 - 1.0f) >= 0.0f) && (a < 7);
    bool neg = (q2 < 0.0f) && (a > -8);
    float out = pos ? 1.0f : (neg ? -1.0f : 0.0f);
    q = q2 - out;
    a += (int)out;
    return out;
}

// ---------------- qkv GEMM (frozen fp32 chain) + FUSED q/k/v IF epilogue ----
// M permuted: m = (b*512+n)*8 + t  ->  x row (t*8+b)*512+n. Thread's 8 acc
// rows are the 8 timesteps of one (b,n); IF chains run in registers.
__global__ __launch_bounds__(256) void gemm_qkv_fused(
    const float* __restrict__ X, const float* __restrict__ B)
{
    __shared__ __align__(16) float As[16][132];   // 128+4
    __shared__ __align__(16) float Bs[16][100];   // 96+4
    const int tid = threadIdx.x;
    const int m0 = blockIdx.y * 128;
    const int j0 = blockIdx.x * 96;
    const int ty = tid >> 4, tx = tid & 15;

    float acc[8][6];
#pragma unroll
    for (int i = 0; i < 8; ++i)
#pragma unroll
        for (int j = 0; j < 6; ++j) acc[i][j] = 0.0f;

    for (int k0 = 0; k0 < Cn; k0 += 16) {
#pragma unroll
        for (int u = 0; u < 2; ++u) {
            int f = tid + u * 256;
            int row = f >> 2;
            int c4 = (f & 3) * 4;
            int m = m0 + row;
            int t = m & 7, bn = m >> 3;
            int b = bn >> 9, n = bn & 511;
            const float* xr = X + ((size_t)((t * 8 + b) * Nn + n)) * Cn;
            float4 av = *(const float4*)(xr + k0 + c4);
            As[c4 + 0][row] = av.x; As[c4 + 1][row] = av.y;
            As[c4 + 2][row] = av.z; As[c4 + 3][row] = av.w;
        }
#pragma unroll
        for (int u = 0; u < 3; ++u) {
            int f = tid + u * 256;
            int row = f >> 3;
            int c2 = (f & 7) * 2;
            float2 bv = *(const float2*)(B + (size_t)(j0 + row) * Cn + k0 + c2);
            Bs[c2][row] = bv.x; Bs[c2 + 1][row] = bv.y;
        }
        __syncthreads();
#pragma unroll
        for (int k = 0; k < 16; ++k) {
            alignas(16) float a[8];
            alignas(8)  float b[6];
            *(float4*)(a)     = *(const float4*)&As[k][ty * 8];
            *(float4*)(a + 4) = *(const float4*)&As[k][ty * 8 + 4];
#pragma unroll
            for (int u = 0; u < 3; ++u) {
                float2 t = *(const float2*)&Bs[k][tx * 2 + 32 * u];
                b[2 * u] = t.x; b[2 * u + 1] = t.y;
            }
#pragma unroll
            for (int i = 0; i < 8; ++i)
#pragma unroll
                for (int j = 0; j < 6; ++j)
                    acc[i][j] = fmaf(a[i], b[j], acc[i][j]);
        }
        __syncthreads();
    }

    // fused IF epilogue: 6 independent 8-step chains per thread
    const int type = (j0 >= 1536) ? 2 : ((j0 >= 768) ? 1 : 0);
    const int bn = (m0 + ty * 8) >> 3;
    const int b = bn >> 9, n = bn & 511;
#pragma unroll
    for (int u = 0; u < 3; ++u) {
        int c  = j0 + 32 * u + tx * 2;       // first col of adjacent pair
        int cl = c - type * 768;
        int h = cl >> 6, d = cl & 63;        // pair (d, d+1), never wraps
        int bh = b * 12 + h;
        float q0 = 0.5f, q1 = 0.5f;
        int   a0 = 0,    a1 = 0;
#pragma unroll
        for (int t = 0; t < Tn; ++t) {
            float o0 = if_sym(acc[t][2 * u],     q0, a0);
            float o1 = if_sym(acc[t][2 * u + 1], q1, a1);
            if (type == 0) {
                size_t p = (((size_t)t * BHn + bh) * Nn + n) * 128 + d;
                st2i8(&g_A1[p],      a0,      a1);        // acc_q half
                st2i8(&g_A1[p + 64], (int)o0, (int)o1);   // q spike half
            } else if (type == 1) {
                size_t p = (((size_t)t * BHn + bh) * Nn + n) * 128 + d;
                st2i8(&g_B1[p],      (int)o0,        (int)o1);        // k spike
                st2i8(&g_B1[p + 64], a0 - (int)o0,   a1 - (int)o1);   // k_acc-k
            } else {
                size_t p = (size_t)t * BHND + ((size_t)bh * Nn + n) * 64 + d;
                st2i8(&g_v8[p],  (int)o0,      (int)o1);
                st2i8(&g_vd8[p], a0 - (int)o0, a1 - (int)o1);
            }
        }
    }
}

// ---------------- build vT[t][bh][d][1024] from v8/vd8 (LDS-tiled transpose) -
__global__ __launch_bounds__(256) void vT_build() {
    int bh = blockIdx.x % BHn;
    int t  = blockIdx.x / BHn;
    const int8_t* src0 = g_v8  + (size_t)t * BHND + (size_t)bh * Nn * Dn;
    const int8_t* src1 = g_vd8 + (size_t)t * BHND + (size_t)bh * Nn * Dn;
    int8_t* dst = g_vT + ((size_t)t * BHn + bh) * Dn * 1024;
    __shared__ __align__(16) int8_t tile[64][80];
    int tid = threadIdx.x;

    for (int s = 0; s < 2; ++s) {
        const int8_t* src = s ? src1 : src0;
        int koff = s * 512;
        for (int nb = 0; nb < Nn; nb += 64) {
            {
                int n  = tid >> 2;
                int d0 = (tid & 3) * 16;
                s8x16 v = *(const s8x16*)(src + (size_t)(nb + n) * Dn + d0);
                *(s8x16*)&tile[n][d0] = v;
            }
            __syncthreads();
            {
                int d  = tid >> 2;
                int n0 = (tid & 3) * 16;
                s8x16 o;
#pragma unroll
                for (int j = 0; j < 16; ++j) o[j] = tile[n0 + j][d];
                *(s8x16*)(dst + (size_t)d * 1024 + koff + nb + n0) = o;
            }
            __syncthreads();
        }
    }
}

// ---------------- attn logits for ALL t: S = accq@k^T + q@(kacc-k)^T --------
__global__ __launch_bounds__(256) void gemm_attn_all() {
    int t = blockIdx.z;
    int bh = blockIdx.y;
    int tm = blockIdx.x >> 3, tn = blockIdx.x & 7;
    int wave = threadIdx.x >> 6, lane = threadIdx.x & 63;
    int wr = wave >> 1, wc = wave & 1;
    int row0 = tm * 64 + wr * 32, col0 = tn * 64 + wc * 32;
    const int8_t* Ab = g_A1 + ((size_t)t * BHn + bh) * Nn * 128;
    const int8_t* Bb = g_B1 + ((size_t)t * BHn + bh) * Nn * 128;
    int lr = lane & 15, kg = (lane >> 4) * 8;
    f32x4 acc[2][2] = {};
#pragma unroll
    for (int kk = 0; kk < 128; kk += 32) {
        s16x8 a0 = cvt_i8_bf16x8(Ab + (size_t)(row0 + lr) * 128 + kk + kg);
        s16x8 a1 = cvt_i8_bf16x8(Ab + (size_t)(row0 + 16 + lr) * 128 + kk + kg);
        s16x8 b0 = cvt_i8_bf16x8(Bb + (size_t)(col0 + lr) * 128 + kk + kg);
        s16x8 b1 = cvt_i8_bf16x8(Bb + (size_t)(col0 + 16 + lr) * 128 + kk + kg);
        acc[0][0] = __builtin_amdgcn_mfma_f32_16x16x32_bf16(a0, b0, acc[0][0], 0, 0, 0);
        acc[0][1] = __builtin_amdgcn_mfma_f32_16x16x32_bf16(a0, b1, acc[0][1], 0, 0, 0);
        acc[1][0] = __builtin_amdgcn_mfma_f32_16x16x32_bf16(a1, b0, acc[1][0], 0, 0, 0);
        acc[1][1] = __builtin_amdgcn_mfma_f32_16x16x32_bf16(a1, b1, acc[1][1], 0, 0, 0);
    }
    short* Sb = g_S16 + (size_t)t * BHNN + (size_t)bh * Nn * Nn;
#pragma unroll
    for (int i = 0; i < 2; ++i)
#pragma unroll
        for (int j = 0; j < 2; ++j)
#pragma unroll
            for (int q = 0; q < 4; ++q) {
                int row = row0 + i * 16 + (lane >> 4) * 4 + q;
                int col = col0 + j * 16 + lr;
                Sb[row * Nn + col] = (short)(int)acc[i][j][q];
            }
}

// ---------------- ALL-t aif IF + spiking softmax + sif IF (reg state) -------
__global__ __launch_bounds__(256) void attn_pipeline_all() {
    int rowid = blockIdx.x;                  // bh*512 + n
    size_t base = (size_t)rowid * Nn;
    int tid = threadIdx.x;
    __shared__ int   redI[4];
    __shared__ float redF[4];

    int   aq8[2]  = {4, 4};
    int   aac[2]  = {0, 0};
    float sq[2]   = {0.5f, 0.5f};
    int   sa[2]   = {0, 0};
    float yold[2] = {0.0f, 0.0f};

    for (int t = 0; t < Tn; ++t) {
        float st = (t + 1) < 6 ? (float)(t + 1) / 6.0f : 1.0f;
        const short* S = g_S16 + (size_t)t * BHNN;

        int X[2];
        int myMax = -128;
#pragma unroll
        for (int u = 0; u < 2; ++u) {
            int c = tid + u * 256;
            int s  = S[base + c];
            int q8 = aq8[u] + s;
            int a  = aac[u];
            bool pos = (q8 >= 8) && (a < 7);
            bool neg = (q8 < 0) && (a > -8);
            int o = pos ? 1 : (neg ? -1 : 0);
            aq8[u] = q8 - (o << 3);
            a += o;
            aac[u] = a;
            X[u] = a;
            myMax = max(myMax, a);
        }
        for (int off = 32; off; off >>= 1) myMax = max(myMax, __shfl_xor(myMax, off));
        if ((tid & 63) == 0) redI[tid >> 6] = myMax;
        __syncthreads();
        int M = max(max(redI[0], redI[1]), max(redI[2], redI[3]));

        float e[2];
        float mySum = 0.0f;
#pragma unroll
        for (int u = 0; u < 2; ++u) { e[u] = expf((float)(X[u] - M)); mySum += e[u]; }
        for (int off = 32; off; off >>= 1) mySum += __shfl_xor(mySum, off);
        if ((tid & 63) == 0) redF[tid >> 6] = mySum;
        __syncthreads();
        float Ssum = (redF[0] + redF[1]) + (redF[2] + redF[3]);

#pragma unroll
        for (int u = 0; u < 2; ++u) {
            int c = tid + u * 256;
            float y = (e[u] / Ssum) * st;
            float dlt = y - yold[u];
            yold[u] = y;
            float q = sq[u] + dlt;
            int a = sa[u];
            bool pos = ((q - 1.0f) >= 0.0f) && (a < 7);
            bool neg = (q < 0.0f) && (a > 0);
            float o = pos ? 1.0f : (neg ? -1.0f : 0.0f);
            sq[u] = q - o;
            a += (int)o;
            sa[u] = a;
            g_sifa8[(size_t)t * BHNN + base + c] = (int8_t)a;
            g_spk8[(size_t)t * BHNN + base + c]  = (int8_t)o;
        }
    }
}

// ---------------- PV for ALL t: pv16 = sifa@v + spk@(vacc-v) (exact ints) ---
__global__ __launch_bounds__(256) void gemm_pv_all() {
    int t = blockIdx.z;
    int bh = blockIdx.y;
    int tm = blockIdx.x;
    int wave = threadIdx.x >> 6, lane = threadIdx.x & 63;
    int wr = wave >> 1, wc = wave & 1;
    int row0 = tm * 64 + wr * 32, col0 = wc * 32;
    const int8_t* Aa  = g_sifa8 + (size_t)t * BHNN + (size_t)bh * Nn * Nn;
    const int8_t* Asp = g_spk8  + (size_t)t * BHNN + (size_t)bh * Nn * Nn;
    const int8_t* Bb  = g_vT + ((size_t)t * BHn + bh) * Dn * 1024;
    int lr = lane & 15, kg = (lane >> 4) * 8;
    f32x4 acc[2][2] = {};
    for (int kk = 0; kk < 512; kk += 32) {
        s16x8 a0 = cvt_i8_bf16x8(Aa + (size_t)(row0 + lr) * 512 + kk + kg);
        s16x8 a1 = cvt_i8_bf16x8(Aa + (size_t)(row0 + 16 + lr) * 512 + kk + kg);
        s16x8 b0 = cvt_i8_bf16x8(Bb + (size_t)(col0 + lr) * 1024 + kk + kg);
        s16x8 b1 = cvt_i8_bf16x8(Bb + (size_t)(col0 + 16 + lr) * 1024 + kk + kg);
        acc[0][0] = __builtin_amdgcn_mfma_f32_16x16x32_bf16(a0, b0, acc[0][0], 0, 0, 0);
        acc[0][1] = __builtin_amdgcn_mfma_f32_16x16x32_bf16(a0, b1, acc[0][1], 0, 0, 0);
        acc[1][0] = __builtin_amdgcn_mfma_f32_16x16x32_bf16(a1, b0, acc[1][0], 0, 0, 0);
        acc[1][1] = __builtin_amdgcn_mfma_f32_16x16x32_bf16(a1, b1, acc[1][1], 0, 0, 0);
    }
    for (int kk = 0; kk < 512; kk += 32) {
        s16x8 a0 = cvt_i8_bf16x8(Asp + (size_t)(row0 + lr) * 512 + kk + kg);
        s16x8 a1 = cvt_i8_bf16x8(Asp + (size_t)(row0 + 16 + lr) * 512 + kk + kg);
        s16x8 b0 = cvt_i8_bf16x8(Bb + (size_t)(col0 + lr) * 1024 + 512 + kk + kg);
        s16x8 b1 = cvt_i8_bf16x8(Bb + (size_t)(col0 + 16 + lr) * 1024 + 512 + kk + kg);
        acc[0][0] = __builtin_amdgcn_mfma_f32_16x16x32_bf16(a0, b0, acc[0][0], 0, 0, 0);
        acc[0][1] = __builtin_amdgcn_mfma_f32_16x16x32_bf16(a0, b1, acc[0][1], 0, 0, 0);
        acc[1][0] = __builtin_amdgcn_mfma_f32_16x16x32_bf16(a1, b0, acc[1][0], 0, 0, 0);
        acc[1][1] = __builtin_amdgcn_mfma_f32_16x16x32_bf16(a1, b1, acc[1][1], 0, 0, 0);
    }
    short* Pb = g_pv16 + (size_t)t * BHND + (size_t)bh * Nn * Dn;
#pragma unroll
    for (int i = 0; i < 2; ++i)
#pragma unroll
        for (int j = 0; j < 2; ++j)
#pragma unroll
            for (int q = 0; q < 4; ++q) {
                int row = row0 + i * 16 + (lane >> 4) * 4 + q;
                int col = col0 + j * 16 + lr;
                Pb[row * Dn + col] = (short)(int)acc[i][j][q];
            }
}

// ---------------- oif IF for ALL t (reg state) -> int8 spikes, permuted -----
__global__ __launch_bounds__(256) void oif_all() {
    int idx = blockIdx.x * 256 + threadIdx.x;   // [0, BHND)
    int d = idx & 63;
    int n = (idx >> 6) & 511;
    int bh = idx >> 15;
    int b = bh / 12, h = bh - b * 12;
    size_t bn = (size_t)(b * Nn + n);
    int c = h * 64 + d;

    float q = 0.5f; int a = 0;
    for (int t = 0; t < Tn; ++t) {
        float x = (float)g_pv16[(size_t)t * BHND + idx];   // exact int -> f32
        float o = if_sym(x, q, a);
        g_osp8i[(bn * 8 + t) * Cn + c] = (int8_t)o;
    }
}

// ---------------- proj GEMM (frozen fp32 chain, int8-A) + FUSED pif ---------
// M permuted: m = (b*512+n)*8 + t. Thread's 8 acc rows = 8 timesteps of one
// (b,n); pif chains run in registers; spikes written straight to output.
__global__ __launch_bounds__(256) void gemm_proj_pif_all(
    const float* __restrict__ B, float* __restrict__ outp)
{
    __shared__ __align__(16) float As[16][132];
    __shared__ __align__(16) float Bs[16][100];
    const int tid = threadIdx.x;
    const int m0 = blockIdx.y * 128;
    const int j0 = blockIdx.x * 96;
    const int ty = tid >> 4, tx = tid & 15;

    float acc[8][6];
#pragma unroll
    for (int i = 0; i < 8; ++i)
#pragma unroll
        for (int j = 0; j < 6; ++j) acc[i][j] = 0.0f;

    for (int k0 = 0; k0 < Cn; k0 += 16) {
        {   // A staging: int8 spikes -> exact fp32
            int row = tid >> 1;
            int c8 = (tid & 1) * 8;
            s8x8 v = *(const s8x8*)(g_osp8i + (size_t)(m0 + row) * Cn + k0 + c8);
#pragma unroll
            for (int j = 0; j < 8; ++j) As[c8 + j][row] = (float)v[j];
        }
#pragma unroll
        for (int u = 0; u < 3; ++u) {
            int f = tid + u * 256;
            int r2 = f >> 3;
            int c2 = (f & 7) * 2;
            float2 bv = *(const float2*)(B + (size_t)(j0 + r2) * Cn + k0 + c2);
            Bs[c2][r2] = bv.x; Bs[c2 + 1][r2] = bv.y;
        }
        __syncthreads();
#pragma unroll
        for (int k = 0; k < 16; ++k) {
            alignas(16) float a[8];
            alignas(8)  float b[6];
            *(float4*)(a)     = *(const float4*)&As[k][ty * 8];
            *(float4*)(a + 4) = *(const float4*)&As[k][ty * 8 + 4];
#pragma unroll
            for (int u = 0; u < 3; ++u) {
                float2 t = *(const float2*)&Bs[k][tx * 2 + 32 * u];
                b[2 * u] = t.x; b[2 * u + 1] = t.y;
            }
#pragma unroll
            for (int i = 0; i < 8; ++i)
#pragma unroll
                for (int j = 0; j < 6; ++j)
                    acc[i][j] = fmaf(a[i], b[j], acc[i][j]);
        }
        __syncthreads();
    }

    // fused pif epilogue: 6 independent 8-step chains per thread -> output
    const size_t bn = (size_t)((m0 + ty * 8) >> 3);
#pragma unroll
    for (int u = 0; u < 3; ++u) {
        size_t cbase = bn * Cn + j0 + 32 * u + tx * 2;
        float q0 = 0.5f, q1 = 0.5f;
        int   a0 = 0,    a1 = 0;
#pragma unroll
        for (int t = 0; t < Tn; ++t) {
            float o0 = if_sym(acc[t][2 * u],     q0, a0);
            float o1 = if_sym(acc[t][2 * u + 1], q1, a1);
            float2 st; st.x = o0; st.y = o1;
            *(float2*)(outp + (size_t)t * BNC + cbase) = st;
        }
    }
}

extern "C" void kernel_launch(void* const* d_in, const int* in_sizes, int n_in,
                              void* d_out, int out_size, void* d_ws, size_t ws_size,
                              hipStream_t stream) {
    (void)in_sizes; (void)n_in; (void)out_size; (void)d_ws; (void)ws_size;
    const float* x      = (const float*)d_in[0];
    const float* w_qkv  = (const float*)d_in[1];
    const float* w_proj = (const float*)d_in[2];
    float* outp = (float*)d_out;

    // qkv GEMM [32768 x 2304] K=768 with fused q/k/v IF epilogue
    gemm_qkv_fused<<<dim3(C3n / 96, (Tn * BNn) / 128), 256, 0, stream>>>(x, w_qkv);
    // transposed V operand
    vT_build<<<Tn * BHn, 256, 0, stream>>>();
    // all-t attn logits
    gemm_attn_all<<<dim3(64, BHn, Tn), 256, 0, stream>>>();
    // all-t aif + softmax + sif recurrence (reg state)
    attn_pipeline_all<<<BHn * Nn, 256, 0, stream>>>();
    // all-t PV
    gemm_pv_all<<<dim3(8, BHn, Tn), 256, 0, stream>>>();
    // all-t oif -> int8 spikes in permuted [bn*8+t][C] layout
    oif_all<<<(int)(BHND / 256), 256, 0, stream>>>();
    // proj GEMM [32768 x 768] K=768 with fused pif epilogue -> output
    gemm_proj_pif_all<<<dim3(Cn / 96, (Tn * BNn) / 128), 256, 0, stream>>>(w_proj, outp);
}

// Round 15
// 2686.287 us; speedup vs baseline: 2.2087x; 1.1147x over previous
//
#include <hip/hip_runtime.h>
#include <stdint.h>

typedef __attribute__((ext_vector_type(4))) float f32x4;
typedef __attribute__((ext_vector_type(4))) int   i32x4;
typedef __attribute__((ext_vector_type(8))) char  s8x8;
typedef __attribute__((ext_vector_type(16))) char s8x16;
typedef unsigned short u16;

constexpr int    Tn  = 8;
constexpr int    Nn  = 512;
constexpr int    Cn  = 768;
constexpr int    Dn  = 64;
constexpr int    BHn = 96;
constexpr int    BNn = 4096;
constexpr int    C3n = 2304;
constexpr size_t BHND = 3145728;     // B*H*N*D
constexpr size_t BHNN = 25165824;    // B*H*N*N
constexpr size_t BNC  = 3145728;     // B*N*C

// ---- all buffers produced-before-consumed each call (no persistent state) ----
__device__ __attribute__((aligned(16))) int8_t g_A1[(size_t)Tn * BHND * 2];  // [t][bh][n][128]
__device__ __attribute__((aligned(16))) int8_t g_B1[(size_t)Tn * BHND * 2];
__device__ __attribute__((aligned(16))) short  g_S16[(size_t)Tn * BHNN];     // [t][bh][n][n]
__device__ __attribute__((aligned(16))) int8_t g_v8 [(size_t)Tn * BHND];     // [t][bh][n][d]
__device__ __attribute__((aligned(16))) int8_t g_vd8[(size_t)Tn * BHND];     // [t][bh][n][d]
__device__ __attribute__((aligned(16))) int8_t g_vT[(size_t)Tn * BHn * Dn * 1024]; // [t][bh][d][1024]
__device__ __attribute__((aligned(16))) int8_t g_sifa8[(size_t)Tn * BHNN];   // sif acc after step t
__device__ __attribute__((aligned(16))) int8_t g_spk8[(size_t)Tn * BHNN];    // sif spike at step t
__device__ __attribute__((aligned(16))) int8_t g_osp8i[(size_t)BNn * Tn * Cn]; // [bn*8+t][C]

static __device__ __forceinline__ void st2i8(int8_t* p, int v0, int v1) {
    *(short*)p = (short)((v0 & 0xff) | (v1 << 8));
}

// symmetric IF neuron step (pos_max=7, neg_min=-8)
static __device__ __forceinline__ float if_sym(float x, float& q, int& a) {
    float q2 = q + x;
    bool pos = ((q2 - 1.0f) >= 0.0f) && (a < 7);
    bool neg = (q2 < 0.0f) && (a > -8);
    float out = pos ? 1.0f : (neg ? -1.0f : 0.0f);
    q = q2 - out;
    a += (int)out;
    return out;
}

// ---------------- qkv GEMM (frozen fp32 chain) + FUSED q/k/v IF epilogue ----
__global__ __launch_bounds__(256) void gemm_qkv_fused(
    const float* __restrict__ X, const float* __restrict__ B)
{
    __shared__ __align__(16) float As[16][132];   // 128+4
    __shared__ __align__(16) float Bs[16][100];   // 96+4
    const int tid = threadIdx.x;
    const int m0 = blockIdx.y * 128;
    const int j0 = blockIdx.x * 96;
    const int ty = tid >> 4, tx = tid & 15;

    float acc[8][6];
#pragma unroll
    for (int i = 0; i < 8; ++i)
#pragma unroll
        for (int j = 0; j < 6; ++j) acc[i][j] = 0.0f;

    for (int k0 = 0; k0 < Cn; k0 += 16) {
#pragma unroll
        for (int u = 0; u < 2; ++u) {
            int f = tid + u * 256;
            int row = f >> 2;
            int c4 = (f & 3) * 4;
            int m = m0 + row;
            int t = m & 7, bn = m >> 3;
            int b = bn >> 9, n = bn & 511;
            const float* xr = X + ((size_t)((t * 8 + b) * Nn + n)) * Cn;
            float4 av = *(const float4*)(xr + k0 + c4);
            As[c4 + 0][row] = av.x; As[c4 + 1][row] = av.y;
            As[c4 + 2][row] = av.z; As[c4 + 3][row] = av.w;
        }
#pragma unroll
        for (int u = 0; u < 3; ++u) {
            int f = tid + u * 256;
            int row = f >> 3;
            int c2 = (f & 7) * 2;
            float2 bv = *(const float2*)(B + (size_t)(j0 + row) * Cn + k0 + c2);
            Bs[c2][row] = bv.x; Bs[c2 + 1][row] = bv.y;
        }
        __syncthreads();
#pragma unroll
        for (int k = 0; k < 16; ++k) {
            alignas(16) float a[8];
            alignas(8)  float b[6];
            *(float4*)(a)     = *(const float4*)&As[k][ty * 8];
            *(float4*)(a + 4) = *(const float4*)&As[k][ty * 8 + 4];
#pragma unroll
            for (int u = 0; u < 3; ++u) {
                float2 t = *(const float2*)&Bs[k][tx * 2 + 32 * u];
                b[2 * u] = t.x; b[2 * u + 1] = t.y;
            }
#pragma unroll
            for (int i = 0; i < 8; ++i)
#pragma unroll
                for (int j = 0; j < 6; ++j)
                    acc[i][j] = fmaf(a[i], b[j], acc[i][j]);
        }
        __syncthreads();
    }

    // fused IF epilogue: 6 independent 8-step chains per thread
    const int type = (j0 >= 1536) ? 2 : ((j0 >= 768) ? 1 : 0);
    const int bn = (m0 + ty * 8) >> 3;
    const int b = bn >> 9, n = bn & 511;
#pragma unroll
    for (int u = 0; u < 3; ++u) {
        int c  = j0 + 32 * u + tx * 2;
        int cl = c - type * 768;
        int h = cl >> 6, d = cl & 63;
        int bh = b * 12 + h;
        float q0 = 0.5f, q1 = 0.5f;
        int   a0 = 0,    a1 = 0;
#pragma unroll
        for (int t = 0; t < Tn; ++t) {
            float o0 = if_sym(acc[t][2 * u],     q0, a0);
            float o1 = if_sym(acc[t][2 * u + 1], q1, a1);
            if (type == 0) {
                size_t p = (((size_t)t * BHn + bh) * Nn + n) * 128 + d;
                st2i8(&g_A1[p],      a0,      a1);
                st2i8(&g_A1[p + 64], (int)o0, (int)o1);
            } else if (type == 1) {
                size_t p = (((size_t)t * BHn + bh) * Nn + n) * 128 + d;
                st2i8(&g_B1[p],      (int)o0,      (int)o1);
                st2i8(&g_B1[p + 64], a0 - (int)o0, a1 - (int)o1);
            } else {
                size_t p = (size_t)t * BHND + ((size_t)bh * Nn + n) * 64 + d;
                st2i8(&g_v8[p],  (int)o0,      (int)o1);
                st2i8(&g_vd8[p], a0 - (int)o0, a1 - (int)o1);
            }
        }
    }
}

// ---------------- build vT[t][bh][d][1024] (LDS-tiled transpose) ------------
__global__ __launch_bounds__(256) void vT_build() {
    int bh = blockIdx.x % BHn;
    int t  = blockIdx.x / BHn;
    const int8_t* src0 = g_v8  + (size_t)t * BHND + (size_t)bh * Nn * Dn;
    const int8_t* src1 = g_vd8 + (size_t)t * BHND + (size_t)bh * Nn * Dn;
    int8_t* dst = g_vT + ((size_t)t * BHn + bh) * Dn * 1024;
    __shared__ __align__(16) int8_t tile[64][80];
    int tid = threadIdx.x;

    for (int s = 0; s < 2; ++s) {
        const int8_t* src = s ? src1 : src0;
        int koff = s * 512;
        for (int nb = 0; nb < Nn; nb += 64) {
            {
                int n  = tid >> 2;
                int d0 = (tid & 3) * 16;
                s8x16 v = *(const s8x16*)(src + (size_t)(nb + n) * Dn + d0);
                *(s8x16*)&tile[n][d0] = v;
            }
            __syncthreads();
            {
                int d  = tid >> 2;
                int n0 = (tid & 3) * 16;
                s8x16 o;
#pragma unroll
                for (int j = 0; j < 16; ++j) o[j] = tile[n0 + j][d];
                *(s8x16*)(dst + (size_t)d * 1024 + koff + nb + n0) = o;
            }
            __syncthreads();
        }
    }
}

// ---------------- attn logits for ALL t (i8 MFMA, exact int32) --------------
__global__ __launch_bounds__(256) void gemm_attn_all() {
    int t = blockIdx.z;
    int bh = blockIdx.y;
    int tm = blockIdx.x >> 3, tn = blockIdx.x & 7;
    int wave = threadIdx.x >> 6, lane = threadIdx.x & 63;
    int wr = wave >> 1, wc = wave & 1;
    int row0 = tm * 64 + wr * 32, col0 = tn * 64 + wc * 32;
    const int8_t* Ab = g_A1 + ((size_t)t * BHn + bh) * Nn * 128;
    const int8_t* Bb = g_B1 + ((size_t)t * BHn + bh) * Nn * 128;
    int lr = lane & 15, kg = (lane >> 4) * 16;
    i32x4 acc[2][2] = {};
#pragma unroll
    for (int kk = 0; kk < 128; kk += 64) {
        i32x4 a0 = *(const i32x4*)(Ab + (size_t)(row0 + lr) * 128 + kk + kg);
        i32x4 a1 = *(const i32x4*)(Ab + (size_t)(row0 + 16 + lr) * 128 + kk + kg);
        i32x4 b0 = *(const i32x4*)(Bb + (size_t)(col0 + lr) * 128 + kk + kg);
        i32x4 b1 = *(const i32x4*)(Bb + (size_t)(col0 + 16 + lr) * 128 + kk + kg);
        acc[0][0] = __builtin_amdgcn_mfma_i32_16x16x64_i8(a0, b0, acc[0][0], 0, 0, 0);
        acc[0][1] = __builtin_amdgcn_mfma_i32_16x16x64_i8(a0, b1, acc[0][1], 0, 0, 0);
        acc[1][0] = __builtin_amdgcn_mfma_i32_16x16x64_i8(a1, b0, acc[1][0], 0, 0, 0);
        acc[1][1] = __builtin_amdgcn_mfma_i32_16x16x64_i8(a1, b1, acc[1][1], 0, 0, 0);
    }
    short* Sb = g_S16 + (size_t)t * BHNN + (size_t)bh * Nn * Nn;
#pragma unroll
    for (int i = 0; i < 2; ++i)
#pragma unroll
        for (int j = 0; j < 2; ++j)
#pragma unroll
            for (int q = 0; q < 4; ++q) {
                int row = row0 + i * 16 + (lane >> 4) * 4 + q;
                int col = col0 + j * 16 + lr;
                Sb[row * Nn + col] = (short)acc[i][j][q];
            }
}

// ---------------- ALL-t aif IF + spiking softmax + sif IF (reg state) -------
__global__ __launch_bounds__(256) void attn_pipeline_all() {
    int rowid = blockIdx.x;                  // bh*512 + n
    size_t base = (size_t)rowid * Nn;
    int tid = threadIdx.x;
    __shared__ int   redI[4];
    __shared__ float redF[4];

    int   aq8[2]  = {4, 4};
    int   aac[2]  = {0, 0};
    float sq[2]   = {0.5f, 0.5f};
    int   sa[2]   = {0, 0};
    float yold[2] = {0.0f, 0.0f};

    for (int t = 0; t < Tn; ++t) {
        float st = (t + 1) < 6 ? (float)(t + 1) / 6.0f : 1.0f;
        const short* S = g_S16 + (size_t)t * BHNN;

        int X[2];
        int myMax = -128;
#pragma unroll
        for (int u = 0; u < 2; ++u) {
            int c = tid + u * 256;
            int s  = S[base + c];
            int q8 = aq8[u] + s;
            int a  = aac[u];
            bool pos = (q8 >= 8) && (a < 7);
            bool neg = (q8 < 0) && (a > -8);
            int o = pos ? 1 : (neg ? -1 : 0);
            aq8[u] = q8 - (o << 3);
            a += o;
            aac[u] = a;
            X[u] = a;
            myMax = max(myMax, a);
        }
        for (int off = 32; off; off >>= 1) myMax = max(myMax, __shfl_xor(myMax, off));
        if ((tid & 63) == 0) redI[tid >> 6] = myMax;
        __syncthreads();
        int M = max(max(redI[0], redI[1]), max(redI[2], redI[3]));

        float e[2];
        float mySum = 0.0f;
#pragma unroll
        for (int u = 0; u < 2; ++u) { e[u] = expf((float)(X[u] - M)); mySum += e[u]; }
        for (int off = 32; off; off >>= 1) mySum += __shfl_xor(mySum, off);
        if ((tid & 63) == 0) redF[tid >> 6] = mySum;
        __syncthreads();
        float Ssum = (redF[0] + redF[1]) + (redF[2] + redF[3]);

#pragma unroll
        for (int u = 0; u < 2; ++u) {
            int c = tid + u * 256;
            float y = (e[u] / Ssum) * st;
            float dlt = y - yold[u];
            yold[u] = y;
            float q = sq[u] + dlt;
            int a = sa[u];
            bool pos = ((q - 1.0f) >= 0.0f) && (a < 7);
            bool neg = (q < 0.0f) && (a > 0);
            float o = pos ? 1.0f : (neg ? -1.0f : 0.0f);
            sq[u] = q - o;
            a += (int)o;
            sa[u] = a;
            g_sifa8[(size_t)t * BHNN + base + c] = (int8_t)a;
            g_spk8[(size_t)t * BHNN + base + c]  = (int8_t)o;
        }
    }
}

// ------- PV (i8 MFMA, t-loop) + FUSED oif epilogue (reg state across t) -----
__global__ __launch_bounds__(256) void gemm_pv_oif_all() {
    int bh = blockIdx.y;
    int tm = blockIdx.x;
    int wave = threadIdx.x >> 6, lane = threadIdx.x & 63;
    int wr = wave >> 1, wc = wave & 1;
    int row0 = tm * 64 + wr * 32, col0 = wc * 32;
    int lr = lane & 15, kg = (lane >> 4) * 16;
    int b = bh / 12, h = bh - b * 12;

    float oq[2][2][4];
    int   oa[2][2][4];
#pragma unroll
    for (int i = 0; i < 2; ++i)
#pragma unroll
        for (int j = 0; j < 2; ++j)
#pragma unroll
            for (int q = 0; q < 4; ++q) { oq[i][j][q] = 0.5f; oa[i][j][q] = 0; }

    for (int t = 0; t < Tn; ++t) {
        const int8_t* Aa  = g_sifa8 + (size_t)t * BHNN + (size_t)bh * Nn * Nn;
        const int8_t* Asp = g_spk8  + (size_t)t * BHNN + (size_t)bh * Nn * Nn;
        const int8_t* Bb  = g_vT + ((size_t)t * BHn + bh) * Dn * 1024;
        i32x4 acc[2][2] = {};
        for (int kk = 0; kk < 512; kk += 64) {
            i32x4 a0 = *(const i32x4*)(Aa + (size_t)(row0 + lr) * 512 + kk + kg);
            i32x4 a1 = *(const i32x4*)(Aa + (size_t)(row0 + 16 + lr) * 512 + kk + kg);
            i32x4 b0 = *(const i32x4*)(Bb + (size_t)(col0 + lr) * 1024 + kk + kg);
            i32x4 b1 = *(const i32x4*)(Bb + (size_t)(col0 + 16 + lr) * 1024 + kk + kg);
            acc[0][0] = __builtin_amdgcn_mfma_i32_16x16x64_i8(a0, b0, acc[0][0], 0, 0, 0);
            acc[0][1] = __builtin_amdgcn_mfma_i32_16x16x64_i8(a0, b1, acc[0][1], 0, 0, 0);
            acc[1][0] = __builtin_amdgcn_mfma_i32_16x16x64_i8(a1, b0, acc[1][0], 0, 0, 0);
            acc[1][1] = __builtin_amdgcn_mfma_i32_16x16x64_i8(a1, b1, acc[1][1], 0, 0, 0);
        }
        for (int kk = 0; kk < 512; kk += 64) {
            i32x4 a0 = *(const i32x4*)(Asp + (size_t)(row0 + lr) * 512 + kk + kg);
            i32x4 a1 = *(const i32x4*)(Asp + (size_t)(row0 + 16 + lr) * 512 + kk + kg);
            i32x4 b0 = *(const i32x4*)(Bb + (size_t)(col0 + lr) * 1024 + 512 + kk + kg);
            i32x4 b1 = *(const i32x4*)(Bb + (size_t)(col0 + 16 + lr) * 1024 + 512 + kk + kg);
            acc[0][0] = __builtin_amdgcn_mfma_i32_16x16x64_i8(a0, b0, acc[0][0], 0, 0, 0);
            acc[0][1] = __builtin_amdgcn_mfma_i32_16x16x64_i8(a0, b1, acc[0][1], 0, 0, 0);
            acc[1][0] = __builtin_amdgcn_mfma_i32_16x16x64_i8(a1, b0, acc[1][0], 0, 0, 0);
            acc[1][1] = __builtin_amdgcn_mfma_i32_16x16x64_i8(a1, b1, acc[1][1], 0, 0, 0);
        }
        // fused oif epilogue (exact int -> f32, IF state in registers)
#pragma unroll
        for (int i = 0; i < 2; ++i)
#pragma unroll
            for (int j = 0; j < 2; ++j)
#pragma unroll
                for (int q = 0; q < 4; ++q) {
                    int row = row0 + i * 16 + (lane >> 4) * 4 + q;   // n
                    int col = col0 + j * 16 + lr;                    // d
                    float x = (float)acc[i][j][q];
                    float o = if_sym(x, oq[i][j][q], oa[i][j][q]);
                    size_t bn = (size_t)(b * Nn + row);
                    g_osp8i[(bn * 8 + t) * Cn + h * 64 + col] = (int8_t)o;
                }
    }
}

// ---------------- proj GEMM (frozen fp32 chain, int8-A) + FUSED pif ---------
__global__ __launch_bounds__(256) void gemm_proj_pif_all(
    const float* __restrict__ B, float* __restrict__ outp)
{
    __shared__ __align__(16) float As[16][132];
    __shared__ __align__(16) float Bs[16][100];
    const int tid = threadIdx.x;
    const int m0 = blockIdx.y * 128;
    const int j0 = blockIdx.x * 96;
    const int ty = tid >> 4, tx = tid & 15;

    float acc[8][6];
#pragma unroll
    for (int i = 0; i < 8; ++i)
#pragma unroll
        for (int j = 0; j < 6; ++j) acc[i][j] = 0.0f;

    for (int k0 = 0; k0 < Cn; k0 += 16) {
        {   // A staging: int8 spikes -> exact fp32
            int row = tid >> 1;
            int c8 = (tid & 1) * 8;
            s8x8 v = *(const s8x8*)(g_osp8i + (size_t)(m0 + row) * Cn + k0 + c8);
#pragma unroll
            for (int j = 0; j < 8; ++j) As[c8 + j][row] = (float)v[j];
        }
#pragma unroll
        for (int u = 0; u < 3; ++u) {
            int f = tid + u * 256;
            int r2 = f >> 3;
            int c2 = (f & 7) * 2;
            float2 bv = *(const float2*)(B + (size_t)(j0 + r2) * Cn + k0 + c2);
            Bs[c2][r2] = bv.x; Bs[c2 + 1][r2] = bv.y;
        }
        __syncthreads();
#pragma unroll
        for (int k = 0; k < 16; ++k) {
            alignas(16) float a[8];
            alignas(8)  float b[6];
            *(float4*)(a)     = *(const float4*)&As[k][ty * 8];
            *(float4*)(a + 4) = *(const float4*)&As[k][ty * 8 + 4];
#pragma unroll
            for (int u = 0; u < 3; ++u) {
                float2 t = *(const float2*)&Bs[k][tx * 2 + 32 * u];
                b[2 * u] = t.x; b[2 * u + 1] = t.y;
            }
#pragma unroll
            for (int i = 0; i < 8; ++i)
#pragma unroll
                for (int j = 0; j < 6; ++j)
                    acc[i][j] = fmaf(a[i], b[j], acc[i][j]);
        }
        __syncthreads();
    }

    // fused pif epilogue
    const size_t bn = (size_t)((m0 + ty * 8) >> 3);
#pragma unroll
    for (int u = 0; u < 3; ++u) {
        size_t cbase = bn * Cn + j0 + 32 * u + tx * 2;
        float q0 = 0.5f, q1 = 0.5f;
        int   a0 = 0,    a1 = 0;
#pragma unroll
        for (int t = 0; t < Tn; ++t) {
            float o0 = if_sym(acc[t][2 * u],     q0, a0);
            float o1 = if_sym(acc[t][2 * u + 1], q1, a1);
            float2 st; st.x = o0; st.y = o1;
            *(float2*)(outp + (size_t)t * BNC + cbase) = st;
        }
    }
}

extern "C" void kernel_launch(void* const* d_in, const int* in_sizes, int n_in,
                              void* d_out, int out_size, void* d_ws, size_t ws_size,
                              hipStream_t stream) {
    (void)in_sizes; (void)n_in; (void)out_size; (void)d_ws; (void)ws_size;
    const float* x      = (const float*)d_in[0];
    const float* w_qkv  = (const float*)d_in[1];
    const float* w_proj = (const float*)d_in[2];
    float* outp = (float*)d_out;

    // qkv GEMM [32768 x 2304] K=768 with fused q/k/v IF epilogue
    gemm_qkv_fused<<<dim3(C3n / 96, (Tn * BNn) / 128), 256, 0, stream>>>(x, w_qkv);
    // transposed V operand
    vT_build<<<Tn * BHn, 256, 0, stream>>>();
    // all-t attn logits (i8 MFMA, exact)
    gemm_attn_all<<<dim3(64, BHn, Tn), 256, 0, stream>>>();
    // all-t aif + softmax + sif recurrence (reg state)
    attn_pipeline_all<<<BHn * Nn, 256, 0, stream>>>();
    // all-t PV (i8 MFMA) + fused oif
    gemm_pv_oif_all<<<dim3(8, BHn), 256, 0, stream>>>();
    // proj GEMM [32768 x 768] K=768 with fused pif epilogue -> output
    gemm_proj_pif_all<<<dim3(Cn / 96, (Tn * BNn) / 128), 256, 0, stream>>>(w_proj, outp);
}